// Round 1
// baseline (15240.849 us; speedup 1.0000x reference)
//
#include <hip/hip_runtime.h>

typedef _Float16 half_t;
typedef _Float16 half8 __attribute__((ext_vector_type(8)));
typedef float f32x4 __attribute__((ext_vector_type(4)));

#define NWG 128   // workgroups in recurrence (1 per CU, <=256 so all resident)

// ---------------- grid barrier (monotonic, memset to 0 before each launch) ----
__device__ inline void gbar(int* bar, int gen) {
  __syncthreads();
  if (threadIdx.x == 0) {
    __threadfence();
    int v = __hip_atomic_fetch_add(bar, 1, __ATOMIC_ACQ_REL, __HIP_MEMORY_SCOPE_AGENT);
    if (v == gen * NWG - 1) {
      __hip_atomic_store(bar + 64, gen, __ATOMIC_RELEASE, __HIP_MEMORY_SCOPE_AGENT);
    } else {
      int g;
      do {
        __builtin_amdgcn_s_sleep(1);
        g = __hip_atomic_load(bar + 64, __ATOMIC_ACQUIRE, __HIP_MEMORY_SCOPE_AGENT);
      } while (g < gen);
    }
  }
  __syncthreads();
}

// ---------------- fp32 [K][N] -> fp16 [N][K] transpose ----------------
__global__ void wt_transpose(const float* __restrict__ in, half_t* __restrict__ outp,
                             int K, int N) {
  __shared__ float tile[32][33];
  int nb = blockIdx.x * 32, kb = blockIdx.y * 32;
  int tx = threadIdx.x, ty = threadIdx.y;  // 32 x 8
  for (int i = ty; i < 32; i += 8)
    tile[i][tx] = in[(size_t)(kb + i) * N + nb + tx];
  __syncthreads();
  for (int i = ty; i < 32; i += 8)
    outp[(size_t)(nb + i) * K + kb + tx] = (half_t)tile[tx][i];
}

// ---------------- embedding gather -> fp16 in MFMA-A fragment order ----------
// frag layout elem (b,s,d): flat = (((s*8 + d>>5)*4 + b>>4)*64 + (b&15) + 16*((d&31)>>3))*8 + (d&7)
__global__ __launch_bounds__(256) void embed_kernel(const int* __restrict__ x,
    const float* __restrict__ emb, half_t* __restrict__ Ef) {
  int g = blockIdx.x * 256 + threadIdx.x;  // 0 .. 32768*32-1
  int m = g >> 5, dp = g & 31;
  int b = m & 63, s = m >> 6;
  int tok = x[b * 512 + s];
  const float* src = emb + (size_t)tok * 256 + dp * 8;
  half8 v;
  #pragma unroll
  for (int i = 0; i < 8; ++i) v[i] = (half_t)src[i];
  size_t fo = ((((size_t)s * 8 + (dp >> 2)) * 4 + (b >> 4)) * 64 + (b & 15) + ((dp & 3) << 4)) * 8;
  *(half8*)(Ef + fo) = v;
}

// ---------------- persistent GRU layer kernel --------------------------------
// KT = K_x/32 (8 for layer0 input dim 256, 32 for layer1 input dim 1024).
// WG w owns hidden units j0=w*8 .. j0+7.  LDS holds U^T slice (rows: z0-7,r0-7,
// hh0-7, pad-zeros) and W^T slice (rows: z,r, zeros, hh in 24..31 so the x-side
// candidate accumulates into acc cols 24..31 separately from h-side hh_r).
template<int KT, bool OUT_FRAG>
__global__ __launch_bounds__(256)
void recur_kernel(const half_t* __restrict__ xfrag, const half_t* __restrict__ WT,
                  const half_t* __restrict__ UT, const float* __restrict__ bias2,
                  half_t* __restrict__ ysout, half_t* __restrict__ hfrag,
                  int* __restrict__ bar) {
  constexpr int KX = KT * 32;
  extern __shared__ unsigned char smem[];
  unsigned char* Uraw = smem;                          // 32 x 1024 halfs = 64KB
  unsigned char* Wraw = smem + 65536;                  // 32 x KX halfs
  float* hg = (float*)(smem + 65536 + 32 * KX * 2);    // [64][33]
  float* hM = hg + 64 * 33;                            // [64][9] fp32 master h
  half_t* hn16 = (half_t*)(hM + 64 * 9);               // [64][8]

  const int tid = threadIdx.x;
  const int w = blockIdx.x;
  const int j0 = w * 8;
  const int lane = tid & 63, wv = tid >> 6;
  const int l15 = lane & 15, l4 = lane >> 4;

  // load U^T slice (+ zero pad rows 24..31)
  #pragma unroll
  for (int it = 0; it < 16; ++it) {
    int idx = it * 256 + tid;          // 0..4095
    int n = idx >> 7, kc = idx & 127;
    int byteoff = (n * 2048 + kc * 16) ^ ((n & 7) << 4);
    half8 v{};
    if (n < 24) {
      int grow = (n >> 3) * 1024 + j0 + (n & 7);
      v = *(const half8*)(UT + (size_t)grow * 1024 + kc * 8);
    }
    *(half8*)(Uraw + byteoff) = v;
  }
  // load W^T slice: rows 0-15 = z|r, rows 16-23 zero, rows 24-31 = hh
  #pragma unroll
  for (int it = 0; it < KT / 2; ++it) {
    int idx = it * 256 + tid;          // 0 .. 32*(KX/8)-1
    int n = idx / (KX / 8), kc = idx % (KX / 8);
    int byteoff = (n * KX * 2 + kc * 16) ^ ((n & 7) << 4);
    half8 v{};
    if (n < 16 || n >= 24) {
      int g = (n < 16) ? (n >> 3) : 2;
      int grow = g * 1024 + j0 + (n & 7);
      v = *(const half8*)(WT + (size_t)grow * KX + kc * 8);
    }
    *(half8*)(Wraw + byteoff) = v;
  }
  // init fp32 master h and hfrag buffer 0 slice
  if (tid < 64) {
    #pragma unroll
    for (int u = 0; u < 8; ++u) hM[tid * 9 + u] = 0.f;
    size_t fo = ((size_t)((w >> 2) * 4 + (tid >> 4)) * 64 + ((tid & 15) | ((w & 3) << 4))) * 8;
    *(half8*)(hfrag + fo) = half8{};
  }
  // hoist bias combos (per-thread constants)
  const int jpq = tid >> 6;
  float bz[2], br[2], bhr[2], bxh[2];
  #pragma unroll
  for (int q = 0; q < 2; ++q) {
    int j = j0 + jpq * 2 + q;
    bz[q]  = bias2[j]        + bias2[3072 + j];
    br[q]  = bias2[1024 + j] + bias2[4096 + j];
    bhr[q] = bias2[5120 + j];
    bxh[q] = bias2[2048 + j];
  }

  gbar(bar, 1);

  for (int t = 0; t < 512; ++t) {
    const half_t* hrd = hfrag + (size_t)(t & 1) * 65536;
    f32x4 acc0{}, acc1{};
    const int kbase2 = l4 * 16;  // byte offset of lane's k-slice within 32-k tile
    {
      const half_t* pa = hrd + wv * 512 + lane * 8;
      #pragma unroll 4
      for (int kt = 0; kt < 32; ++kt) {
        half8 af = *(const half8*)(pa + (size_t)kt * 2048);
        int k2 = kt * 64 + kbase2;
        int sw = (l15 & 7) << 4;
        half8 bf0 = *(const half8*)(Uraw + ((l15 * 2048 + k2) ^ sw));
        half8 bf1 = *(const half8*)(Uraw + (((16 + l15) * 2048 + k2) ^ sw));
        acc0 = __builtin_amdgcn_mfma_f32_16x16x32_f16(af, bf0, acc0, 0, 0, 0);
        acc1 = __builtin_amdgcn_mfma_f32_16x16x32_f16(af, bf1, acc1, 0, 0, 0);
      }
    }
    {
      const half_t* px = xfrag + ((size_t)t * KT * 4 + wv) * 512 + lane * 8;
      #pragma unroll 4
      for (int kt = 0; kt < KT; ++kt) {
        half8 xf = *(const half8*)(px + (size_t)kt * 2048);
        int k2 = kt * 64 + kbase2;
        int sw = (l15 & 7) << 4;
        half8 bf0 = *(const half8*)(Wraw + ((l15 * KX * 2 + k2) ^ sw));
        half8 bf1 = *(const half8*)(Wraw + (((16 + l15) * KX * 2 + k2) ^ sw));
        acc0 = __builtin_amdgcn_mfma_f32_16x16x32_f16(xf, bf0, acc0, 0, 0, 0);
        acc1 = __builtin_amdgcn_mfma_f32_16x16x32_f16(xf, bf1, acc1, 0, 0, 0);
      }
    }
    // scatter acc -> hg[64][33]  (C layout: col=lane&15, row=(lane>>4)*4+reg)
    #pragma unroll
    for (int r = 0; r < 4; ++r) {
      int row = wv * 16 + l4 * 4 + r;
      hg[row * 33 + l15] = acc0[r];
      hg[row * 33 + 16 + l15] = acc1[r];
    }
    __syncthreads();
    // gate combine: thread handles (b, 2 units)
    {
      int b = tid & 63;
      #pragma unroll
      for (int q = 0; q < 2; ++q) {
        int jj = jpq * 2 + q;
        float zp  = hg[b * 33 + jj] + bz[q];
        float rp  = hg[b * 33 + 8 + jj] + br[q];
        float hhr = hg[b * 33 + 16 + jj] + bhr[q];
        float xh  = hg[b * 33 + 24 + jj] + bxh[q];
        float z = 1.f / (1.f + __expf(-zp));
        float r = 1.f / (1.f + __expf(-rp));
        float hh = tanhf(xh + r * hhr);
        float hnew = z * hM[b * 9 + jj] + (1.f - z) * hh;
        hM[b * 9 + jj] = hnew;
        hn16[b * 8 + jj] = (half_t)hnew;
      }
    }
    __syncthreads();
    if (tid < 64) {
      int b = tid;
      half8 v = *(const half8*)(hn16 + b * 8);
      half_t* hwr = hfrag + (size_t)((t + 1) & 1) * 65536;
      size_t fo = ((size_t)((w >> 2) * 4 + (b >> 4)) * 64 + ((b & 15) | ((w & 3) << 4))) * 8;
      *(half8*)(hwr + fo) = v;
      if (OUT_FRAG) {
        size_t xo = (((size_t)t * 32 + (w >> 2)) * 4 + (b >> 4)) * 512 +
                    (size_t)((b & 15) | ((w & 3) << 4)) * 8;
        *(half8*)(ysout + xo) = v;
      } else {
        *(half8*)(ysout + ((size_t)t * 64 + b) * 1024 + j0) = v;
      }
    }
    gbar(bar, t + 2);
  }
}

// ---------------- 128x128 fp16 MFMA GEMM, fp32 C:  C[M][N] = A[M][K] @ BT[N][K]^T
__global__ __launch_bounds__(256)
void gemm128(const half_t* __restrict__ A, const half_t* __restrict__ BT,
             float* __restrict__ C, int M, int N, int K) {
  __shared__ __align__(16) half_t As[128 * 32];
  __shared__ __align__(16) half_t Bs[128 * 32];
  const int tid = threadIdx.x;
  const int lane = tid & 63, wid = tid >> 6;
  const int wm = wid >> 1, wn = wid & 1;
  const int l15 = lane & 15, l4 = lane >> 4;
  const int bm = blockIdx.y * 128, bn = blockIdx.x * 128;
  const int srow = tid >> 2;           // 0..63
  const int skb = (tid & 3) * 8;       // halfs
  f32x4 acc[4][4] = {};

  half8 va[2], vb[2];
  #pragma unroll
  for (int c = 0; c < 2; ++c) {
    int row = c * 64 + srow;
    va[c] = *(const half8*)(A + (size_t)(bm + row) * K + skb);
    vb[c] = *(const half8*)(BT + (size_t)(bn + row) * K + skb);
  }
  for (int k0 = 0; k0 < K; k0 += 32) {
    __syncthreads();
    #pragma unroll
    for (int c = 0; c < 2; ++c) {
      int row = c * 64 + srow;
      *(half8*)(As + row * 32 + skb) = va[c];
      *(half8*)(Bs + row * 32 + skb) = vb[c];
    }
    __syncthreads();
    int k1 = k0 + 32;
    if (k1 < K) {
      #pragma unroll
      for (int c = 0; c < 2; ++c) {
        int row = c * 64 + srow;
        va[c] = *(const half8*)(A + (size_t)(bm + row) * K + k1 + skb);
        vb[c] = *(const half8*)(BT + (size_t)(bn + row) * K + k1 + skb);
      }
    }
    half8 af[4], bf[4];
    #pragma unroll
    for (int mt = 0; mt < 4; ++mt)
      af[mt] = *(const half8*)(As + (wm * 64 + mt * 16 + l15) * 32 + l4 * 8);
    #pragma unroll
    for (int nt = 0; nt < 4; ++nt)
      bf[nt] = *(const half8*)(Bs + (wn * 64 + nt * 16 + l15) * 32 + l4 * 8);
    #pragma unroll
    for (int mt = 0; mt < 4; ++mt)
      #pragma unroll
      for (int nt = 0; nt < 4; ++nt)
        acc[mt][nt] = __builtin_amdgcn_mfma_f32_16x16x32_f16(af[mt], bf[nt], acc[mt][nt], 0, 0, 0);
  }
  #pragma unroll
  for (int mt = 0; mt < 4; ++mt)
    #pragma unroll
    for (int nt = 0; nt < 4; ++nt) {
      int col = bn + wn * 64 + nt * 16 + l15;
      int row0 = bm + wm * 64 + mt * 16 + l4 * 4;
      #pragma unroll
      for (int r = 0; r < 4; ++r)
        C[(size_t)(row0 + r) * N + col] = acc[mt][nt][r];
    }
}

// ---------------- softmax over 256 vocab (one wave per row) -------------------
__global__ __launch_bounds__(256)
void softmax_kernel(const float* __restrict__ logits, const float* __restrict__ bd,
                    float* __restrict__ out) {
  int w = threadIdx.x >> 6, lane = threadIdx.x & 63;
  int m = blockIdx.x * 4 + w;          // m = s*64 + b
  const float* lrow = logits + (size_t)m * 256;
  float v[4];
  #pragma unroll
  for (int i = 0; i < 4; ++i) v[i] = lrow[lane + i * 64] + bd[lane + i * 64];
  float mx = fmaxf(fmaxf(v[0], v[1]), fmaxf(v[2], v[3]));
  #pragma unroll
  for (int off = 32; off; off >>= 1) mx = fmaxf(mx, __shfl_xor(mx, off));
  float s = 0.f;
  #pragma unroll
  for (int i = 0; i < 4; ++i) { v[i] = __expf(v[i] - mx); s += v[i]; }
  #pragma unroll
  for (int off = 32; off; off >>= 1) s += __shfl_xor(s, off);
  float inv = 1.f / s;
  int b = m & 63, sq = m >> 6;
  float* orow = out + ((size_t)b * 512 + sq) * 256;
  #pragma unroll
  for (int i = 0; i < 4; ++i) orow[lane + i * 64] = v[i] * inv;
}

// ---------------- launch ------------------------------------------------------
extern "C" void kernel_launch(void* const* d_in, const int* in_sizes, int n_in,
                              void* d_out, int out_size, void* d_ws, size_t ws_size,
                              hipStream_t stream) {
  const int*   x   = (const int*)d_in[0];
  const float* emb = (const float*)d_in[1];
  const float* W0  = (const float*)d_in[2];
  const float* U0  = (const float*)d_in[3];
  const float* b0  = (const float*)d_in[4];
  const float* W1  = (const float*)d_in[5];
  const float* U1  = (const float*)d_in[6];
  const float* b1  = (const float*)d_in[7];
  const float* Wd  = (const float*)d_in[8];
  const float* bd  = (const float*)d_in[9];
  float* out = (float*)d_out;

  char* p = (char*)d_ws;
  size_t off = 0;
  auto take = [&](size_t bytes) {
    char* r = p + off;
    off = (off + bytes + 255) & ~(size_t)255;
    return r;
  };
  half_t* W0T = (half_t*)take(3072ull * 256 * 2);
  half_t* U0T = (half_t*)take(3072ull * 1024 * 2);
  half_t* W1T = (half_t*)take(3072ull * 1024 * 2);
  half_t* U1T = (half_t*)take(3072ull * 1024 * 2);
  half_t* WdT = (half_t*)take(256ull * 1024 * 2);
  half_t* E16 = (half_t*)take(32768ull * 256 * 2);   // frag-ordered embedded input
  half_t* ys0 = (half_t*)take(32768ull * 1024 * 2);  // frag-ordered layer0 output
  half_t* ys1 = (half_t*)take(32768ull * 1024 * 2);  // [s*64+b][1024] layer1 output
  half_t* hfrag = (half_t*)take(2ull * 65536 * 2);   // double-buffered h (frag order)
  int* bar = (int*)take(512);
  float* logits = (float*)take(32768ull * 256 * 4);
  (void)in_sizes; (void)n_in; (void)out_size; (void)ws_size;

  // weight transposes fp32->fp16 [N][K]
  wt_transpose<<<dim3(96, 8),  dim3(32, 8), 0, stream>>>(W0, W0T, 256, 3072);
  wt_transpose<<<dim3(96, 32), dim3(32, 8), 0, stream>>>(U0, U0T, 1024, 3072);
  wt_transpose<<<dim3(96, 32), dim3(32, 8), 0, stream>>>(W1, W1T, 1024, 3072);
  wt_transpose<<<dim3(96, 32), dim3(32, 8), 0, stream>>>(U1, U1T, 1024, 3072);
  wt_transpose<<<dim3(8, 32),  dim3(32, 8), 0, stream>>>(Wd, WdT, 1024, 256);
  embed_kernel<<<4096, 256, 0, stream>>>(x, emb, E16);

  hipFuncSetAttribute((const void*)recur_kernel<8, true>,
                      hipFuncAttributeMaxDynamicSharedMemorySize, 93696);
  hipFuncSetAttribute((const void*)recur_kernel<32, false>,
                      hipFuncAttributeMaxDynamicSharedMemorySize, 142848);

  hipMemsetAsync(bar, 0, 512, stream);
  recur_kernel<8, true><<<NWG, 256, 93696, stream>>>(E16, W0T, U0T, b0, ys0, hfrag, bar);
  hipMemsetAsync(bar, 0, 512, stream);
  recur_kernel<32, false><<<NWG, 256, 142848, stream>>>(ys0, W1T, U1T, b1, ys1, hfrag, bar);

  gemm128<<<dim3(2, 256), 256, 0, stream>>>(ys1, WdT, logits, 32768, 256, 1024);
  softmax_kernel<<<8192, 256, 0, stream>>>(logits, bd, out);
}

// Round 3
// 8965.745 us; speedup vs baseline: 1.6999x; 1.6999x over previous
//
#include <hip/hip_runtime.h>

typedef _Float16 half_t;
typedef _Float16 half8 __attribute__((ext_vector_type(8)));
typedef _Float16 half4 __attribute__((ext_vector_type(4)));
typedef float f32x4 __attribute__((ext_vector_type(4)));
typedef float f32x2 __attribute__((ext_vector_type(2)));

#define NWG 64   // recurrence workgroups, 16 hidden units each

// ---------------- fp32 [K][N] -> fp16 [N][K] transpose ----------------
__global__ void wt_transpose(const float* __restrict__ in, half_t* __restrict__ outp,
                             int K, int N) {
  __shared__ float tile[32][33];
  int nb = blockIdx.x * 32, kb = blockIdx.y * 32;
  int tx = threadIdx.x, ty = threadIdx.y;  // 32 x 8
  for (int i = ty; i < 32; i += 8)
    tile[i][tx] = in[(size_t)(kb + i) * N + nb + tx];
  __syncthreads();
  for (int i = ty; i < 32; i += 8)
    outp[(size_t)(nb + i) * K + kb + tx] = (half_t)tile[tx][i];
}

// ---------------- embedding gather -> fp16 row-major [m=s*64+b][256] ---------
__global__ __launch_bounds__(256) void embed_kernel(const int* __restrict__ x,
    const float* __restrict__ emb, half_t* __restrict__ E) {
  int g = blockIdx.x * 256 + threadIdx.x;  // 0 .. 32768*32-1
  int m = g >> 5, dp = g & 31;
  int b = m & 63, s = m >> 6;
  int tok = x[b * 512 + s];
  const float* src = emb + (size_t)tok * 256 + dp * 8;
  half8 v;
  #pragma unroll
  for (int i = 0; i < 8; ++i) v[i] = (half_t)src[i];
  *(half8*)(E + (size_t)m * 256 + dp * 8) = v;
}

// ---------------- 128x128 fp16 MFMA GEMM ------------------------------------
// A[.][K] fp16 row-major (rows offset by mbase), BT[N][K] fp16.
// XG=false: C fp32 row-major [local M][N].
// XG=true : C fp16 scattered as xg[tloc][w][g][b][jj], tloc=m>>6 (local), b=m&63,
//           w=(n&1023)>>4, g=n>>10, jj=n&15  (per-WG 6KB step slices).
template<bool XG>
__global__ __launch_bounds__(256)
void gemm128(const half_t* __restrict__ A, const half_t* __restrict__ BT,
             void* __restrict__ Cv, int mbase, int N, int K) {
  __shared__ __align__(16) half_t As[128 * 32];
  __shared__ __align__(16) half_t Bs[128 * 32];
  const int tid = threadIdx.x;
  const int lane = tid & 63, wid = tid >> 6;
  const int wm = wid >> 1, wn = wid & 1;
  const int l15 = lane & 15, l4 = lane >> 4;
  const int bm = blockIdx.y * 128, bn = blockIdx.x * 128;
  const int srow = tid >> 2;           // 0..63
  const int skb = (tid & 3) * 8;       // halfs
  f32x4 acc[4][4] = {};

  half8 va[2], vb[2];
  #pragma unroll
  for (int c = 0; c < 2; ++c) {
    int row = c * 64 + srow;
    va[c] = *(const half8*)(A + (size_t)(mbase + bm + row) * K + skb);
    vb[c] = *(const half8*)(BT + (size_t)(bn + row) * K + skb);
  }
  for (int k0 = 0; k0 < K; k0 += 32) {
    __syncthreads();
    #pragma unroll
    for (int c = 0; c < 2; ++c) {
      int row = c * 64 + srow;
      *(half8*)(As + row * 32 + skb) = va[c];
      *(half8*)(Bs + row * 32 + skb) = vb[c];
    }
    __syncthreads();
    int k1 = k0 + 32;
    if (k1 < K) {
      #pragma unroll
      for (int c = 0; c < 2; ++c) {
        int row = c * 64 + srow;
        va[c] = *(const half8*)(A + (size_t)(mbase + bm + row) * K + k1 + skb);
        vb[c] = *(const half8*)(BT + (size_t)(bn + row) * K + k1 + skb);
      }
    }
    half8 af[4], bf[4];
    #pragma unroll
    for (int mt = 0; mt < 4; ++mt)
      af[mt] = *(const half8*)(As + (wm * 64 + mt * 16 + l15) * 32 + l4 * 8);
    #pragma unroll
    for (int nt = 0; nt < 4; ++nt)
      bf[nt] = *(const half8*)(Bs + (wn * 64 + nt * 16 + l15) * 32 + l4 * 8);
    #pragma unroll
    for (int mt = 0; mt < 4; ++mt)
      #pragma unroll
      for (int nt = 0; nt < 4; ++nt)
        acc[mt][nt] = __builtin_amdgcn_mfma_f32_16x16x32_f16(af[mt], bf[nt], acc[mt][nt], 0, 0, 0);
  }
  if (XG) {
    half_t* Cx = (half_t*)Cv;
    #pragma unroll
    for (int mt = 0; mt < 4; ++mt)
      #pragma unroll
      for (int nt = 0; nt < 4; ++nt) {
        int n = bn + wn * 64 + nt * 16 + l15;
        int wslot = (n & 1023) >> 4, g = n >> 10, jj = n & 15;
        int m0 = bm + wm * 64 + mt * 16 + l4 * 4;
        #pragma unroll
        for (int r = 0; r < 4; ++r) {
          int m = m0 + r;
          size_t off = ((((size_t)(m >> 6) * 64 + wslot) * 3 + g) * 64 + (m & 63)) * 16 + jj;
          Cx[off] = (half_t)acc[mt][nt][r];
        }
      }
  } else {
    float* C = (float*)Cv;
    #pragma unroll
    for (int mt = 0; mt < 4; ++mt)
      #pragma unroll
      for (int nt = 0; nt < 4; ++nt) {
        int col = bn + wn * 64 + nt * 16 + l15;
        int row0 = bm + wm * 64 + mt * 16 + l4 * 4;
        #pragma unroll
        for (int r = 0; r < 4; ++r)
          C[(size_t)(row0 + r) * N + col] = acc[mt][nt][r];
      }
  }
}

// ---------------- persistent GRU recurrence (h-side only), chunked -----------
// 64 WGs, WG w owns units j0=w*16..+15. LDS: U^T slice 48 rows x 1024 (96KB,
// XOR-swizzled). xg pre-staged per step (6KB chunk-local slices). h exchanged
// via sc0/sc1 write-through stores + forced-miss loads (meets at L3);
// distributed per-WG flag barrier. fp32 master h persists in hMbuf.
__global__ __launch_bounds__(256, 1)
void recur2(const half_t* __restrict__ xg,   // chunk: [S][64][3][64][16] half
            const half_t* __restrict__ UT,   // [3072][1024] half
            const float* __restrict__ bias2, // [2][3072]
            half_t* __restrict__ ys,         // chunk rows: [(t-t0)*64+b][1024]
            half_t* __restrict__ hfrag,      // [2][65536] half
            float*  __restrict__ hMbuf,      // [64][1024] f32
            int* __restrict__ flags,         // [64]
            int t0, int t1) {
  extern __shared__ unsigned char smem[];
  float*  hg   = (float*)(smem + 98304);                   // [64][49]
  half_t* xsl  = (half_t*)(smem + 98304 + 12544);          // [3][64][16]
  half_t* hn16 = (half_t*)(smem + 98304 + 12544 + 6144);   // [64][16]

  const int tid = threadIdx.x;
  const int w = blockIdx.x;
  const int j0 = w * 16;
  const int lane = tid & 63, wv = tid >> 6;
  const int l15 = lane & 15, l4 = lane >> 4;
  const int ug = wv;
  const int b = tid & 63;

  // stage U^T slice: 48 rows (g*16+u) of 1024 k, XOR-swizzled
  for (int it = 0; it < 24; ++it) {
    int idx = it * 256 + tid;          // 0..6143
    int n = idx >> 7, kc = idx & 127;
    int byteoff = (n * 2048 + kc * 16) ^ ((n & 7) << 4);
    int g = n >> 4, u = n & 15;
    half8 v = *(const half8*)(UT + ((size_t)g * 1024 + j0 + u) * 1024 + kc * 8);
    *(half8*)(smem + byteoff) = v;
  }

  // per-thread gate constants + fp32 master h restore
  float bz[4], br[4], bhr[4], bxh[4], hMr[4];
  {
    f32x4 hm = *(const f32x4*)(hMbuf + b * 1024 + j0 + ug * 4);
    #pragma unroll
    for (int q = 0; q < 4; ++q) {
      int j = j0 + ug * 4 + q;
      bz[q]  = bias2[j]        + bias2[3072 + j];
      br[q]  = bias2[1024 + j] + bias2[4096 + j];
      bxh[q] = bias2[2048 + j];
      bhr[q] = bias2[5120 + j];
      hMr[q] = hm[q];
    }
  }

  // prologue: prefetch first xg slice of this chunk
  f32x2 xa, xb, xc;
  {
    const char* xp = (const char*)xg + (size_t)w * 6144 + tid * 24;
    asm volatile("global_load_dwordx2 %0, %1, off" : "=v"(xa) : "v"(xp));
    asm volatile("global_load_dwordx2 %0, %1, off" : "=v"(xb) : "v"(xp + 8));
    asm volatile("global_load_dwordx2 %0, %1, off" : "=v"(xc) : "v"(xp + 16));
  }

  for (int t = t0; t < t1; ++t) {
    // ---- wait for h_t published (distributed flags, agent-coherent) ----
    if (tid < 64) {
      while (true) {
        int f = __hip_atomic_load(&flags[tid], __ATOMIC_ACQUIRE, __HIP_MEMORY_SCOPE_AGENT);
        if (__all(f >= t)) break;
        __builtin_amdgcn_s_sleep(1);
      }
    }
    __syncthreads();  // S1

    // ---- commit prefetched xg regs -> LDS ----
    asm volatile("s_waitcnt vmcnt(0)" ::: "memory");
    __builtin_amdgcn_sched_barrier(0);
    {
      char* xd = (char*)xsl + tid * 24;
      *(f32x2*)xd = xa; *(f32x2*)(xd + 8) = xb; *(f32x2*)(xd + 16) = xc;
    }

    // ---- issue h loads (forced-miss), then next xg prefetch ----
    const half_t* hb = hfrag + ((size_t)(t & 1) << 16) + wv * 512 + lane * 8;
    f32x4 hr[32];
    #pragma unroll
    for (int kt = 0; kt < 32; ++kt)
      asm volatile("global_load_dwordx4 %0, %1, off sc0 sc1"
                   : "=v"(hr[kt]) : "v"(hb + kt * 2048));
    {
      int tl = ((t + 1 < t1) ? t + 1 : t) - t0;
      const char* xp = (const char*)xg + ((size_t)tl * 64 + w) * 6144 + tid * 24;
      asm volatile("global_load_dwordx2 %0, %1, off" : "=v"(xa) : "v"(xp));
      asm volatile("global_load_dwordx2 %0, %1, off" : "=v"(xb) : "v"(xp + 8));
      asm volatile("global_load_dwordx2 %0, %1, off" : "=v"(xc) : "v"(xp + 16));
    }
    asm volatile("s_waitcnt vmcnt(3)" ::: "memory");
    __builtin_amdgcn_sched_barrier(0);

    // ---- h @ U^T : 3 acc tiles (z|r|hh), 32 k-steps ----
    f32x4 a0{}, a1{}, a2{};
    const int k2b = l4 * 16;
    const int sw = (l15 & 7) << 4;
    #pragma unroll
    for (int kt = 0; kt < 32; ++kt) {
      int k2 = kt * 64 + k2b;
      half8 af = __builtin_bit_cast(half8, hr[kt]);
      half8 b0 = *(const half8*)(smem + ((l15 * 2048 + k2) ^ sw));
      half8 b1 = *(const half8*)(smem + (((16 + l15) * 2048 + k2) ^ sw));
      half8 b2 = *(const half8*)(smem + (((32 + l15) * 2048 + k2) ^ sw));
      a0 = __builtin_amdgcn_mfma_f32_16x16x32_f16(af, b0, a0, 0, 0, 0);
      a1 = __builtin_amdgcn_mfma_f32_16x16x32_f16(af, b1, a1, 0, 0, 0);
      a2 = __builtin_amdgcn_mfma_f32_16x16x32_f16(af, b2, a2, 0, 0, 0);
    }
    // scatter C (col=l15, row=l4*4+r) -> hg[batch][gatecol]
    #pragma unroll
    for (int r = 0; r < 4; ++r) {
      int row = wv * 16 + l4 * 4 + r;
      hg[row * 49 + l15]      = a0[r];
      hg[row * 49 + 16 + l15] = a1[r];
      hg[row * 49 + 32 + l15] = a2[r];
    }
    __syncthreads();  // S2

    // ---- gate combine: thread = (b, 4 units) ----
    half4 hv;
    #pragma unroll
    for (int q = 0; q < 4; ++q) {
      int jq = ug * 4 + q;
      float xz = (float)xsl[b * 16 + jq];
      float xr = (float)xsl[(64 + b) * 16 + jq];
      float xh = (float)xsl[(128 + b) * 16 + jq];
      float hz  = hg[b * 49 + jq];
      float hrv = hg[b * 49 + 16 + jq];
      float hhr = hg[b * 49 + 32 + jq];
      float z = 1.f / (1.f + __expf(-(xz + hz + bz[q])));
      float r = 1.f / (1.f + __expf(-(xr + hrv + br[q])));
      float targ = xh + bxh[q] + r * (hhr + bhr[q]);
      float hh = 1.f - 2.f / (1.f + __expf(2.f * targ));   // tanh
      float hnew = z * hMr[q] + (1.f - z) * hh;
      hMr[q] = hnew;
      hv[q] = (half_t)hnew;
      hn16[b * 16 + jq] = hv[q];
    }
    *(half4*)(ys + ((size_t)(t - t0) * 64 + b) * 1024 + j0 + ug * 4) = hv;
    __syncthreads();  // S3

    // ---- publish h_{t+1}: write-through frag stores, then flag ----
    if (tid < 128) {
      int bb = tid & 63, hs = tid >> 6;
      f32x4 dat = *(const f32x4*)(hn16 + bb * 16 + hs * 8);
      half_t* hwr = hfrag + ((size_t)((t + 1) & 1) << 16);
      size_t fo = (((size_t)(w >> 1) * 4 + (bb >> 4)) * 64 +
                   ((bb & 15) | (((w & 1) * 2 + hs) << 4))) * 8;
      asm volatile("global_store_dwordx4 %0, %1, off sc0 sc1"
                   :: "v"(hwr + fo), "v"(dat) : "memory");
    }
    asm volatile("s_waitcnt vmcnt(0)" ::: "memory");
    __syncthreads();  // S4
    if (tid == 0) {
      int tv = t + 1;
      asm volatile("global_store_dword %0, %1, off sc0 sc1"
                   :: "v"(flags + w), "v"(tv) : "memory");
    }
  }

  // save fp32 master h for next chunk
  {
    f32x4 hm;
    #pragma unroll
    for (int q = 0; q < 4; ++q) hm[q] = hMr[q];
    *(f32x4*)(hMbuf + b * 1024 + j0 + ug * 4) = hm;
  }
}

// ---------------- softmax over 256 vocab (one wave per row) -------------------
__global__ __launch_bounds__(256)
void softmax_kernel(const float* __restrict__ logits, const float* __restrict__ bd,
                    float* __restrict__ out) {
  int w = threadIdx.x >> 6, lane = threadIdx.x & 63;
  int m = blockIdx.x * 4 + w;          // m = s*64 + b
  const float* lrow = logits + (size_t)m * 256;
  float v[4];
  #pragma unroll
  for (int i = 0; i < 4; ++i) v[i] = lrow[lane + i * 64] + bd[lane + i * 64];
  float mx = fmaxf(fmaxf(v[0], v[1]), fmaxf(v[2], v[3]));
  #pragma unroll
  for (int off = 32; off; off >>= 1) mx = fmaxf(mx, __shfl_xor(mx, off));
  float s = 0.f;
  #pragma unroll
  for (int i = 0; i < 4; ++i) { v[i] = __expf(v[i] - mx); s += v[i]; }
  #pragma unroll
  for (int off = 32; off; off >>= 1) s += __shfl_xor(s, off);
  float inv = 1.f / s;
  int b = m & 63, sq = m >> 6;
  float* orow = out + ((size_t)b * 512 + sq) * 256;
  #pragma unroll
  for (int i = 0; i < 4; ++i) orow[lane + i * 64] = v[i] * inv;
}

// ---------------- workspace plan ---------------------------------------------
struct WSPlan {
  half_t *W0T, *U0T, *W1T, *U1T, *WdT;
  char* stateblk; size_t statebytes;
  half_t *hfrag0, *hfrag1; float *hM0, *hM1; int *flags0, *flags1;
  half_t *E16, *ys1, *ysc, *xgc; float* logits;
  size_t total;
};

static WSPlan plan_ws(char* base, size_t S) {
  WSPlan P; size_t off = 0;
  auto take = [&](size_t b) { char* r = base + off; off = (off + b + 255) & ~(size_t)255; return r; };
  P.W0T = (half_t*)take(3072ull * 256 * 2);
  P.U0T = (half_t*)take(3072ull * 1024 * 2);
  P.W1T = (half_t*)take(3072ull * 1024 * 2);
  P.U1T = (half_t*)take(3072ull * 1024 * 2);
  P.WdT = (half_t*)take(256ull * 1024 * 2);
  P.statebytes = 2 * (262144 + 262144 + 512);
  P.stateblk = take(P.statebytes);
  P.hfrag0 = (half_t*)P.stateblk;
  P.hM0    = (float*)(P.stateblk + 262144);
  P.flags0 = (int*)(P.stateblk + 524288);
  char* sb1 = P.stateblk + 524800;
  P.hfrag1 = (half_t*)sb1;
  P.hM1    = (float*)(sb1 + 262144);
  P.flags1 = (int*)(sb1 + 524288);
  P.E16 = (half_t*)take(32768ull * 256 * 2);
  P.ys1 = (half_t*)take(32768ull * 1024 * 2);
  P.ysc = (half_t*)take(S * 64ull * 1024 * 2);
  size_t xgb = S * 64ull * 3072 * 2;
  if (xgb < 33554432) xgb = 33554432;   // logits alias needs 32M
  char* rx = take(xgb);
  P.xgc = (half_t*)rx; P.logits = (float*)rx;
  P.total = off;
  return P;
}

// ---------------- launch ------------------------------------------------------
extern "C" void kernel_launch(void* const* d_in, const int* in_sizes, int n_in,
                              void* d_out, int out_size, void* d_ws, size_t ws_size,
                              hipStream_t stream) {
  const int*   x   = (const int*)d_in[0];
  const float* emb = (const float*)d_in[1];
  const float* W0  = (const float*)d_in[2];
  const float* U0  = (const float*)d_in[3];
  const float* b0  = (const float*)d_in[4];
  const float* W1  = (const float*)d_in[5];
  const float* U1  = (const float*)d_in[6];
  const float* b1  = (const float*)d_in[7];
  const float* Wd  = (const float*)d_in[8];
  const float* bd  = (const float*)d_in[9];
  float* out = (float*)d_out;
  (void)in_sizes; (void)n_in; (void)out_size;

  // choose largest chunk S that fits the workspace
  size_t S = 512;
  while (S > 64 && plan_ws((char*)0, S).total > ws_size) S >>= 1;
  WSPlan P = plan_ws((char*)d_ws, S);

  // weight transposes fp32->fp16 [N][K]
  wt_transpose<<<dim3(96, 8),  dim3(32, 8), 0, stream>>>(W0, P.W0T, 256, 3072);
  wt_transpose<<<dim3(96, 32), dim3(32, 8), 0, stream>>>(U0, P.U0T, 1024, 3072);
  wt_transpose<<<dim3(96, 32), dim3(32, 8), 0, stream>>>(W1, P.W1T, 1024, 3072);
  wt_transpose<<<dim3(96, 32), dim3(32, 8), 0, stream>>>(U1, P.U1T, 1024, 3072);
  wt_transpose<<<dim3(8, 32),  dim3(32, 8), 0, stream>>>(Wd, P.WdT, 1024, 256);
  embed_kernel<<<4096, 256, 0, stream>>>(x, emb, P.E16);

  hipFuncSetAttribute((const void*)recur2,
                      hipFuncAttributeMaxDynamicSharedMemorySize, 119040);

  // zero persistent state (hfrag/hM/flags for both layers) once per launch
  hipMemsetAsync(P.stateblk, 0, P.statebytes, stream);

  for (int t0 = 0; t0 < 512; t0 += (int)S) {
    int t1 = t0 + (int)S;
    // layer 0: xg chunk = E16[t0*64 ..] @ W0T
    gemm128<true><<<dim3(24, S / 2), 256, 0, stream>>>(P.E16, P.W0T, P.xgc, t0 * 64, 3072, 256);
    recur2<<<NWG, 256, 119040, stream>>>(P.xgc, P.U0T, b0, P.ysc,
                                         P.hfrag0, P.hM0, P.flags0, t0, t1);
    // layer 1: xg chunk = ysc @ W1T
    gemm128<true><<<dim3(24, S / 2), 256, 0, stream>>>(P.ysc, P.W1T, P.xgc, 0, 3072, 1024);
    recur2<<<NWG, 256, 119040, stream>>>(P.xgc, P.U1T, b1, P.ys1 + (size_t)t0 * 64 * 1024,
                                         P.hfrag1, P.hM1, P.flags1, t0, t1);
  }

  // dense + softmax
  gemm128<false><<<dim3(2, 256), 256, 0, stream>>>(P.ys1, P.WdT, P.logits, 0, 256, 1024);
  softmax_kernel<<<8192, 256, 0, stream>>>(P.logits, bd, out);
}

// Round 4
// 7595.304 us; speedup vs baseline: 2.0066x; 1.1804x over previous
//
#include <hip/hip_runtime.h>

typedef _Float16 half_t;
typedef _Float16 half8 __attribute__((ext_vector_type(8)));
typedef _Float16 half4 __attribute__((ext_vector_type(4)));
typedef float f32x4 __attribute__((ext_vector_type(4)));
typedef float f32x2 __attribute__((ext_vector_type(2)));

#define NWG 64   // recurrence workgroups, 16 hidden units each

// ---------------- fp32 [K][N] -> fp16 [N][K] transpose ----------------
__global__ void wt_transpose(const float* __restrict__ in, half_t* __restrict__ outp,
                             int K, int N) {
  __shared__ float tile[32][33];
  int nb = blockIdx.x * 32, kb = blockIdx.y * 32;
  int tx = threadIdx.x, ty = threadIdx.y;  // 32 x 8
  for (int i = ty; i < 32; i += 8)
    tile[i][tx] = in[(size_t)(kb + i) * N + nb + tx];
  __syncthreads();
  for (int i = ty; i < 32; i += 8)
    outp[(size_t)(nb + i) * K + kb + tx] = (half_t)tile[tx][i];
}

// ---------------- embedding gather -> fp16 row-major [m=s*64+b][256] ---------
__global__ __launch_bounds__(256) void embed_kernel(const int* __restrict__ x,
    const float* __restrict__ emb, half_t* __restrict__ E) {
  int g = blockIdx.x * 256 + threadIdx.x;  // 0 .. 32768*32-1
  int m = g >> 5, dp = g & 31;
  int b = m & 63, s = m >> 6;
  int tok = x[b * 512 + s];
  const float* src = emb + (size_t)tok * 256 + dp * 8;
  half8 v;
  #pragma unroll
  for (int i = 0; i < 8; ++i) v[i] = (half_t)src[i];
  *(half8*)(E + (size_t)m * 256 + dp * 8) = v;
}

// ---------------- 128x128 fp16 MFMA GEMM ------------------------------------
// A[.][K] fp16 row-major (rows offset by mbase), BT[N][K] fp16.
// XG=false: C fp32 row-major [local M][N].
// XG=true : C fp16 scattered as xg[tloc][w][g][b][jj], tloc=m>>6 (local), b=m&63,
//           w=(n&1023)>>4, g=n>>10, jj=n&15  (per-WG 6KB step slices).
template<bool XG>
__global__ __launch_bounds__(256)
void gemm128(const half_t* __restrict__ A, const half_t* __restrict__ BT,
             void* __restrict__ Cv, int mbase, int N, int K) {
  __shared__ __align__(16) half_t As[128 * 32];
  __shared__ __align__(16) half_t Bs[128 * 32];
  const int tid = threadIdx.x;
  const int lane = tid & 63, wid = tid >> 6;
  const int wm = wid >> 1, wn = wid & 1;
  const int l15 = lane & 15, l4 = lane >> 4;
  const int bm = blockIdx.y * 128, bn = blockIdx.x * 128;
  const int srow = tid >> 2;           // 0..63
  const int skb = (tid & 3) * 8;       // halfs
  f32x4 acc[4][4] = {};

  half8 va[2], vb[2];
  #pragma unroll
  for (int c = 0; c < 2; ++c) {
    int row = c * 64 + srow;
    va[c] = *(const half8*)(A + (size_t)(mbase + bm + row) * K + skb);
    vb[c] = *(const half8*)(BT + (size_t)(bn + row) * K + skb);
  }
  for (int k0 = 0; k0 < K; k0 += 32) {
    __syncthreads();
    #pragma unroll
    for (int c = 0; c < 2; ++c) {
      int row = c * 64 + srow;
      *(half8*)(As + row * 32 + skb) = va[c];
      *(half8*)(Bs + row * 32 + skb) = vb[c];
    }
    __syncthreads();
    int k1 = k0 + 32;
    if (k1 < K) {
      #pragma unroll
      for (int c = 0; c < 2; ++c) {
        int row = c * 64 + srow;
        va[c] = *(const half8*)(A + (size_t)(mbase + bm + row) * K + k1 + skb);
        vb[c] = *(const half8*)(BT + (size_t)(bn + row) * K + k1 + skb);
      }
    }
    half8 af[4], bf[4];
    #pragma unroll
    for (int mt = 0; mt < 4; ++mt)
      af[mt] = *(const half8*)(As + (wm * 64 + mt * 16 + l15) * 32 + l4 * 8);
    #pragma unroll
    for (int nt = 0; nt < 4; ++nt)
      bf[nt] = *(const half8*)(Bs + (wn * 64 + nt * 16 + l15) * 32 + l4 * 8);
    #pragma unroll
    for (int mt = 0; mt < 4; ++mt)
      #pragma unroll
      for (int nt = 0; nt < 4; ++nt)
        acc[mt][nt] = __builtin_amdgcn_mfma_f32_16x16x32_f16(af[mt], bf[nt], acc[mt][nt], 0, 0, 0);
  }
  if (XG) {
    half_t* Cx = (half_t*)Cv;
    #pragma unroll
    for (int mt = 0; mt < 4; ++mt)
      #pragma unroll
      for (int nt = 0; nt < 4; ++nt) {
        int n = bn + wn * 64 + nt * 16 + l15;
        int wslot = (n & 1023) >> 4, g = n >> 10, jj = n & 15;
        int m0 = bm + wm * 64 + mt * 16 + l4 * 4;
        #pragma unroll
        for (int r = 0; r < 4; ++r) {
          int m = m0 + r;
          size_t off = ((((size_t)(m >> 6) * 64 + wslot) * 3 + g) * 64 + (m & 63)) * 16 + jj;
          Cx[off] = (half_t)acc[mt][nt][r];
        }
      }
  } else {
    float* C = (float*)Cv;
    #pragma unroll
    for (int mt = 0; mt < 4; ++mt)
      #pragma unroll
      for (int nt = 0; nt < 4; ++nt) {
        int col = bn + wn * 64 + nt * 16 + l15;
        int row0 = bm + wm * 64 + mt * 16 + l4 * 4;
        #pragma unroll
        for (int r = 0; r < 4; ++r)
          C[(size_t)(row0 + r) * N + col] = acc[mt][nt][r];
      }
  }
}

// ---------------- persistent GRU recurrence (h-side only), chunked -----------
// 64 WGs, WG w owns units j0=w*16..+15. LDS: U^T slice 48 rows x 1024 (96KB,
// XOR-swizzled); z-gate B-frags additionally pinned in VGPRs. xg pre-staged per
// step (6KB chunk-local slices). h exchanged via sc0/sc1 write-through stores +
// forced-miss loads (meets at L3); relaxed sc0/sc1 flag poll (NO acquire -> no
// L2 invalidate). fp32 master h persists in hMbuf across chunk dispatches.
#define LDB(row, kt) (*(const half8*)(smem + ((((row) * 2048) + (kt) * 64 + k2b) ^ sw)))
#define MF(af, bf, acc) acc = __builtin_amdgcn_mfma_f32_16x16x32_f16(af, bf, acc, 0, 0, 0)
#define HL(i) asm volatile("global_load_dwordx4 %0, %1, off sc0 sc1" : "=v"(hr##i) : "v"(hb + i * 2048))
#define ZLD(i) half8 zf##i = LDB(l15, i)
#define K1(i) { half8 af = __builtin_bit_cast(half8, hr##i); \
    MF(af, zf##i, a0); \
    MF(af, LDB(16 + l15, i), a1); \
    MF(af, LDB(32 + l15, i), a2); }

__global__ __launch_bounds__(256, 1)
void recur2(const half_t* __restrict__ xg,   // chunk: [S][64][3][64][16] half
            const half_t* __restrict__ UT,   // [3072][1024] half
            const float* __restrict__ bias2, // [2][3072]
            half_t* __restrict__ ys,         // chunk rows: [(t-t0)*64+b][1024]
            half_t* __restrict__ hfrag,      // [2][65536] half
            float*  __restrict__ hMbuf,      // [64][1024] f32
            int* __restrict__ flags,         // [64]
            int t0, int t1) {
  extern __shared__ unsigned char smem[];
  float*  hg   = (float*)(smem + 98304);                   // [64][49]
  half_t* xsl  = (half_t*)(smem + 98304 + 12544);          // [3][64][16]

  const int tid = threadIdx.x;
  const int w = blockIdx.x;
  const int j0 = w * 16;
  const int lane = tid & 63, wv = tid >> 6;
  const int l15 = lane & 15, l4 = lane >> 4;
  const int ug = wv;
  const int b = tid & 63;

  // stage U^T slice: 48 rows (g*16+u) of 1024 k, XOR-swizzled
  for (int it = 0; it < 24; ++it) {
    int idx = it * 256 + tid;          // 0..6143
    int n = idx >> 7, kc = idx & 127;
    int byteoff = (n * 2048 + kc * 16) ^ ((n & 7) << 4);
    int g = n >> 4, u = n & 15;
    half8 v = *(const half8*)(UT + ((size_t)g * 1024 + j0 + u) * 1024 + kc * 8);
    *(half8*)(smem + byteoff) = v;
  }
  __syncthreads();

  const int k2b = l4 * 16;
  const int sw = (l15 & 7) << 4;
  // pin z-gate B-frags in registers (rows 0..15 of the slice)
  ZLD(0);  ZLD(1);  ZLD(2);  ZLD(3);  ZLD(4);  ZLD(5);  ZLD(6);  ZLD(7);
  ZLD(8);  ZLD(9);  ZLD(10); ZLD(11); ZLD(12); ZLD(13); ZLD(14); ZLD(15);
  ZLD(16); ZLD(17); ZLD(18); ZLD(19); ZLD(20); ZLD(21); ZLD(22); ZLD(23);
  ZLD(24); ZLD(25); ZLD(26); ZLD(27); ZLD(28); ZLD(29); ZLD(30); ZLD(31);

  // per-thread gate constants + fp32 master h restore
  float bz[4], br[4], bhr[4], bxh[4], hMr[4];
  {
    f32x4 hm = *(const f32x4*)(hMbuf + b * 1024 + j0 + ug * 4);
    #pragma unroll
    for (int q = 0; q < 4; ++q) {
      int j = j0 + ug * 4 + q;
      bz[q]  = bias2[j]        + bias2[3072 + j];
      br[q]  = bias2[1024 + j] + bias2[4096 + j];
      bxh[q] = bias2[2048 + j];
      bhr[q] = bias2[5120 + j];
      hMr[q] = hm[q];
    }
  }

  // prologue: prefetch first xg slice of this chunk
  f32x2 xa, xb, xc;
  {
    const char* xp = (const char*)xg + (size_t)w * 6144 + tid * 24;
    asm volatile("global_load_dwordx2 %0, %1, off" : "=v"(xa) : "v"(xp));
    asm volatile("global_load_dwordx2 %0, %1, off" : "=v"(xb) : "v"(xp + 8));
    asm volatile("global_load_dwordx2 %0, %1, off" : "=v"(xc) : "v"(xp + 16));
  }

  for (int t = t0; t < t1; ++t) {
    // ---- wait for h_t published: relaxed forced-miss poll (no invalidate) ----
    if (tid < 64) {
      const int* fp = flags + tid;
      int f;
      while (true) {
        asm volatile("global_load_dword %0, %1, off sc0 sc1\n\ts_waitcnt vmcnt(0)"
                     : "=v"(f) : "v"(fp) : "memory");
        if (__all(f >= t)) break;
        __builtin_amdgcn_s_sleep(2);
      }
    }
    __syncthreads();  // S1

    // ---- commit prefetched xg regs -> LDS ----
    asm volatile("s_waitcnt vmcnt(0)" ::: "memory");
    __builtin_amdgcn_sched_barrier(0);
    {
      char* xd = (char*)xsl + tid * 24;
      *(f32x2*)xd = xa; *(f32x2*)(xd + 8) = xb; *(f32x2*)(xd + 16) = xc;
    }

    // ---- issue h loads (forced-miss), then next xg prefetch ----
    const half_t* hb = hfrag + ((size_t)(t & 1) << 16) + wv * 512 + lane * 8;
    f32x4 hr0,  hr1,  hr2,  hr3,  hr4,  hr5,  hr6,  hr7;
    f32x4 hr8,  hr9,  hr10, hr11, hr12, hr13, hr14, hr15;
    f32x4 hr16, hr17, hr18, hr19, hr20, hr21, hr22, hr23;
    f32x4 hr24, hr25, hr26, hr27, hr28, hr29, hr30, hr31;
    HL(0);  HL(1);  HL(2);  HL(3);  HL(4);  HL(5);  HL(6);  HL(7);
    HL(8);  HL(9);  HL(10); HL(11); HL(12); HL(13); HL(14); HL(15);
    HL(16); HL(17); HL(18); HL(19); HL(20); HL(21); HL(22); HL(23);
    HL(24); HL(25); HL(26); HL(27); HL(28); HL(29); HL(30); HL(31);
    {
      int tl = ((t + 1 < t1) ? t + 1 : t) - t0;
      const char* xp = (const char*)xg + ((size_t)tl * 64 + w) * 6144 + tid * 24;
      asm volatile("global_load_dwordx2 %0, %1, off" : "=v"(xa) : "v"(xp));
      asm volatile("global_load_dwordx2 %0, %1, off" : "=v"(xb) : "v"(xp + 8));
      asm volatile("global_load_dwordx2 %0, %1, off" : "=v"(xc) : "v"(xp + 16));
    }

    // ---- h @ U^T, pipelined: 4 groups of 8 k-tiles, counted vmcnt ----
    f32x4 a0{}, a1{}, a2{};
    asm volatile("s_waitcnt vmcnt(27)" ::: "memory");
    __builtin_amdgcn_sched_barrier(0);
    K1(0)  K1(1)  K1(2)  K1(3)  K1(4)  K1(5)  K1(6)  K1(7)
    asm volatile("s_waitcnt vmcnt(19)" ::: "memory");
    __builtin_amdgcn_sched_barrier(0);
    K1(8)  K1(9)  K1(10) K1(11) K1(12) K1(13) K1(14) K1(15)
    asm volatile("s_waitcnt vmcnt(11)" ::: "memory");
    __builtin_amdgcn_sched_barrier(0);
    K1(16) K1(17) K1(18) K1(19) K1(20) K1(21) K1(22) K1(23)
    asm volatile("s_waitcnt vmcnt(3)" ::: "memory");
    __builtin_amdgcn_sched_barrier(0);
    K1(24) K1(25) K1(26) K1(27) K1(28) K1(29) K1(30) K1(31)

    // scatter C (col=l15, row=l4*4+r) -> hg[batch][gatecol]
    #pragma unroll
    for (int r = 0; r < 4; ++r) {
      int row = wv * 16 + l4 * 4 + r;
      hg[row * 49 + l15]      = a0[r];
      hg[row * 49 + 16 + l15] = a1[r];
      hg[row * 49 + 32 + l15] = a2[r];
    }
    __syncthreads();  // S2

    // ---- gate combine: thread = (b, 4 units) ----
    half4 hv;
    #pragma unroll
    for (int q = 0; q < 4; ++q) {
      int jq = ug * 4 + q;
      float xz = (float)xsl[b * 16 + jq];
      float xr = (float)xsl[(64 + b) * 16 + jq];
      float xh = (float)xsl[(128 + b) * 16 + jq];
      float hz  = hg[b * 49 + jq];
      float hrv = hg[b * 49 + 16 + jq];
      float hhr = hg[b * 49 + 32 + jq];
      float z = 1.f / (1.f + __expf(-(xz + hz + bz[q])));
      float r = 1.f / (1.f + __expf(-(xr + hrv + br[q])));
      float targ = xh + bxh[q] + r * (hhr + bhr[q]);
      float hh = 1.f - 2.f / (1.f + __expf(2.f * targ));   // tanh
      float hnew = z * hMr[q] + (1.f - z) * hh;
      hMr[q] = hnew;
      hv[q] = (half_t)hnew;
    }
    *(half4*)(ys + ((size_t)(t - t0) * 64 + b) * 1024 + j0 + ug * 4) = hv;

    // ---- publish h_{t+1} directly from regs: 8B write-through per thread ----
    {
      half_t* hwr = hfrag + ((size_t)((t + 1) & 1) << 16);
      size_t fo = (size_t)(w >> 1) * 2048 + (size_t)(b >> 4) * 512
                + (size_t)((w & 1) * 2 + (ug >> 1)) * 128 + (size_t)(b & 15) * 8
                + (size_t)(ug & 1) * 4;
      f32x2 pv = __builtin_bit_cast(f32x2, hv);
      asm volatile("global_store_dwordx2 %0, %1, off sc0 sc1"
                   :: "v"(hwr + fo), "v"(pv) : "memory");
    }
    asm volatile("s_waitcnt vmcnt(0)" ::: "memory");
    __syncthreads();  // S3: all publish stores complete
    if (tid == 0) {
      int tv = t + 1;
      asm volatile("global_store_dword %0, %1, off sc0 sc1"
                   :: "v"(flags + w), "v"(tv) : "memory");
    }
  }

  // save fp32 master h for next chunk
  {
    f32x4 hm;
    #pragma unroll
    for (int q = 0; q < 4; ++q) hm[q] = hMr[q];
    *(f32x4*)(hMbuf + b * 1024 + j0 + ug * 4) = hm;
  }
}

// ---------------- softmax over 256 vocab (one wave per row) -------------------
__global__ __launch_bounds__(256)
void softmax_kernel(const float* __restrict__ logits, const float* __restrict__ bd,
                    float* __restrict__ out) {
  int w = threadIdx.x >> 6, lane = threadIdx.x & 63;
  int m = blockIdx.x * 4 + w;          // m = s*64 + b
  const float* lrow = logits + (size_t)m * 256;
  float v[4];
  #pragma unroll
  for (int i = 0; i < 4; ++i) v[i] = lrow[lane + i * 64] + bd[lane + i * 64];
  float mx = fmaxf(fmaxf(v[0], v[1]), fmaxf(v[2], v[3]));
  #pragma unroll
  for (int off = 32; off; off >>= 1) mx = fmaxf(mx, __shfl_xor(mx, off));
  float s = 0.f;
  #pragma unroll
  for (int i = 0; i < 4; ++i) { v[i] = __expf(v[i] - mx); s += v[i]; }
  #pragma unroll
  for (int off = 32; off; off >>= 1) s += __shfl_xor(s, off);
  float inv = 1.f / s;
  int b = m & 63, sq = m >> 6;
  float* orow = out + ((size_t)b * 512 + sq) * 256;
  #pragma unroll
  for (int i = 0; i < 4; ++i) orow[lane + i * 64] = v[i] * inv;
}

// ---------------- workspace plan ---------------------------------------------
struct WSPlan {
  half_t *W0T, *U0T, *W1T, *U1T, *WdT;
  char* stateblk; size_t statebytes;
  half_t *hfrag0, *hfrag1; float *hM0, *hM1; int *flags0, *flags1;
  half_t *E16, *ys1, *ysc, *xgc; float* logits;
  size_t total;
};

static WSPlan plan_ws(char* base, size_t S) {
  WSPlan P; size_t off = 0;
  auto take = [&](size_t b) { char* r = base + off; off = (off + b + 255) & ~(size_t)255; return r; };
  P.W0T = (half_t*)take(3072ull * 256 * 2);
  P.U0T = (half_t*)take(3072ull * 1024 * 2);
  P.W1T = (half_t*)take(3072ull * 1024 * 2);
  P.U1T = (half_t*)take(3072ull * 1024 * 2);
  P.WdT = (half_t*)take(256ull * 1024 * 2);
  P.statebytes = 2 * (262144 + 262144 + 512);
  P.stateblk = take(P.statebytes);
  P.hfrag0 = (half_t*)P.stateblk;
  P.hM0    = (float*)(P.stateblk + 262144);
  P.flags0 = (int*)(P.stateblk + 524288);
  char* sb1 = P.stateblk + 524800;
  P.hfrag1 = (half_t*)sb1;
  P.hM1    = (float*)(sb1 + 262144);
  P.flags1 = (int*)(sb1 + 524288);
  P.E16 = (half_t*)take(32768ull * 256 * 2);
  P.ys1 = (half_t*)take(32768ull * 1024 * 2);
  P.ysc = (half_t*)take(S * 64ull * 1024 * 2);
  size_t xgb = S * 64ull * 3072 * 2;
  if (xgb < 33554432) xgb = 33554432;   // logits alias needs 32M
  char* rx = take(xgb);
  P.xgc = (half_t*)rx; P.logits = (float*)rx;
  P.total = off;
  return P;
}

// ---------------- launch ------------------------------------------------------
extern "C" void kernel_launch(void* const* d_in, const int* in_sizes, int n_in,
                              void* d_out, int out_size, void* d_ws, size_t ws_size,
                              hipStream_t stream) {
  const int*   x   = (const int*)d_in[0];
  const float* emb = (const float*)d_in[1];
  const float* W0  = (const float*)d_in[2];
  const float* U0  = (const float*)d_in[3];
  const float* b0  = (const float*)d_in[4];
  const float* W1  = (const float*)d_in[5];
  const float* U1  = (const float*)d_in[6];
  const float* b1  = (const float*)d_in[7];
  const float* Wd  = (const float*)d_in[8];
  const float* bd  = (const float*)d_in[9];
  float* out = (float*)d_out;
  (void)in_sizes; (void)n_in; (void)out_size;

  // choose largest chunk S that fits the workspace
  size_t S = 512;
  while (S > 64 && plan_ws((char*)0, S).total > ws_size) S >>= 1;
  WSPlan P = plan_ws((char*)d_ws, S);

  // weight transposes fp32->fp16 [N][K]
  wt_transpose<<<dim3(96, 8),  dim3(32, 8), 0, stream>>>(W0, P.W0T, 256, 3072);
  wt_transpose<<<dim3(96, 32), dim3(32, 8), 0, stream>>>(U0, P.U0T, 1024, 3072);
  wt_transpose<<<dim3(96, 32), dim3(32, 8), 0, stream>>>(W1, P.W1T, 1024, 3072);
  wt_transpose<<<dim3(96, 32), dim3(32, 8), 0, stream>>>(U1, P.U1T, 1024, 3072);
  wt_transpose<<<dim3(8, 32),  dim3(32, 8), 0, stream>>>(Wd, P.WdT, 1024, 256);
  embed_kernel<<<4096, 256, 0, stream>>>(x, emb, P.E16);

  hipFuncSetAttribute((const void*)recur2,
                      hipFuncAttributeMaxDynamicSharedMemorySize, 116992);

  // zero persistent state (hfrag/hM/flags for both layers) once per launch
  hipMemsetAsync(P.stateblk, 0, P.statebytes, stream);

  for (int t0 = 0; t0 < 512; t0 += (int)S) {
    int t1 = t0 + (int)S;
    // layer 0: xg chunk = E16[t0*64 ..] @ W0T
    gemm128<true><<<dim3(24, S / 2), 256, 0, stream>>>(P.E16, P.W0T, P.xgc, t0 * 64, 3072, 256);
    recur2<<<NWG, 256, 116992, stream>>>(P.xgc, P.U0T, b0, P.ysc,
                                         P.hfrag0, P.hM0, P.flags0, t0, t1);
    // layer 1: xg chunk = ysc @ W1T
    gemm128<true><<<dim3(24, S / 2), 256, 0, stream>>>(P.ysc, P.W1T, P.xgc, 0, 3072, 1024);
    recur2<<<NWG, 256, 116992, stream>>>(P.xgc, P.U1T, b1, P.ys1 + (size_t)t0 * 64 * 1024,
                                         P.hfrag1, P.hM1, P.flags1, t0, t1);
  }

  // dense + softmax
  gemm128<false><<<dim3(2, 256), 256, 0, stream>>>(P.ys1, P.WdT, P.logits, 0, 256, 1024);
  softmax_kernel<<<8192, 256, 0, stream>>>(P.logits, bd, out);
}

// Round 5
// 6889.236 us; speedup vs baseline: 2.2123x; 1.1025x over previous
//
#include <hip/hip_runtime.h>

typedef _Float16 half_t;
typedef _Float16 half8 __attribute__((ext_vector_type(8)));
typedef _Float16 half4 __attribute__((ext_vector_type(4)));
typedef float f32x4 __attribute__((ext_vector_type(4)));
typedef float f32x2 __attribute__((ext_vector_type(2)));

#define NWG 64   // recurrence WGs: 2 batch-groups x 32 unit-slots

// ---------------- fp32 [K][N] -> fp16 [N][K] transpose ----------------
__global__ void wt_transpose(const float* __restrict__ in, half_t* __restrict__ outp,
                             int K, int N) {
  __shared__ float tile[32][33];
  int nb = blockIdx.x * 32, kb = blockIdx.y * 32;
  int tx = threadIdx.x, ty = threadIdx.y;  // 32 x 8
  for (int i = ty; i < 32; i += 8)
    tile[i][tx] = in[(size_t)(kb + i) * N + nb + tx];
  __syncthreads();
  for (int i = ty; i < 32; i += 8)
    outp[(size_t)(nb + i) * K + kb + tx] = (half_t)tile[tx][i];
}

// ---------------- embedding gather -> fp16 row-major [m=s*64+b][256] ---------
__global__ __launch_bounds__(256) void embed_kernel(const int* __restrict__ x,
    const float* __restrict__ emb, half_t* __restrict__ E) {
  int g = blockIdx.x * 256 + threadIdx.x;  // 0 .. 32768*32-1
  int m = g >> 5, dp = g & 31;
  int b = m & 63, s = m >> 6;
  int tok = x[b * 512 + s];
  const float* src = emb + (size_t)tok * 256 + dp * 8;
  half8 v;
  #pragma unroll
  for (int i = 0; i < 8; ++i) v[i] = (half_t)src[i];
  *(half8*)(E + (size_t)m * 256 + dp * 8) = v;
}

// ---------------- 128x128 fp16 MFMA GEMM ------------------------------------
// A[.][K] fp16 row-major (rows offset by mbase), BT[N][K] fp16.
// XG=false: C fp32 row-major [local M][N].
// XG=true : C fp16 scattered per-WG slices: for element (m,n):
//   tloc=m>>6, bg=m&63, g=bg>>5, bl=bg&31, gate=n>>10, j=n&1023,
//   uslot=j>>5, u=j&31, w=g*32+uslot
//   off = ((tloc*64 + w)*3 + gate)*1024 + bl*32 + u
template<bool XG>
__global__ __launch_bounds__(256)
void gemm128(const half_t* __restrict__ A, const half_t* __restrict__ BT,
             void* __restrict__ Cv, int mbase, int N, int K) {
  __shared__ __align__(16) half_t As[128 * 32];
  __shared__ __align__(16) half_t Bs[128 * 32];
  const int tid = threadIdx.x;
  const int lane = tid & 63, wid = tid >> 6;
  const int wm = wid >> 1, wn = wid & 1;
  const int l15 = lane & 15, l4 = lane >> 4;
  const int bm = blockIdx.y * 128, bn = blockIdx.x * 128;
  const int srow = tid >> 2;           // 0..63
  const int skb = (tid & 3) * 8;       // halfs
  f32x4 acc[4][4] = {};

  half8 va[2], vb[2];
  #pragma unroll
  for (int c = 0; c < 2; ++c) {
    int row = c * 64 + srow;
    va[c] = *(const half8*)(A + (size_t)(mbase + bm + row) * K + skb);
    vb[c] = *(const half8*)(BT + (size_t)(bn + row) * K + skb);
  }
  for (int k0 = 0; k0 < K; k0 += 32) {
    __syncthreads();
    #pragma unroll
    for (int c = 0; c < 2; ++c) {
      int row = c * 64 + srow;
      *(half8*)(As + row * 32 + skb) = va[c];
      *(half8*)(Bs + row * 32 + skb) = vb[c];
    }
    __syncthreads();
    int k1 = k0 + 32;
    if (k1 < K) {
      #pragma unroll
      for (int c = 0; c < 2; ++c) {
        int row = c * 64 + srow;
        va[c] = *(const half8*)(A + (size_t)(mbase + bm + row) * K + k1 + skb);
        vb[c] = *(const half8*)(BT + (size_t)(bn + row) * K + k1 + skb);
      }
    }
    half8 af[4], bf[4];
    #pragma unroll
    for (int mt = 0; mt < 4; ++mt)
      af[mt] = *(const half8*)(As + (wm * 64 + mt * 16 + l15) * 32 + l4 * 8);
    #pragma unroll
    for (int nt = 0; nt < 4; ++nt)
      bf[nt] = *(const half8*)(Bs + (wn * 64 + nt * 16 + l15) * 32 + l4 * 8);
    #pragma unroll
    for (int mt = 0; mt < 4; ++mt)
      #pragma unroll
      for (int nt = 0; nt < 4; ++nt)
        acc[mt][nt] = __builtin_amdgcn_mfma_f32_16x16x32_f16(af[mt], bf[nt], acc[mt][nt], 0, 0, 0);
  }
  if (XG) {
    half_t* Cx = (half_t*)Cv;
    #pragma unroll
    for (int mt = 0; mt < 4; ++mt)
      #pragma unroll
      for (int nt = 0; nt < 4; ++nt) {
        int n = bn + wn * 64 + nt * 16 + l15;
        int gate = n >> 10, j = n & 1023;
        int uslot = j >> 5, u = j & 31;
        int m0 = bm + wm * 64 + mt * 16 + l4 * 4;
        #pragma unroll
        for (int r = 0; r < 4; ++r) {
          int m = m0 + r;
          int tloc = m >> 6, bg = m & 63;
          int g = bg >> 5, bl = bg & 31;
          size_t off = (((size_t)(tloc * 64 + g * 32 + uslot) * 3 + gate) << 10) + bl * 32 + u;
          Cx[off] = (half_t)acc[mt][nt][r];
        }
      }
  } else {
    float* C = (float*)Cv;
    #pragma unroll
    for (int mt = 0; mt < 4; ++mt)
      #pragma unroll
      for (int nt = 0; nt < 4; ++nt) {
        int col = bn + wn * 64 + nt * 16 + l15;
        int row0 = bm + wm * 64 + mt * 16 + l4 * 4;
        #pragma unroll
        for (int r = 0; r < 4; ++r)
          C[(size_t)(row0 + r) * N + col] = acc[mt][nt][r];
      }
  }
}

// ---------------- persistent GRU recurrence, batch-grouped ------------------
// WG w: group g=w>>5 (batch g*32..+31), uslot=w&31 (units j0=uslot*32..+31).
// Waves split K: wave wv handles k in [wv*256, wv*256+256).
// z,r weight frags pinned in VGPRs (loaded from UT global once);
// hh weight slice in swizzled LDS (64KB). Per-wave flags (4/WG), per-wave
// polling, h via sc0/sc1 write-through/forced-miss at L3.
#define MF(af, bf, acc) acc = __builtin_amdgcn_mfma_f32_16x16x32_f16(af, bf, acc, 0, 0, 0)
#define LDSH(u, kt) (*(const half8*)(smem + (((u) * 2048 + wv * 512 + (kt) * 64 + l4 * 16) ^ (((u) & 7) << 4))))
#define HLD(reg, base, OFS) asm volatile("global_load_dwordx4 %0, %1, off offset:" OFS " sc0 sc1" : "=v"(reg) : "v"(base))
#define KSTEP(kt) { \
    half8 af0 = __builtin_bit_cast(half8, hrA[0][kt]); \
    half8 af1 = __builtin_bit_cast(half8, hrA[1][kt]); \
    MF(af0, zr[0][0][kt], acc[0][0]); MF(af1, zr[0][0][kt], acc[1][0]); \
    MF(af0, zr[0][1][kt], acc[0][1]); MF(af1, zr[0][1][kt], acc[1][1]); \
    MF(af0, zr[1][0][kt], acc[0][2]); MF(af1, zr[1][0][kt], acc[1][2]); \
    MF(af0, zr[1][1][kt], acc[0][3]); MF(af1, zr[1][1][kt], acc[1][3]); \
    half8 bh0 = LDSH(l15, kt); half8 bh1 = LDSH(16 + l15, kt); \
    MF(af0, bh0, acc[0][4]); MF(af1, bh0, acc[1][4]); \
    MF(af0, bh1, acc[0][5]); MF(af1, bh1, acc[1][5]); }

__global__ __launch_bounds__(256, 1)
void recur3(const half_t* __restrict__ xg,   // [S][64 w][3][32 bl][32 u] half
            const half_t* __restrict__ UT,   // [3072][1024] half
            const float* __restrict__ bias2, // [2][3072]
            half_t* __restrict__ ys,         // [(t-t0)*64 + bglob][1024]
            half_t* __restrict__ hfrag,      // [2][64][1024] half
            float*  __restrict__ hMbuf,      // [64][1024] f32
            int* __restrict__ flags,         // [64 w][4 wv]
            int t0, int t1) {
  extern __shared__ unsigned char smem[];
  float* hgp = (float*)(smem + 65536);       // [4 kv][32 b][97] f32 partials

  const int tid = threadIdx.x;
  const int w = blockIdx.x;
  const int g = w >> 5, uslot = w & 31;
  const int j0 = uslot * 32;
  const int lane = tid & 63, wv = tid >> 6;
  const int l15 = lane & 15, l4 = lane >> 4;
  const int ug = tid >> 5;                   // 0..7
  const int bl = lane & 31;                  // batch within group

  // stage hh rows (32 units x 1024 k), XOR-swizzled
  for (int it = 0; it < 16; ++it) {
    int idx = it * 256 + tid;                // 0..4095
    int u = idx >> 7, kc = idx & 127;
    int byteoff = (u * 2048 + kc * 16) ^ ((u & 7) << 4);
    half8 v = *(const half8*)(UT + ((size_t)(2048 + j0 + u)) * 1024 + kc * 8);
    *(half8*)(smem + byteoff) = v;
  }

  // pin z,r B-frags in VGPRs: zr[gate][unit-half][kt], k-slice of this wave
  half8 zr[2][2][8];
  #pragma unroll
  for (int gate = 0; gate < 2; ++gate)
    #pragma unroll
    for (int uh = 0; uh < 2; ++uh)
      #pragma unroll
      for (int kt = 0; kt < 8; ++kt)
        zr[gate][uh][kt] = *(const half8*)(UT +
            ((size_t)(gate * 1024 + j0 + uh * 16 + l15)) * 1024 + wv * 256 + kt * 32 + l4 * 8);

  // per-thread gate constants + fp32 master h
  float bz[4], br[4], bhr[4], bxh[4], hMr[4];
  {
    f32x4 hm = *(const f32x4*)(hMbuf + (g * 32 + bl) * 1024 + j0 + ug * 4);
    #pragma unroll
    for (int q = 0; q < 4; ++q) {
      int j = j0 + ug * 4 + q;
      bz[q]  = bias2[j]        + bias2[3072 + j];
      br[q]  = bias2[1024 + j] + bias2[4096 + j];
      bxh[q] = bias2[2048 + j];
      bhr[q] = bias2[5120 + j];
      hMr[q] = hm[q];
    }
  }

  // prologue: prefetch first xg slice (per-thread 3 x 8B, consumer-ordered)
  f32x2 x0, x1, x2, xn0, xn1, xn2;
  {
    const char* xp = (const char*)xg + (size_t)w * 6144 + bl * 64 + ug * 8;
    asm volatile("global_load_dwordx2 %0, %1, off" : "=v"(x0) : "v"(xp));
    asm volatile("global_load_dwordx2 %0, %1, off" : "=v"(x1) : "v"(xp + 2048));
    asm volatile("global_load_dwordx2 %0, %1, off" : "=v"(x2) : "v"(xp + 4096));
  }
  const int fidx = (g * 32 + 8 * wv + ((lane & 31) >> 2)) * 4 + (lane & 3);
  const int* fp = flags + fidx;
  __syncthreads();   // hh staged

  for (int t = t0; t < t1; ++t) {
    // ---- per-wave poll: wait producers of our k-slice (32 flags) ----
    {
      int f;
      while (true) {
        asm volatile("global_load_dword %0, %1, off sc0 sc1\n\ts_waitcnt vmcnt(0)"
                     : "=v"(f) : "v"(fp) : "memory");
        if (__all(f >= t)) break;
        __builtin_amdgcn_s_sleep(1);
      }
    }

    // ---- issue h loads (forced-miss), reversed order on odd uslot ----
    f32x4 hrA[2][8];
    const char* hb0 = (const char*)hfrag + ((t & 1) << 17)
                    + (g * 32 + l15) * 2048 + wv * 512 + l4 * 16;
    const char* hb1 = hb0 + 32768;
    if (uslot & 1) {
      HLD(hrA[1][7], hb1, "448"); HLD(hrA[1][6], hb1, "384");
      HLD(hrA[1][5], hb1, "320"); HLD(hrA[1][4], hb1, "256");
      HLD(hrA[1][3], hb1, "192"); HLD(hrA[1][2], hb1, "128");
      HLD(hrA[1][1], hb1, "64");  HLD(hrA[1][0], hb1, "0");
      HLD(hrA[0][7], hb0, "448"); HLD(hrA[0][6], hb0, "384");
      HLD(hrA[0][5], hb0, "320"); HLD(hrA[0][4], hb0, "256");
      HLD(hrA[0][3], hb0, "192"); HLD(hrA[0][2], hb0, "128");
      HLD(hrA[0][1], hb0, "64");  HLD(hrA[0][0], hb0, "0");
    } else {
      HLD(hrA[0][0], hb0, "0");   HLD(hrA[0][1], hb0, "64");
      HLD(hrA[0][2], hb0, "128"); HLD(hrA[0][3], hb0, "192");
      HLD(hrA[0][4], hb0, "256"); HLD(hrA[0][5], hb0, "320");
      HLD(hrA[0][6], hb0, "384"); HLD(hrA[0][7], hb0, "448");
      HLD(hrA[1][0], hb1, "0");   HLD(hrA[1][1], hb1, "64");
      HLD(hrA[1][2], hb1, "128"); HLD(hrA[1][3], hb1, "192");
      HLD(hrA[1][4], hb1, "256"); HLD(hrA[1][5], hb1, "320");
      HLD(hrA[1][6], hb1, "384"); HLD(hrA[1][7], hb1, "448");
    }
    // next xg prefetch
    {
      int tl = ((t + 1 < t1) ? t + 1 : t) - t0;
      const char* xp = (const char*)xg + ((size_t)(tl * 64 + w)) * 6144 + bl * 64 + ug * 8;
      asm volatile("global_load_dwordx2 %0, %1, off" : "=v"(xn0) : "v"(xp));
      asm volatile("global_load_dwordx2 %0, %1, off" : "=v"(xn1) : "v"(xp + 2048));
      asm volatile("global_load_dwordx2 %0, %1, off" : "=v"(xn2) : "v"(xp + 4096));
    }
    asm volatile("s_waitcnt vmcnt(3)" ::: "memory");   // h + cur-xg done
    __builtin_amdgcn_sched_barrier(0);

    // ---- k-loop: 96 MFMA, all A/z/r from regs, hh from LDS ----
    f32x4 acc[2][6] = {};
    KSTEP(0) KSTEP(1) KSTEP(2) KSTEP(3) KSTEP(4) KSTEP(5) KSTEP(6) KSTEP(7)

    // ---- scatter partials: hg[wv][batch][col] ----
    #pragma unroll
    for (int m = 0; m < 2; ++m)
      #pragma unroll
      for (int n = 0; n < 6; ++n) {
        int col = (n >> 1) * 32 + (n & 1) * 16 + l15;
        #pragma unroll
        for (int r = 0; r < 4; ++r)
          hgp[(wv * 32 + m * 16 + l4 * 4 + r) * 97 + col] = acc[m][n][r];
      }
    __syncthreads();   // partials visible

    // ---- combine: thread=(bl, ug->4 units); sum 4 K-partials ----
    half4 hv;
    half4 xzv = __builtin_bit_cast(half4, x0);
    half4 xrv = __builtin_bit_cast(half4, x1);
    half4 xhv = __builtin_bit_cast(half4, x2);
    #pragma unroll
    for (int q = 0; q < 4; ++q) {
      int c = ug * 4 + q;
      float hz  = hgp[bl * 97 + c]        + hgp[(32 + bl) * 97 + c]
                + hgp[(64 + bl) * 97 + c] + hgp[(96 + bl) * 97 + c];
      float hrv = hgp[bl * 97 + 32 + c]        + hgp[(32 + bl) * 97 + 32 + c]
                + hgp[(64 + bl) * 97 + 32 + c] + hgp[(96 + bl) * 97 + 32 + c];
      float hhr = hgp[bl * 97 + 64 + c]        + hgp[(32 + bl) * 97 + 64 + c]
                + hgp[(64 + bl) * 97 + 64 + c] + hgp[(96 + bl) * 97 + 64 + c];
      float z = 1.f / (1.f + __expf(-((float)xzv[q] + hz + bz[q])));
      float r = 1.f / (1.f + __expf(-((float)xrv[q] + hrv + br[q])));
      float targ = (float)xhv[q] + bxh[q] + r * (hhr + bhr[q]);
      float hh = 1.f - 2.f / (1.f + __expf(2.f * targ));   // tanh
      float hnew = z * hMr[q] + (1.f - z) * hh;
      hMr[q] = hnew;
      hv[q] = (half_t)hnew;
    }
    // publish h_{t+1} (8B write-through per thread)
    {
      const char* hwr = (const char*)hfrag + (((t + 1) & 1) << 17)
                      + (g * 32 + bl) * 2048 + (j0 + ug * 4) * 2;
      f32x2 pv = __builtin_bit_cast(f32x2, hv);
      asm volatile("global_store_dwordx2 %0, %1, off sc0 sc1"
                   :: "v"(hwr), "v"(pv) : "memory");
    }
    *(half4*)(ys + ((size_t)(t - t0) * 64 + g * 32 + bl) * 1024 + j0 + ug * 4) = hv;
    asm volatile("s_waitcnt vmcnt(0)" ::: "memory");   // publish (and loads) drained
    __builtin_amdgcn_sched_barrier(0);
    x0 = xn0; x1 = xn1; x2 = xn2;
    if (lane == 0) {
      int tv = t + 1;
      asm volatile("global_store_dword %0, %1, off sc0 sc1"
                   :: "v"(flags + w * 4 + wv), "v"(tv) : "memory");
    }
    __syncthreads();   // hg reuse protection
  }

  // save fp32 master h for next chunk
  {
    f32x4 hm;
    #pragma unroll
    for (int q = 0; q < 4; ++q) hm[q] = hMr[q];
    *(f32x4*)(hMbuf + (g * 32 + bl) * 1024 + j0 + ug * 4) = hm;
  }
}

// ---------------- softmax over 256 vocab (one wave per row) -------------------
__global__ __launch_bounds__(256)
void softmax_kernel(const float* __restrict__ logits, const float* __restrict__ bd,
                    float* __restrict__ out) {
  int w = threadIdx.x >> 6, lane = threadIdx.x & 63;
  int m = blockIdx.x * 4 + w;          // m = s*64 + b
  const float* lrow = logits + (size_t)m * 256;
  float v[4];
  #pragma unroll
  for (int i = 0; i < 4; ++i) v[i] = lrow[lane + i * 64] + bd[lane + i * 64];
  float mx = fmaxf(fmaxf(v[0], v[1]), fmaxf(v[2], v[3]));
  #pragma unroll
  for (int off = 32; off; off >>= 1) mx = fmaxf(mx, __shfl_xor(mx, off));
  float s = 0.f;
  #pragma unroll
  for (int i = 0; i < 4; ++i) { v[i] = __expf(v[i] - mx); s += v[i]; }
  #pragma unroll
  for (int off = 32; off; off >>= 1) s += __shfl_xor(s, off);
  float inv = 1.f / s;
  int b = m & 63, sq = m >> 6;
  float* orow = out + ((size_t)b * 512 + sq) * 256;
  #pragma unroll
  for (int i = 0; i < 4; ++i) orow[lane + i * 64] = v[i] * inv;
}

// ---------------- workspace plan ---------------------------------------------
struct WSPlan {
  half_t *W0T, *U0T, *W1T, *U1T, *WdT;
  char* stateblk; size_t statebytes;
  half_t *hfrag0, *hfrag1; float *hM0, *hM1; int *flags0, *flags1;
  half_t *E16, *ys1, *ysc, *xgc; float* logits;
  size_t total;
};

static WSPlan plan_ws(char* base, size_t S) {
  WSPlan P; size_t off = 0;
  auto take = [&](size_t b) { char* r = base + off; off = (off + b + 255) & ~(size_t)255; return r; };
  P.W0T = (half_t*)take(3072ull * 256 * 2);
  P.U0T = (half_t*)take(3072ull * 1024 * 2);
  P.W1T = (half_t*)take(3072ull * 1024 * 2);
  P.U1T = (half_t*)take(3072ull * 1024 * 2);
  P.WdT = (half_t*)take(256ull * 1024 * 2);
  const size_t per_layer = 262144 + 262144 + 1024;  // hfrag + hM + flags
  P.statebytes = 2 * per_layer;
  P.stateblk = take(P.statebytes);
  P.hfrag0 = (half_t*)P.stateblk;
  P.hM0    = (float*)(P.stateblk + 262144);
  P.flags0 = (int*)(P.stateblk + 524288);
  char* sb1 = P.stateblk + per_layer;
  P.hfrag1 = (half_t*)sb1;
  P.hM1    = (float*)(sb1 + 262144);
  P.flags1 = (int*)(sb1 + 524288);
  P.E16 = (half_t*)take(32768ull * 256 * 2);
  P.ys1 = (half_t*)take(32768ull * 1024 * 2);
  P.ysc = (half_t*)take(S * 64ull * 1024 * 2);
  size_t xgb = S * 64ull * 3072 * 2;
  if (xgb < 33554432) xgb = 33554432;   // logits alias needs 32M
  char* rx = take(xgb);
  P.xgc = (half_t*)rx; P.logits = (float*)rx;
  P.total = off;
  return P;
}

// ---------------- launch ------------------------------------------------------
extern "C" void kernel_launch(void* const* d_in, const int* in_sizes, int n_in,
                              void* d_out, int out_size, void* d_ws, size_t ws_size,
                              hipStream_t stream) {
  const int*   x   = (const int*)d_in[0];
  const float* emb = (const float*)d_in[1];
  const float* W0  = (const float*)d_in[2];
  const float* U0  = (const float*)d_in[3];
  const float* b0  = (const float*)d_in[4];
  const float* W1  = (const float*)d_in[5];
  const float* U1  = (const float*)d_in[6];
  const float* b1  = (const float*)d_in[7];
  const float* Wd  = (const float*)d_in[8];
  const float* bd  = (const float*)d_in[9];
  float* out = (float*)d_out;
  (void)in_sizes; (void)n_in; (void)out_size;

  // choose largest chunk S that fits the workspace
  size_t S = 512;
  while (S > 64 && plan_ws((char*)0, S).total > ws_size) S >>= 1;
  WSPlan P = plan_ws((char*)d_ws, S);

  // weight transposes fp32->fp16 [N][K]
  wt_transpose<<<dim3(96, 8),  dim3(32, 8), 0, stream>>>(W0, P.W0T, 256, 3072);
  wt_transpose<<<dim3(96, 32), dim3(32, 8), 0, stream>>>(U0, P.U0T, 1024, 3072);
  wt_transpose<<<dim3(96, 32), dim3(32, 8), 0, stream>>>(W1, P.W1T, 1024, 3072);
  wt_transpose<<<dim3(96, 32), dim3(32, 8), 0, stream>>>(U1, P.U1T, 1024, 3072);
  wt_transpose<<<dim3(8, 32),  dim3(32, 8), 0, stream>>>(Wd, P.WdT, 1024, 256);
  embed_kernel<<<4096, 256, 0, stream>>>(x, emb, P.E16);

  hipFuncSetAttribute((const void*)recur3,
                      hipFuncAttributeMaxDynamicSharedMemorySize, 115200);

  // zero persistent state (hfrag/hM/flags for both layers) once per launch
  hipMemsetAsync(P.stateblk, 0, P.statebytes, stream);

  for (int t0 = 0; t0 < 512; t0 += (int)S) {
    int t1 = t0 + (int)S;
    // layer 0: xg chunk = E16[t0*64 ..] @ W0T
    gemm128<true><<<dim3(24, S / 2), 256, 0, stream>>>(P.E16, P.W0T, P.xgc, t0 * 64, 3072, 256);
    recur3<<<NWG, 256, 115200, stream>>>(P.xgc, P.U0T, b0, P.ysc,
                                         P.hfrag0, P.hM0, P.flags0, t0, t1);
    // layer 1: xg chunk = ysc @ W1T
    gemm128<true><<<dim3(24, S / 2), 256, 0, stream>>>(P.ysc, P.W1T, P.xgc, 0, 3072, 1024);
    recur3<<<NWG, 256, 115200, stream>>>(P.xgc, P.U1T, b1, P.ys1 + (size_t)t0 * 64 * 1024,
                                         P.hfrag1, P.hM1, P.flags1, t0, t1);
  }

  // dense + softmax
  gemm128<false><<<dim3(2, 256), 256, 0, stream>>>(P.ys1, P.WdT, P.logits, 0, 256, 1024);
  softmax_kernel<<<8192, 256, 0, stream>>>(P.logits, bd, out);
}

// Round 6
// 4509.047 us; speedup vs baseline: 3.3801x; 1.5279x over previous
//
#include <hip/hip_runtime.h>

typedef _Float16 half_t;
typedef _Float16 half8 __attribute__((ext_vector_type(8)));
typedef _Float16 half4 __attribute__((ext_vector_type(4)));
typedef _Float16 half2 __attribute__((ext_vector_type(2)));
typedef float f32x4 __attribute__((ext_vector_type(4)));
typedef float f32x2 __attribute__((ext_vector_type(2)));

// ---------------- fp32 [K][N] -> fp16 [N rows][ldo] transpose (col offset) ---
__global__ void wt_transpose(const float* __restrict__ in, half_t* __restrict__ outp,
                             int K, int N, int ldo, int co) {
  __shared__ float tile[32][33];
  int nb = blockIdx.x * 32, kb = blockIdx.y * 32;
  int tx = threadIdx.x, ty = threadIdx.y;  // 32 x 8
  for (int i = ty; i < 32; i += 8)
    tile[i][tx] = in[(size_t)(kb + i) * N + nb + tx];
  __syncthreads();
  for (int i = ty; i < 32; i += 8)
    outp[(size_t)(nb + i) * ldo + co + kb + tx] = (half_t)tile[tx][i];
}

// ---------------- embedding gather -> fp16 row-major [m=s*64+b][256] ---------
__global__ __launch_bounds__(256) void embed_kernel(const int* __restrict__ x,
    const float* __restrict__ emb, half_t* __restrict__ E) {
  int g = blockIdx.x * 256 + threadIdx.x;  // 0 .. 32768*32-1
  int m = g >> 5, dp = g & 31;
  int b = m & 63, s = m >> 6;
  int tok = x[b * 512 + s];
  const float* src = emb + (size_t)tok * 256 + dp * 8;
  half8 v;
  #pragma unroll
  for (int i = 0; i < 8; ++i) v[i] = (half_t)src[i];
  *(half8*)(E + (size_t)m * 256 + dp * 8) = v;
}

// ---------------- 128x128 fp16 MFMA GEMM, fp32 C row-major -------------------
__global__ __launch_bounds__(256)
void gemm128(const half_t* __restrict__ A, const half_t* __restrict__ BT,
             float* __restrict__ C, int N, int K) {
  __shared__ __align__(16) half_t As[128 * 32];
  __shared__ __align__(16) half_t Bs[128 * 32];
  const int tid = threadIdx.x;
  const int lane = tid & 63, wid = tid >> 6;
  const int wm = wid >> 1, wn = wid & 1;
  const int l15 = lane & 15, l4 = lane >> 4;
  const int bm = blockIdx.y * 128, bn = blockIdx.x * 128;
  const int srow = tid >> 2;
  const int skb = (tid & 3) * 8;
  f32x4 acc[4][4] = {};

  half8 va[2], vb[2];
  #pragma unroll
  for (int c = 0; c < 2; ++c) {
    int row = c * 64 + srow;
    va[c] = *(const half8*)(A + (size_t)(bm + row) * K + skb);
    vb[c] = *(const half8*)(BT + (size_t)(bn + row) * K + skb);
  }
  for (int k0 = 0; k0 < K; k0 += 32) {
    __syncthreads();
    #pragma unroll
    for (int c = 0; c < 2; ++c) {
      int row = c * 64 + srow;
      *(half8*)(As + row * 32 + skb) = va[c];
      *(half8*)(Bs + row * 32 + skb) = vb[c];
    }
    __syncthreads();
    int k1 = k0 + 32;
    if (k1 < K) {
      #pragma unroll
      for (int c = 0; c < 2; ++c) {
        int row = c * 64 + srow;
        va[c] = *(const half8*)(A + (size_t)(bm + row) * K + k1 + skb);
        vb[c] = *(const half8*)(BT + (size_t)(bn + row) * K + k1 + skb);
      }
    }
    half8 af[4], bf[4];
    #pragma unroll
    for (int mt = 0; mt < 4; ++mt)
      af[mt] = *(const half8*)(As + (wm * 64 + mt * 16 + l15) * 32 + l4 * 8);
    #pragma unroll
    for (int nt = 0; nt < 4; ++nt)
      bf[nt] = *(const half8*)(Bs + (wn * 64 + nt * 16 + l15) * 32 + l4 * 8);
    #pragma unroll
    for (int mt = 0; mt < 4; ++mt)
      #pragma unroll
      for (int nt = 0; nt < 4; ++nt)
        acc[mt][nt] = __builtin_amdgcn_mfma_f32_16x16x32_f16(af[mt], bf[nt], acc[mt][nt], 0, 0, 0);
  }
  #pragma unroll
  for (int mt = 0; mt < 4; ++mt)
    #pragma unroll
    for (int nt = 0; nt < 4; ++nt) {
      int col = bn + wn * 64 + nt * 16 + l15;
      int row0 = bm + wm * 64 + mt * 16 + l4 * 4;
      #pragma unroll
      for (int r = 0; r < 4; ++r)
        C[(size_t)(row0 + r) * N + col] = acc[mt][nt][r];
    }
}

// ---------------- fused 2-layer persistent GRU recurrence --------------------
// 192 WGs. WGs 0..63 = layer0 (group g=w>>5 batches g*32..+31, uslot=w&31,
// units j0=uslot*32..+31), K-concat [h0(1024); e(256)] vs T0=[U0;W0]^T.
// WGs 64..191 = layer1 (g=(w-64)>>6, uslot=(w-64)&63, units j0=uslot*16..+15),
// K-concat [h0(1024); h1(1024)] vs T1=[W1;U1]^T, running 1 epoch behind.
// h0frag triple-buffered (s%3), h1frag double-buffered (s&1); sc0/sc1
// write-through publish + forced-miss loads; per-WG flags.
// flag0 = e+1 <=> h0[e] published; flag1 = e <=> h1[e-1] published.
#define MF(af, bf, a) a = __builtin_amdgcn_mfma_f32_16x16x32_f16(af, bf, a, 0, 0, 0)
#define BC8(x) __builtin_bit_cast(half8, x)
#define GLD4(dst, base, OFS) asm volatile("global_load_dwordx4 %0, %1, off offset:" OFS " sc0 sc1" : "=v"(dst) : "v"(base))
#define GLD4P(dst, base, OFS) asm volatile("global_load_dwordx4 %0, %1, off offset:" OFS : "=v"(dst) : "v"(base))
#define HL8(t, B) GLD4(hrA[t][0],B,"0");GLD4(hrA[t][1],B,"64");GLD4(hrA[t][2],B,"128");GLD4(hrA[t][3],B,"192");GLD4(hrA[t][4],B,"256");GLD4(hrA[t][5],B,"320");GLD4(hrA[t][6],B,"384");GLD4(hrA[t][7],B,"448")
#define HL16(t, B) HL8(t,B);GLD4(hrA[t][8],B,"512");GLD4(hrA[t][9],B,"576");GLD4(hrA[t][10],B,"640");GLD4(hrA[t][11],B,"704");GLD4(hrA[t][12],B,"768");GLD4(hrA[t][13],B,"832");GLD4(hrA[t][14],B,"896");GLD4(hrA[t][15],B,"960")
#define LDH0(u, kt) (*(const half8*)(smem + ((((u) * 2048) + wv * 512 + (kt) * 64 + l4x16) ^ (((u) & 7) << 4))))
#define LDE0(u, kt) (*(const half8*)(smem + 65536 + ((((u) * 512) + wv * 128 + (kt) * 64 + l4x16) ^ (((u) & 7) << 4))))
#define LDH1(kt) (*(const half8*)(smem + ((l15 * 4096 + wv * 1024 + (kt) * 64 + l4x16) ^ ((l15 & 7) << 4))))

__global__ __launch_bounds__(256, 1)
void recur_fused(const half_t* __restrict__ E16,  // [32768][256]
                 const half_t* __restrict__ T0,   // [3072][1280] = [U0;W0]^T
                 const half_t* __restrict__ T1,   // [3072][2048] = [W1;U1]^T
                 const float* __restrict__ bias0, // [2][3072]
                 const float* __restrict__ bias1, // [2][3072]
                 half_t* __restrict__ ys1,        // [32768][1024]
                 half_t* __restrict__ h0f,        // [3][64][1024] half
                 half_t* __restrict__ h1f,        // [2][64][1024] half
                 int* __restrict__ flags0,        // [64]
                 int* __restrict__ flags1) {      // [128]
  extern __shared__ unsigned char smem[];
  const int tid = threadIdx.x;
  const int lane = tid & 63, wv = tid >> 6;
  const int l15 = lane & 15, l4 = lane >> 4;
  const int l4x16 = l4 * 16;
  const int ug = tid >> 5;          // 0..7
  const int bl = lane & 31;         // batch within group

  if (blockIdx.x < 64) {
    // =================== LAYER 0 ===================
    const int w = blockIdx.x;
    const int g = w >> 5, uslot = w & 31, j0 = uslot * 32;
    float* hgp = (float*)(smem + 81920);   // [4][32][129]

    // stage h-part hh rows (32 units x 1024), XOR-swizzled
    for (int it = 0; it < 16; ++it) {
      int idx = it * 256 + tid;
      int u = idx >> 7, kc = idx & 127;
      int byteoff = (u * 2048 + kc * 16) ^ ((u & 7) << 4);
      *(half8*)(smem + byteoff) =
          *(const half8*)(T0 + (size_t)(2048 + j0 + u) * 1280 + kc * 8);
    }
    // stage e-part hh rows (32 units x 256)
    for (int it = 0; it < 4; ++it) {
      int idx = it * 256 + tid;
      int u = idx >> 5, kc = idx & 31;
      int byteoff = 65536 + ((u * 512 + kc * 16) ^ ((u & 7) << 4));
      *(half8*)(smem + byteoff) =
          *(const half8*)(T0 + (size_t)(2048 + j0 + u) * 1280 + 1024 + kc * 8);
    }
    // pin z,r B-frags: h-part and e-part
    half8 zr[2][2][8], ezr[2][2][2];
    #pragma unroll
    for (int gate = 0; gate < 2; ++gate)
      #pragma unroll
      for (int uh = 0; uh < 2; ++uh) {
        const half_t* row = T0 + (size_t)(gate * 1024 + j0 + uh * 16 + l15) * 1280;
        #pragma unroll
        for (int kt = 0; kt < 8; ++kt)
          zr[gate][uh][kt] = *(const half8*)(row + wv * 256 + kt * 32 + l4 * 8);
        #pragma unroll
        for (int kt = 0; kt < 2; ++kt)
          ezr[gate][uh][kt] = *(const half8*)(row + 1024 + wv * 64 + kt * 32 + l4 * 8);
      }
    // gate constants + master h in regs
    float bz[4], br[4], bhr[4], bxh[4], hM[4];
    #pragma unroll
    for (int q = 0; q < 4; ++q) {
      int j = j0 + ug * 4 + q;
      bz[q]  = bias0[j]        + bias0[3072 + j];
      br[q]  = bias0[1024 + j] + bias0[4096 + j];
      bxh[q] = bias0[2048 + j];
      bhr[q] = bias0[5120 + j];
      hM[q] = 0.f;
    }
    __syncthreads();

    for (int e = 0; e < 512; ++e) {
      // poll: data (flags0 >= e) + WAR slack-2 (flags1 >= e-2)
      {
        const int* p0 = flags0 + g * 32 + bl;
        const int* p1 = flags1 + g * 64 + lane;
        int f0, f1;
        while (true) {
          asm volatile("global_load_dword %0, %2, off sc0 sc1\n\t"
                       "global_load_dword %1, %3, off sc0 sc1\n\t"
                       "s_waitcnt vmcnt(0)"
                       : "=v"(f0), "=v"(f1) : "v"(p0), "v"(p1) : "memory");
          if (__all((f0 >= e) && (f1 >= e - 2))) break;
          __builtin_amdgcn_s_sleep(1);
        }
      }
      // A loads: h0[e-1] (sc forced-miss) + e_t (plain)
      f32x4 hrA[2][8], erA[2][2];
      {
        const char* hbb = (const char*)h0f + (size_t)((e + 2) % 3) * 131072;
        const char* hb0 = hbb + (g * 32 + l15) * 2048 + wv * 512 + l4x16;
        const char* hb1 = hb0 + 32768;
        HL8(0, hb0); HL8(1, hb1);
        const char* eb0 = (const char*)E16 +
            (size_t)(e * 64 + g * 32 + l15) * 512 + wv * 128 + l4x16;
        const char* eb1 = eb0 + 8192;
        GLD4P(erA[0][0], eb0, "0"); GLD4P(erA[0][1], eb0, "64");
        GLD4P(erA[1][0], eb1, "0"); GLD4P(erA[1][1], eb1, "64");
      }
      asm volatile("s_waitcnt vmcnt(0)" ::: "memory");
      __builtin_amdgcn_sched_barrier(0);

      // MFMA: h-part 8 kt x 12 + e-part 2 kt x 12 = 120
      f32x4 acc[2][8] = {};
      #pragma unroll
      for (int kt = 0; kt < 8; ++kt) {
        half8 af0 = BC8(hrA[0][kt]), af1 = BC8(hrA[1][kt]);
        MF(af0, zr[0][0][kt], acc[0][0]); MF(af1, zr[0][0][kt], acc[1][0]);
        MF(af0, zr[0][1][kt], acc[0][1]); MF(af1, zr[0][1][kt], acc[1][1]);
        MF(af0, zr[1][0][kt], acc[0][2]); MF(af1, zr[1][0][kt], acc[1][2]);
        MF(af0, zr[1][1][kt], acc[0][3]); MF(af1, zr[1][1][kt], acc[1][3]);
        half8 bh0 = LDH0(l15, kt), bh1 = LDH0(16 + l15, kt);
        MF(af0, bh0, acc[0][4]); MF(af1, bh0, acc[1][4]);
        MF(af0, bh1, acc[0][5]); MF(af1, bh1, acc[1][5]);
      }
      #pragma unroll
      for (int kt = 0; kt < 2; ++kt) {
        half8 af0 = BC8(erA[0][kt]), af1 = BC8(erA[1][kt]);
        MF(af0, ezr[0][0][kt], acc[0][0]); MF(af1, ezr[0][0][kt], acc[1][0]);
        MF(af0, ezr[0][1][kt], acc[0][1]); MF(af1, ezr[0][1][kt], acc[1][1]);
        MF(af0, ezr[1][0][kt], acc[0][2]); MF(af1, ezr[1][0][kt], acc[1][2]);
        MF(af0, ezr[1][1][kt], acc[0][3]); MF(af1, ezr[1][1][kt], acc[1][3]);
        half8 be0 = LDE0(l15, kt), be1 = LDE0(16 + l15, kt);
        MF(af0, be0, acc[0][6]); MF(af1, be0, acc[1][6]);
        MF(af0, be1, acc[0][7]); MF(af1, be1, acc[1][7]);
      }
      // scatter partials: rows = kv*32 + batch, cols: z0..31|r|hh_h|hh_e
      #pragma unroll
      for (int m = 0; m < 2; ++m)
        #pragma unroll
        for (int n = 0; n < 8; ++n) {
          int colb = (n < 6) ? ((n >> 1) * 32 + (n & 1) * 16) : (96 + (n & 1) * 16);
          #pragma unroll
          for (int r = 0; r < 4; ++r)
            hgp[(wv * 32 + m * 16 + l4 * 4 + r) * 129 + colb + l15] = acc[m][n][r];
        }
      __syncthreads();
      // combine (thread = batch bl x 4 units)
      half4 hv;
      #pragma unroll
      for (int q = 0; q < 4; ++q) {
        int c = ug * 4 + q;
        float hz = 0.f, hr = 0.f, hhh = 0.f, xh = 0.f;
        #pragma unroll
        for (int kv = 0; kv < 4; ++kv) {
          const float* rowp = hgp + (kv * 32 + bl) * 129 + c;
          hz += rowp[0]; hr += rowp[32]; hhh += rowp[64]; xh += rowp[96];
        }
        float z = 1.f / (1.f + __expf(-(hz + bz[q])));
        float r = 1.f / (1.f + __expf(-(hr + br[q])));
        float targ = xh + bxh[q] + r * (hhh + bhr[q]);
        float hh = 1.f - 2.f / (1.f + __expf(2.f * targ));
        float hnew = z * hM[q] + (1.f - z) * hh;
        hM[q] = hnew;
        hv[q] = (half_t)hnew;
      }
      // publish h0[e] -> buf e%3
      {
        const char* dst = (const char*)h0f + (size_t)(e % 3) * 131072
                        + (g * 32 + bl) * 2048 + (j0 + ug * 4) * 2;
        f32x2 pv = __builtin_bit_cast(f32x2, hv);
        asm volatile("global_store_dwordx2 %0, %1, off sc0 sc1"
                     :: "v"(dst), "v"(pv) : "memory");
      }
      asm volatile("s_waitcnt vmcnt(0)" ::: "memory");
      __syncthreads();
      if (tid == 0) {
        int tv = e + 1;
        asm volatile("global_store_dword %0, %1, off sc0 sc1"
                     :: "v"(flags0 + w), "v"(tv) : "memory");
      }
    }
  } else {
    // =================== LAYER 1 ===================
    const int wp = blockIdx.x - 64;
    const int g = wp >> 6, uslot = wp & 63, j0 = uslot * 16;
    float* hgp = (float*)(smem + 65536);   // [4][32][65]

    // stage hh rows (16 units x 2048), XOR-swizzled
    for (int it = 0; it < 16; ++it) {
      int idx = it * 256 + tid;
      int u = idx >> 8, kc = idx & 255;
      int byteoff = (u * 4096 + kc * 16) ^ ((u & 7) << 4);
      *(half8*)(smem + byteoff) =
          *(const half8*)(T1 + (size_t)(2048 + j0 + u) * 2048 + kc * 8);
    }
    // pin z,r B-frags over this wave's 512-k slice
    half8 zr1[2][16];
    #pragma unroll
    for (int gate = 0; gate < 2; ++gate) {
      const half_t* row = T1 + (size_t)(gate * 1024 + j0 + l15) * 2048 + wv * 512;
      #pragma unroll
      for (int kt = 0; kt < 16; ++kt)
        zr1[gate][kt] = *(const half8*)(row + kt * 32 + l4 * 8);
    }
    float bz[2], br[2], bhr[2], bxh[2], hM[2];
    #pragma unroll
    for (int q = 0; q < 2; ++q) {
      int j = j0 + ug * 2 + q;
      bz[q]  = bias1[j]        + bias1[3072 + j];
      br[q]  = bias1[1024 + j] + bias1[4096 + j];
      bxh[q] = bias1[2048 + j];
      bhr[q] = bias1[5120 + j];
      hM[q] = 0.f;
    }
    __syncthreads();

    for (int e = 1; e <= 512; ++e) {
      // poll: waves 0,1 need h0[e-1] (flags0>=e); waves 2,3 need h1[e-2] (flags1>=e-1)
      {
        const int* p = (wv < 2) ? (flags0 + g * 32 + bl) : (flags1 + g * 64 + lane);
        const int tgt = (wv < 2) ? e : (e - 1);
        int f;
        while (true) {
          asm volatile("global_load_dword %0, %1, off sc0 sc1\n\ts_waitcnt vmcnt(0)"
                       : "=v"(f) : "v"(p) : "memory");
          if (__all(f >= tgt)) break;
          __builtin_amdgcn_s_sleep(1);
        }
      }
      // A loads: waves 0,1 from h0[e-1] (buf (e-1)%3); waves 2,3 from h1[e-2] (buf e&1)
      f32x4 hrA[2][16];
      {
        const char* fb = (wv < 2)
            ? (const char*)h0f + (size_t)((e + 2) % 3) * 131072
            : (const char*)h1f + (size_t)(e & 1) * 131072;
        const char* b0 = fb + (g * 32 + l15) * 2048 + (wv & 1) * 1024 + l4x16;
        const char* b1 = b0 + 32768;
        HL16(0, b0); HL16(1, b1);
      }
      asm volatile("s_waitcnt vmcnt(0)" ::: "memory");
      __builtin_amdgcn_sched_barrier(0);

      // MFMA: 16 kt x 6 = 96
      f32x4 acc[2][3] = {};
      #pragma unroll
      for (int kt = 0; kt < 16; ++kt) {
        half8 af0 = BC8(hrA[0][kt]), af1 = BC8(hrA[1][kt]);
        MF(af0, zr1[0][kt], acc[0][0]); MF(af1, zr1[0][kt], acc[1][0]);
        MF(af0, zr1[1][kt], acc[0][1]); MF(af1, zr1[1][kt], acc[1][1]);
        half8 bh = LDH1(kt);
        MF(af0, bh, acc[0][2]); MF(af1, bh, acc[1][2]);
      }
      // scatter: cols z:0..15, r:16..31, hh_h:32..47 (wv>=2), hh_x:48..63 (wv<2)
      {
        int hhcol = (wv < 2) ? 48 : 32;
        #pragma unroll
        for (int m = 0; m < 2; ++m)
          #pragma unroll
          for (int r = 0; r < 4; ++r) {
            int row = (wv * 32 + m * 16 + l4 * 4 + r) * 65;
            hgp[row + l15]        = acc[m][0][r];
            hgp[row + 16 + l15]   = acc[m][1][r];
            hgp[row + hhcol + l15] = acc[m][2][r];
          }
      }
      __syncthreads();
      // combine (thread = batch bl x 2 units)
      half2 hv;
      #pragma unroll
      for (int q = 0; q < 2; ++q) {
        int c = ug * 2 + q;
        float hz = 0.f, hr = 0.f;
        #pragma unroll
        for (int kv = 0; kv < 4; ++kv) {
          const float* rowp = hgp + (kv * 32 + bl) * 65 + c;
          hz += rowp[0]; hr += rowp[16];
        }
        float hhh = hgp[(2 * 32 + bl) * 65 + 32 + c] + hgp[(3 * 32 + bl) * 65 + 32 + c];
        float xh  = hgp[(0 * 32 + bl) * 65 + 48 + c] + hgp[(1 * 32 + bl) * 65 + 48 + c];
        float z = 1.f / (1.f + __expf(-(hz + bz[q])));
        float r = 1.f / (1.f + __expf(-(hr + br[q])));
        float targ = xh + bxh[q] + r * (hhh + bhr[q]);
        float hh = 1.f - 2.f / (1.f + __expf(2.f * targ));
        float hnew = z * hM[q] + (1.f - z) * hh;
        hM[q] = hnew;
        hv[q] = (half_t)hnew;
      }
      // output + publish h1[e-1] -> buf (e-1)&1
      *(half2*)(ys1 + ((size_t)(e - 1) * 64 + g * 32 + bl) * 1024 + j0 + ug * 2) = hv;
      {
        const char* dst = (const char*)h1f + (size_t)((e - 1) & 1) * 131072
                        + (g * 32 + bl) * 2048 + (j0 + ug * 2) * 2;
        float pv = __builtin_bit_cast(float, hv);
        asm volatile("global_store_dword %0, %1, off sc0 sc1"
                     :: "v"(dst), "v"(pv) : "memory");
      }
      asm volatile("s_waitcnt vmcnt(0)" ::: "memory");
      __syncthreads();
      if (tid == 0) {
        int tv = e;
        asm volatile("global_store_dword %0, %1, off sc0 sc1"
                     :: "v"(flags1 + wp), "v"(tv) : "memory");
      }
    }
  }
}

// ---------------- softmax over 256 vocab (one wave per row) -------------------
__global__ __launch_bounds__(256)
void softmax_kernel(const float* __restrict__ logits, const float* __restrict__ bd,
                    float* __restrict__ out) {
  int w = threadIdx.x >> 6, lane = threadIdx.x & 63;
  int m = blockIdx.x * 4 + w;          // m = s*64 + b
  const float* lrow = logits + (size_t)m * 256;
  float v[4];
  #pragma unroll
  for (int i = 0; i < 4; ++i) v[i] = lrow[lane + i * 64] + bd[lane + i * 64];
  float mx = fmaxf(fmaxf(v[0], v[1]), fmaxf(v[2], v[3]));
  #pragma unroll
  for (int off = 32; off; off >>= 1) mx = fmaxf(mx, __shfl_xor(mx, off));
  float s = 0.f;
  #pragma unroll
  for (int i = 0; i < 4; ++i) { v[i] = __expf(v[i] - mx); s += v[i]; }
  #pragma unroll
  for (int off = 32; off; off >>= 1) s += __shfl_xor(s, off);
  float inv = 1.f / s;
  int b = m & 63, sq = m >> 6;
  float* orow = out + ((size_t)b * 512 + sq) * 256;
  #pragma unroll
  for (int i = 0; i < 4; ++i) orow[lane + i * 64] = v[i] * inv;
}

// ---------------- launch ------------------------------------------------------
extern "C" void kernel_launch(void* const* d_in, const int* in_sizes, int n_in,
                              void* d_out, int out_size, void* d_ws, size_t ws_size,
                              hipStream_t stream) {
  const int*   x   = (const int*)d_in[0];
  const float* emb = (const float*)d_in[1];
  const float* W0  = (const float*)d_in[2];
  const float* U0  = (const float*)d_in[3];
  const float* b0  = (const float*)d_in[4];
  const float* W1  = (const float*)d_in[5];
  const float* U1  = (const float*)d_in[6];
  const float* b1  = (const float*)d_in[7];
  const float* Wd  = (const float*)d_in[8];
  const float* bd  = (const float*)d_in[9];
  float* out = (float*)d_out;
  (void)in_sizes; (void)n_in; (void)out_size; (void)ws_size;

  char* p = (char*)d_ws;
  size_t off = 0;
  auto take = [&](size_t bytes) {
    char* r = p + off;
    off = (off + bytes + 255) & ~(size_t)255;
    return r;
  };
  half_t* T0  = (half_t*)take(3072ull * 1280 * 2);   // [U0;W0]^T
  half_t* T1  = (half_t*)take(3072ull * 2048 * 2);   // [W1;U1]^T
  half_t* WdT = (half_t*)take(256ull * 1024 * 2);
  char* stateblk = take(393216 + 262144 + 256 + 512);
  half_t* h0f   = (half_t*)stateblk;
  half_t* h1f   = (half_t*)(stateblk + 393216);
  int*    flags0 = (int*)(stateblk + 393216 + 262144);
  int*    flags1 = (int*)(stateblk + 393216 + 262144 + 256);
  half_t* E16 = (half_t*)take(32768ull * 256 * 2);
  half_t* ys1 = (half_t*)take(32768ull * 1024 * 2);
  float* logits = (float*)take(32768ull * 256 * 4);

  // weight transposes fp32->fp16 into concat layouts
  wt_transpose<<<dim3(96, 32), dim3(32, 8), 0, stream>>>(U0, T0, 1024, 3072, 1280, 0);
  wt_transpose<<<dim3(96, 8),  dim3(32, 8), 0, stream>>>(W0, T0, 256,  3072, 1280, 1024);
  wt_transpose<<<dim3(96, 32), dim3(32, 8), 0, stream>>>(W1, T1, 1024, 3072, 2048, 0);
  wt_transpose<<<dim3(96, 32), dim3(32, 8), 0, stream>>>(U1, T1, 1024, 3072, 2048, 1024);
  wt_transpose<<<dim3(8, 32),  dim3(32, 8), 0, stream>>>(Wd, WdT, 1024, 256, 1024, 0);
  embed_kernel<<<4096, 256, 0, stream>>>(x, emb, E16);

  hipFuncSetAttribute((const void*)recur_fused,
                      hipFuncAttributeMaxDynamicSharedMemorySize, 147968);
  hipMemsetAsync(stateblk, 0, 393216 + 262144 + 256 + 512, stream);

  recur_fused<<<192, 256, 147968, stream>>>(E16, T0, T1, b0, b1, ys1,
                                            h0f, h1f, flags0, flags1);

  gemm128<<<dim3(2, 256), 256, 0, stream>>>(ys1, WdT, logits, 256, 1024);
  softmax_kernel<<<8192, 256, 0, stream>>>(logits, bd, out);
}

// Round 7
// 3811.885 us; speedup vs baseline: 3.9982x; 1.1829x over previous
//
#include <hip/hip_runtime.h>

typedef _Float16 half_t;
typedef _Float16 half8 __attribute__((ext_vector_type(8)));
typedef _Float16 half4 __attribute__((ext_vector_type(4)));
typedef _Float16 half2 __attribute__((ext_vector_type(2)));
typedef float f32x4 __attribute__((ext_vector_type(4)));
typedef float f32x2 __attribute__((ext_vector_type(2)));

// ---------------- fp32 [K][N] -> fp16 [N rows][ldo] transpose (col offset) ---
__global__ void wt_transpose(const float* __restrict__ in, half_t* __restrict__ outp,
                             int K, int N, int ldo, int co) {
  __shared__ float tile[32][33];
  int nb = blockIdx.x * 32, kb = blockIdx.y * 32;
  int tx = threadIdx.x, ty = threadIdx.y;  // 32 x 8
  for (int i = ty; i < 32; i += 8)
    tile[i][tx] = in[(size_t)(kb + i) * N + nb + tx];
  __syncthreads();
  for (int i = ty; i < 32; i += 8)
    outp[(size_t)(nb + i) * ldo + co + kb + tx] = (half_t)tile[tx][i];
}

// ---------------- embedding gather -> fp16 row-major [m=s*64+b][256] ---------
__global__ __launch_bounds__(256) void embed_kernel(const int* __restrict__ x,
    const float* __restrict__ emb, half_t* __restrict__ E) {
  int g = blockIdx.x * 256 + threadIdx.x;  // 0 .. 32768*32-1
  int m = g >> 5, dp = g & 31;
  int b = m & 63, s = m >> 6;
  int tok = x[b * 512 + s];
  const float* src = emb + (size_t)tok * 256 + dp * 8;
  half8 v;
  #pragma unroll
  for (int i = 0; i < 8; ++i) v[i] = (half_t)src[i];
  *(half8*)(E + (size_t)m * 256 + dp * 8) = v;
}

// ---------------- 128x128 fp16 MFMA GEMM, fp32 C row-major -------------------
__global__ __launch_bounds__(256)
void gemm128(const half_t* __restrict__ A, const half_t* __restrict__ BT,
             float* __restrict__ C, int N, int K) {
  __shared__ __align__(16) half_t As[128 * 32];
  __shared__ __align__(16) half_t Bs[128 * 32];
  const int tid = threadIdx.x;
  const int lane = tid & 63, wid = tid >> 6;
  const int wm = wid >> 1, wn = wid & 1;
  const int l15 = lane & 15, l4 = lane >> 4;
  const int bm = blockIdx.y * 128, bn = blockIdx.x * 128;
  const int srow = tid >> 2;
  const int skb = (tid & 3) * 8;
  f32x4 acc[4][4] = {};

  half8 va[2], vb[2];
  #pragma unroll
  for (int c = 0; c < 2; ++c) {
    int row = c * 64 + srow;
    va[c] = *(const half8*)(A + (size_t)(bm + row) * K + skb);
    vb[c] = *(const half8*)(BT + (size_t)(bn + row) * K + skb);
  }
  for (int k0 = 0; k0 < K; k0 += 32) {
    __syncthreads();
    #pragma unroll
    for (int c = 0; c < 2; ++c) {
      int row = c * 64 + srow;
      *(half8*)(As + row * 32 + skb) = va[c];
      *(half8*)(Bs + row * 32 + skb) = vb[c];
    }
    __syncthreads();
    int k1 = k0 + 32;
    if (k1 < K) {
      #pragma unroll
      for (int c = 0; c < 2; ++c) {
        int row = c * 64 + srow;
        va[c] = *(const half8*)(A + (size_t)(bm + row) * K + k1 + skb);
        vb[c] = *(const half8*)(BT + (size_t)(bn + row) * K + k1 + skb);
      }
    }
    half8 af[4], bf[4];
    #pragma unroll
    for (int mt = 0; mt < 4; ++mt)
      af[mt] = *(const half8*)(As + (wm * 64 + mt * 16 + l15) * 32 + l4 * 8);
    #pragma unroll
    for (int nt = 0; nt < 4; ++nt)
      bf[nt] = *(const half8*)(Bs + (wn * 64 + nt * 16 + l15) * 32 + l4 * 8);
    #pragma unroll
    for (int mt = 0; mt < 4; ++mt)
      #pragma unroll
      for (int nt = 0; nt < 4; ++nt)
        acc[mt][nt] = __builtin_amdgcn_mfma_f32_16x16x32_f16(af[mt], bf[nt], acc[mt][nt], 0, 0, 0);
  }
  #pragma unroll
  for (int mt = 0; mt < 4; ++mt)
    #pragma unroll
    for (int nt = 0; nt < 4; ++nt) {
      int col = bn + wn * 64 + nt * 16 + l15;
      int row0 = bm + wm * 64 + mt * 16 + l4 * 4;
      #pragma unroll
      for (int r = 0; r < 4; ++r)
        C[(size_t)(row0 + r) * N + col] = acc[mt][nt][r];
    }
}

// ---------------- fused 2-layer persistent GRU recurrence --------------------
// 192 WGs. WGs 0..63 = layer0 (g=w>>5, uslot=w&31, units j0=uslot*32..+31),
// K-concat [h0(1024); e(256)] vs T0=[U0;W0]^T. WGs 64..191 = layer1
// (g=(w-64)>>6, uslot=(w-64)&63, units j0=uslot*16..+15), K-concat
// [h0(1024); h1(1024)] vs T1=[W1;U1]^T, 1 epoch behind.
// h0f 6-buffered (e%6), h1f 4-buffered; sc0/sc1 write-through publish +
// forced-miss loads. Flags are REPLICATED x4 (one replica per polling wave)
// and 16B-strided (one flag per lane, spread over many L3 lines/banks) to
// avoid hot-line serialization. flag0=e+1 <=> h0[e] published; flag1=e <=>
// h1[e-1] published. L0 WAR (overwrite h0[e-6]) gated by flags1 >= e-5,
// checked by lanes 32..63 in the same poll. L1 self-WAR implied by data poll.
#define MF(af, bf, a) a = __builtin_amdgcn_mfma_f32_16x16x32_f16(af, bf, a, 0, 0, 0)
#define BC8(x) __builtin_bit_cast(half8, x)
#define GLD4(dst, base, OFS) asm volatile("global_load_dwordx4 %0, %1, off offset:" OFS " sc0 sc1" : "=v"(dst) : "v"(base))
#define GLD4P(dst, base, OFS) asm volatile("global_load_dwordx4 %0, %1, off offset:" OFS : "=v"(dst) : "v"(base))
#define HL8(t, B) GLD4(hrA[t][0],B,"0");GLD4(hrA[t][1],B,"64");GLD4(hrA[t][2],B,"128");GLD4(hrA[t][3],B,"192");GLD4(hrA[t][4],B,"256");GLD4(hrA[t][5],B,"320");GLD4(hrA[t][6],B,"384");GLD4(hrA[t][7],B,"448")
#define HL16(t, B) HL8(t,B);GLD4(hrA[t][8],B,"512");GLD4(hrA[t][9],B,"576");GLD4(hrA[t][10],B,"640");GLD4(hrA[t][11],B,"704");GLD4(hrA[t][12],B,"768");GLD4(hrA[t][13],B,"832");GLD4(hrA[t][14],B,"896");GLD4(hrA[t][15],B,"960")
#define LDH0(u, kt) (*(const half8*)(smem + ((((u) * 2048) + wv * 512 + (kt) * 64 + l4x16) ^ (((u) & 7) << 4))))
#define LDE0(u, kt) (*(const half8*)(smem + 65536 + ((((u) * 512) + wv * 128 + (kt) * 64 + l4x16) ^ (((u) & 7) << 4))))
#define LDH1(kt) (*(const half8*)(smem + ((l15 * 4096 + wv * 1024 + (kt) * 64 + l4x16) ^ ((l15 & 7) << 4))))
#define POLL(fp, tgt) { int f_; while (true) { \
    asm volatile("global_load_dword %0, %1, off sc0 sc1\n\ts_waitcnt vmcnt(0)" \
                 : "=v"(f_) : "v"(fp) : "memory"); \
    if (__all(f_ >= (tgt))) break; \
    __builtin_amdgcn_s_sleep(2); } }

__global__ __launch_bounds__(256, 1)
void recur_fused(const half_t* __restrict__ E16,  // [32768][256]
                 const half_t* __restrict__ T0,   // [3072][1280] = [U0;W0]^T
                 const half_t* __restrict__ T1,   // [3072][2048] = [W1;U1]^T
                 const float* __restrict__ bias0, // [2][3072]
                 const float* __restrict__ bias1, // [2][3072]
                 half_t* __restrict__ ys1,        // [32768][1024]
                 half_t* __restrict__ h0f,        // [6][64][1024] half
                 half_t* __restrict__ h1f,        // [4][64][1024] half
                 int* __restrict__ flags0,        // [4 rep][64 WG][4] (16B stride)
                 int* __restrict__ flags1) {      // [4 rep][128 WG][4]
  extern __shared__ unsigned char smem[];
  const int tid = threadIdx.x;
  const int lane = tid & 63, wv = tid >> 6;
  const int l15 = lane & 15, l4 = lane >> 4;
  const int l4x16 = l4 * 16;
  const int ug = tid >> 5;          // 0..7
  const int bl = lane & 31;         // batch within group

  if (blockIdx.x < 64) {
    // =================== LAYER 0 ===================
    const int w = blockIdx.x;
    const int g = w >> 5, uslot = w & 31, j0 = uslot * 32;
    float* hgp = (float*)(smem + 81920);   // [4][32][129]

    // stage h-part hh rows (32 units x 1024), XOR-swizzled
    for (int it = 0; it < 16; ++it) {
      int idx = it * 256 + tid;
      int u = idx >> 7, kc = idx & 127;
      int byteoff = (u * 2048 + kc * 16) ^ ((u & 7) << 4);
      *(half8*)(smem + byteoff) =
          *(const half8*)(T0 + (size_t)(2048 + j0 + u) * 1280 + kc * 8);
    }
    // stage e-part hh rows (32 units x 256)
    for (int it = 0; it < 4; ++it) {
      int idx = it * 256 + tid;
      int u = idx >> 5, kc = idx & 31;
      int byteoff = 65536 + ((u * 512 + kc * 16) ^ ((u & 7) << 4));
      *(half8*)(smem + byteoff) =
          *(const half8*)(T0 + (size_t)(2048 + j0 + u) * 1280 + 1024 + kc * 8);
    }
    // pin z,r B-frags: h-part and e-part
    half8 zr[2][2][8], ezr[2][2][2];
    #pragma unroll
    for (int gate = 0; gate < 2; ++gate)
      #pragma unroll
      for (int uh = 0; uh < 2; ++uh) {
        const half_t* row = T0 + (size_t)(gate * 1024 + j0 + uh * 16 + l15) * 1280;
        #pragma unroll
        for (int kt = 0; kt < 8; ++kt)
          zr[gate][uh][kt] = *(const half8*)(row + wv * 256 + kt * 32 + l4 * 8);
        #pragma unroll
        for (int kt = 0; kt < 2; ++kt)
          ezr[gate][uh][kt] = *(const half8*)(row + 1024 + wv * 64 + kt * 32 + l4 * 8);
      }
    // gate constants + master h in regs
    float bz[4], br[4], bhr[4], bxh[4], hM[4];
    #pragma unroll
    for (int q = 0; q < 4; ++q) {
      int j = j0 + ug * 4 + q;
      bz[q]  = bias0[j]        + bias0[3072 + j];
      br[q]  = bias0[1024 + j] + bias0[4096 + j];
      bxh[q] = bias0[2048 + j];
      bhr[q] = bias0[5120 + j];
      hM[q] = 0.f;
    }
    // poll addresses: lanes<32 -> own-group flags0 replica wv (data dep);
    // lanes>=32 -> flags1 quarter (WAR slack-5)
    const int* fp = (lane < 32)
        ? flags0 + (wv * 64 + g * 32 + bl) * 4
        : flags1 + (wv * 128 + g * 64 + wv * 16 + (lane & 15)) * 4;
    __syncthreads();

    for (int e = 0; e < 512; ++e) {
      int tgt = (lane < 32) ? e : (e - 5);
      POLL(fp, tgt);
      // A loads: h0[e-1] (buf (e+5)%6, sc forced-miss) + e_t (plain)
      f32x4 hrA[2][8], erA[2][2];
      {
        const char* hbb = (const char*)h0f + (size_t)((e + 5) % 6) * 131072;
        const char* hb0 = hbb + (g * 32 + l15) * 2048 + wv * 512 + l4x16;
        const char* hb1 = hb0 + 32768;
        HL8(0, hb0); HL8(1, hb1);
        const char* eb0 = (const char*)E16 +
            (size_t)(e * 64 + g * 32 + l15) * 512 + wv * 128 + l4x16;
        const char* eb1 = eb0 + 8192;
        GLD4P(erA[0][0], eb0, "0"); GLD4P(erA[0][1], eb0, "64");
        GLD4P(erA[1][0], eb1, "0"); GLD4P(erA[1][1], eb1, "64");
      }
      asm volatile("s_waitcnt vmcnt(0)" ::: "memory");
      __builtin_amdgcn_sched_barrier(0);

      // MFMA: h-part 8 kt x 12 + e-part 2 kt x 12 = 120
      f32x4 acc[2][8] = {};
      #pragma unroll
      for (int kt = 0; kt < 8; ++kt) {
        half8 af0 = BC8(hrA[0][kt]), af1 = BC8(hrA[1][kt]);
        MF(af0, zr[0][0][kt], acc[0][0]); MF(af1, zr[0][0][kt], acc[1][0]);
        MF(af0, zr[0][1][kt], acc[0][1]); MF(af1, zr[0][1][kt], acc[1][1]);
        MF(af0, zr[1][0][kt], acc[0][2]); MF(af1, zr[1][0][kt], acc[1][2]);
        MF(af0, zr[1][1][kt], acc[0][3]); MF(af1, zr[1][1][kt], acc[1][3]);
        half8 bh0 = LDH0(l15, kt), bh1 = LDH0(16 + l15, kt);
        MF(af0, bh0, acc[0][4]); MF(af1, bh0, acc[1][4]);
        MF(af0, bh1, acc[0][5]); MF(af1, bh1, acc[1][5]);
      }
      #pragma unroll
      for (int kt = 0; kt < 2; ++kt) {
        half8 af0 = BC8(erA[0][kt]), af1 = BC8(erA[1][kt]);
        MF(af0, ezr[0][0][kt], acc[0][0]); MF(af1, ezr[0][0][kt], acc[1][0]);
        MF(af0, ezr[0][1][kt], acc[0][1]); MF(af1, ezr[0][1][kt], acc[1][1]);
        MF(af0, ezr[1][0][kt], acc[0][2]); MF(af1, ezr[1][0][kt], acc[1][2]);
        MF(af0, ezr[1][1][kt], acc[0][3]); MF(af1, ezr[1][1][kt], acc[1][3]);
        half8 be0 = LDE0(l15, kt), be1 = LDE0(16 + l15, kt);
        MF(af0, be0, acc[0][6]); MF(af1, be0, acc[1][6]);
        MF(af0, be1, acc[0][7]); MF(af1, be1, acc[1][7]);
      }
      // scatter partials: rows = kv*32 + batch, cols: z0..31|r|hh_h|hh_e
      #pragma unroll
      for (int m = 0; m < 2; ++m)
        #pragma unroll
        for (int n = 0; n < 8; ++n) {
          int colb = (n < 6) ? ((n >> 1) * 32 + (n & 1) * 16) : (96 + (n & 1) * 16);
          #pragma unroll
          for (int r = 0; r < 4; ++r)
            hgp[(wv * 32 + m * 16 + l4 * 4 + r) * 129 + colb + l15] = acc[m][n][r];
        }
      __syncthreads();
      // combine (thread = batch bl x 4 units)
      half4 hv;
      #pragma unroll
      for (int q = 0; q < 4; ++q) {
        int c = ug * 4 + q;
        float hz = 0.f, hr = 0.f, hhh = 0.f, xh = 0.f;
        #pragma unroll
        for (int kv = 0; kv < 4; ++kv) {
          const float* rowp = hgp + (kv * 32 + bl) * 129 + c;
          hz += rowp[0]; hr += rowp[32]; hhh += rowp[64]; xh += rowp[96];
        }
        float z = 1.f / (1.f + __expf(-(hz + bz[q])));
        float r = 1.f / (1.f + __expf(-(hr + br[q])));
        float targ = xh + bxh[q] + r * (hhh + bhr[q]);
        float hh = 1.f - 2.f / (1.f + __expf(2.f * targ));
        float hnew = z * hM[q] + (1.f - z) * hh;
        hM[q] = hnew;
        hv[q] = (half_t)hnew;
      }
      // publish h0[e] -> buf e%6
      {
        const char* dst = (const char*)h0f + (size_t)(e % 6) * 131072
                        + (g * 32 + bl) * 2048 + (j0 + ug * 4) * 2;
        f32x2 pv = __builtin_bit_cast(f32x2, hv);
        asm volatile("global_store_dwordx2 %0, %1, off sc0 sc1"
                     :: "v"(dst), "v"(pv) : "memory");
      }
      asm volatile("s_waitcnt vmcnt(0)" ::: "memory");
      __syncthreads();
      if (tid < 4) {
        int tv = e + 1;
        const int* dst = flags0 + (tid * 64 + w) * 4;
        asm volatile("global_store_dword %0, %1, off sc0 sc1"
                     :: "v"(dst), "v"(tv) : "memory");
      }
    }
  } else {
    // =================== LAYER 1 ===================
    const int wp = blockIdx.x - 64;
    const int g = wp >> 6, uslot = wp & 63, j0 = uslot * 16;
    float* hgp = (float*)(smem + 65536);   // [4][32][65]

    // stage hh rows (16 units x 2048), XOR-swizzled
    for (int it = 0; it < 16; ++it) {
      int idx = it * 256 + tid;
      int u = idx >> 8, kc = idx & 255;
      int byteoff = (u * 4096 + kc * 16) ^ ((u & 7) << 4);
      *(half8*)(smem + byteoff) =
          *(const half8*)(T1 + (size_t)(2048 + j0 + u) * 2048 + kc * 8);
    }
    // pin z,r B-frags over this wave's 512-k slice
    half8 zr1[2][16];
    #pragma unroll
    for (int gate = 0; gate < 2; ++gate) {
      const half_t* row = T1 + (size_t)(gate * 1024 + j0 + l15) * 2048 + wv * 512;
      #pragma unroll
      for (int kt = 0; kt < 16; ++kt)
        zr1[gate][kt] = *(const half8*)(row + kt * 32 + l4 * 8);
    }
    float bz[2], br[2], bhr[2], bxh[2], hM[2];
    #pragma unroll
    for (int q = 0; q < 2; ++q) {
      int j = j0 + ug * 2 + q;
      bz[q]  = bias1[j]        + bias1[3072 + j];
      br[q]  = bias1[1024 + j] + bias1[4096 + j];
      bxh[q] = bias1[2048 + j];
      bhr[q] = bias1[5120 + j];
      hM[q] = 0.f;
    }
    // poll addresses: waves 0,1 -> flags0 (replicas 0,1); waves 2,3 -> flags1
    const int* fp = (wv < 2)
        ? flags0 + (wv * 64 + g * 32 + bl) * 4
        : flags1 + (wv * 128 + g * 64 + lane) * 4;
    __syncthreads();

    for (int e = 1; e <= 512; ++e) {
      int tgt = (wv < 2) ? e : (e - 1);
      POLL(fp, tgt);
      // A loads: waves 0,1 from h0[e-1] (buf (e+5)%6); waves 2,3 from h1[e-2]
      f32x4 hrA[2][16];
      {
        const char* fb = (wv < 2)
            ? (const char*)h0f + (size_t)((e + 5) % 6) * 131072
            : (const char*)h1f + (size_t)((e + 2) & 3) * 131072;
        const char* b0 = fb + (g * 32 + l15) * 2048 + (wv & 1) * 1024 + l4x16;
        const char* b1 = b0 + 32768;
        HL16(0, b0); HL16(1, b1);
      }
      asm volatile("s_waitcnt vmcnt(0)" ::: "memory");
      __builtin_amdgcn_sched_barrier(0);

      // MFMA: 16 kt x 6 = 96
      f32x4 acc[2][3] = {};
      #pragma unroll
      for (int kt = 0; kt < 16; ++kt) {
        half8 af0 = BC8(hrA[0][kt]), af1 = BC8(hrA[1][kt]);
        MF(af0, zr1[0][kt], acc[0][0]); MF(af1, zr1[0][kt], acc[1][0]);
        MF(af0, zr1[1][kt], acc[0][1]); MF(af1, zr1[1][kt], acc[1][1]);
        half8 bh = LDH1(kt);
        MF(af0, bh, acc[0][2]); MF(af1, bh, acc[1][2]);
      }
      // scatter: cols z:0..15, r:16..31, hh_h:32..47 (wv>=2), hh_x:48..63 (wv<2)
      {
        int hhcol = (wv < 2) ? 48 : 32;
        #pragma unroll
        for (int m = 0; m < 2; ++m)
          #pragma unroll
          for (int r = 0; r < 4; ++r) {
            int row = (wv * 32 + m * 16 + l4 * 4 + r) * 65;
            hgp[row + l15]        = acc[m][0][r];
            hgp[row + 16 + l15]   = acc[m][1][r];
            hgp[row + hhcol + l15] = acc[m][2][r];
          }
      }
      __syncthreads();
      // combine (thread = batch bl x 2 units)
      half2 hv;
      #pragma unroll
      for (int q = 0; q < 2; ++q) {
        int c = ug * 2 + q;
        float hz = 0.f, hr = 0.f;
        #pragma unroll
        for (int kv = 0; kv < 4; ++kv) {
          const float* rowp = hgp + (kv * 32 + bl) * 65 + c;
          hz += rowp[0]; hr += rowp[16];
        }
        float hhh = hgp[(2 * 32 + bl) * 65 + 32 + c] + hgp[(3 * 32 + bl) * 65 + 32 + c];
        float xh  = hgp[(0 * 32 + bl) * 65 + 48 + c] + hgp[(1 * 32 + bl) * 65 + 48 + c];
        float z = 1.f / (1.f + __expf(-(hz + bz[q])));
        float r = 1.f / (1.f + __expf(-(hr + br[q])));
        float targ = xh + bxh[q] + r * (hhh + bhr[q]);
        float hh = 1.f - 2.f / (1.f + __expf(2.f * targ));
        float hnew = z * hM[q] + (1.f - z) * hh;
        hM[q] = hnew;
        hv[q] = (half_t)hnew;
      }
      // output + publish h1[e-1] -> buf (e-1)&3
      *(half2*)(ys1 + ((size_t)(e - 1) * 64 + g * 32 + bl) * 1024 + j0 + ug * 2) = hv;
      {
        const char* dst = (const char*)h1f + (size_t)((e + 3) & 3) * 131072
                        + (g * 32 + bl) * 2048 + (j0 + ug * 2) * 2;
        float pv = __builtin_bit_cast(float, hv);
        asm volatile("global_store_dword %0, %1, off sc0 sc1"
                     :: "v"(dst), "v"(pv) : "memory");
      }
      asm volatile("s_waitcnt vmcnt(0)" ::: "memory");
      __syncthreads();
      if (tid < 4) {
        int tv = e;
        const int* dst = flags1 + (tid * 128 + wp) * 4;
        asm volatile("global_store_dword %0, %1, off sc0 sc1"
                     :: "v"(dst), "v"(tv) : "memory");
      }
    }
  }
}

// ---------------- softmax over 256 vocab (one wave per row) -------------------
__global__ __launch_bounds__(256)
void softmax_kernel(const float* __restrict__ logits, const float* __restrict__ bd,
                    float* __restrict__ out) {
  int w = threadIdx.x >> 6, lane = threadIdx.x & 63;
  int m = blockIdx.x * 4 + w;          // m = s*64 + b
  const float* lrow = logits + (size_t)m * 256;
  float v[4];
  #pragma unroll
  for (int i = 0; i < 4; ++i) v[i] = lrow[lane + i * 64] + bd[lane + i * 64];
  float mx = fmaxf(fmaxf(v[0], v[1]), fmaxf(v[2], v[3]));
  #pragma unroll
  for (int off = 32; off; off >>= 1) mx = fmaxf(mx, __shfl_xor(mx, off));
  float s = 0.f;
  #pragma unroll
  for (int i = 0; i < 4; ++i) { v[i] = __expf(v[i] - mx); s += v[i]; }
  #pragma unroll
  for (int off = 32; off; off >>= 1) s += __shfl_xor(s, off);
  float inv = 1.f / s;
  int b = m & 63, sq = m >> 6;
  float* orow = out + ((size_t)b * 512 + sq) * 256;
  #pragma unroll
  for (int i = 0; i < 4; ++i) orow[lane + i * 64] = v[i] * inv;
}

// ---------------- launch ------------------------------------------------------
extern "C" void kernel_launch(void* const* d_in, const int* in_sizes, int n_in,
                              void* d_out, int out_size, void* d_ws, size_t ws_size,
                              hipStream_t stream) {
  const int*   x   = (const int*)d_in[0];
  const float* emb = (const float*)d_in[1];
  const float* W0  = (const float*)d_in[2];
  const float* U0  = (const float*)d_in[3];
  const float* b0  = (const float*)d_in[4];
  const float* W1  = (const float*)d_in[5];
  const float* U1  = (const float*)d_in[6];
  const float* b1  = (const float*)d_in[7];
  const float* Wd  = (const float*)d_in[8];
  const float* bd  = (const float*)d_in[9];
  float* out = (float*)d_out;
  (void)in_sizes; (void)n_in; (void)out_size; (void)ws_size;

  char* p = (char*)d_ws;
  size_t off = 0;
  auto take = [&](size_t bytes) {
    char* r = p + off;
    off = (off + bytes + 255) & ~(size_t)255;
    return r;
  };
  half_t* T0  = (half_t*)take(3072ull * 1280 * 2);   // [U0;W0]^T
  half_t* T1  = (half_t*)take(3072ull * 2048 * 2);   // [W1;U1]^T
  half_t* WdT = (half_t*)take(256ull * 1024 * 2);
  const size_t H0B = 6ull * 131072, H1B = 4ull * 131072;
  const size_t F0B = 4096, F1B = 8192;
  char* stateblk = take(H0B + H1B + F0B + F1B);
  half_t* h0f   = (half_t*)stateblk;
  half_t* h1f   = (half_t*)(stateblk + H0B);
  int*    flags0 = (int*)(stateblk + H0B + H1B);
  int*    flags1 = (int*)(stateblk + H0B + H1B + F0B);
  half_t* E16 = (half_t*)take(32768ull * 256 * 2);
  half_t* ys1 = (half_t*)take(32768ull * 1024 * 2);
  float* logits = (float*)take(32768ull * 256 * 4);

  // weight transposes fp32->fp16 into concat layouts
  wt_transpose<<<dim3(96, 32), dim3(32, 8), 0, stream>>>(U0, T0, 1024, 3072, 1280, 0);
  wt_transpose<<<dim3(96, 8),  dim3(32, 8), 0, stream>>>(W0, T0, 256,  3072, 1280, 1024);
  wt_transpose<<<dim3(96, 32), dim3(32, 8), 0, stream>>>(W1, T1, 1024, 3072, 2048, 0);
  wt_transpose<<<dim3(96, 32), dim3(32, 8), 0, stream>>>(U1, T1, 1024, 3072, 2048, 1024);
  wt_transpose<<<dim3(8, 32),  dim3(32, 8), 0, stream>>>(Wd, WdT, 1024, 256, 1024, 0);
  embed_kernel<<<4096, 256, 0, stream>>>(x, emb, E16);

  hipFuncSetAttribute((const void*)recur_fused,
                      hipFuncAttributeMaxDynamicSharedMemorySize, 147968);
  hipMemsetAsync(stateblk, 0, H0B + H1B + F0B + F1B, stream);

  recur_fused<<<192, 256, 147968, stream>>>(E16, T0, T1, b0, b1, ys1,
                                            h0f, h1f, flags0, flags1);

  gemm128<<<dim3(2, 256), 256, 0, stream>>>(ys1, WdT, logits, 256, 1024);
  softmax_kernel<<<8192, 256, 0, stream>>>(logits, bd, out);
}

// Round 10
// 3775.057 us; speedup vs baseline: 4.0373x; 1.0098x over previous
//
#include <hip/hip_runtime.h>

typedef _Float16 half_t;
typedef _Float16 half8 __attribute__((ext_vector_type(8)));
typedef _Float16 half4 __attribute__((ext_vector_type(4)));
typedef _Float16 half2 __attribute__((ext_vector_type(2)));
typedef float f32x4 __attribute__((ext_vector_type(4)));
typedef float f32x2 __attribute__((ext_vector_type(2)));

// ---------------- fp32 [K][N] -> fp16 [N rows][ldo] transpose (col offset) ---
__global__ void wt_transpose(const float* __restrict__ in, half_t* __restrict__ outp,
                             int K, int N, int ldo, int co) {
  __shared__ float tile[32][33];
  int nb = blockIdx.x * 32, kb = blockIdx.y * 32;
  int tx = threadIdx.x, ty = threadIdx.y;  // 32 x 8
  for (int i = ty; i < 32; i += 8)
    tile[i][tx] = in[(size_t)(kb + i) * N + nb + tx];
  __syncthreads();
  for (int i = ty; i < 32; i += 8)
    outp[(size_t)(nb + i) * ldo + co + kb + tx] = (half_t)tile[tx][i];
}

// ---------------- embedding gather -> fp16 row-major [m=s*64+b][256] ---------
__global__ __launch_bounds__(256) void embed_kernel(const int* __restrict__ x,
    const float* __restrict__ emb, half_t* __restrict__ E) {
  int g = blockIdx.x * 256 + threadIdx.x;  // 0 .. 32768*32-1
  int m = g >> 5, dp = g & 31;
  int b = m & 63, s = m >> 6;
  int tok = x[b * 512 + s];
  const float* src = emb + (size_t)tok * 256 + dp * 8;
  half8 v;
  #pragma unroll
  for (int i = 0; i < 8; ++i) v[i] = (half_t)src[i];
  *(half8*)(E + (size_t)m * 256 + dp * 8) = v;
}

// ---------------- 128x128 fp16 MFMA GEMM, fp32 C row-major -------------------
__global__ __launch_bounds__(256)
void gemm128(const half_t* __restrict__ A, const half_t* __restrict__ BT,
             float* __restrict__ C, int N, int K) {
  __shared__ __align__(16) half_t As[128 * 32];
  __shared__ __align__(16) half_t Bs[128 * 32];
  const int tid = threadIdx.x;
  const int lane = tid & 63, wid = tid >> 6;
  const int wm = wid >> 1, wn = wid & 1;
  const int l15 = lane & 15, l4 = lane >> 4;
  const int bm = blockIdx.y * 128, bn = blockIdx.x * 128;
  const int srow = tid >> 2;
  const int skb = (tid & 3) * 8;
  f32x4 acc[4][4] = {};

  half8 va[2], vb[2];
  #pragma unroll
  for (int c = 0; c < 2; ++c) {
    int row = c * 64 + srow;
    va[c] = *(const half8*)(A + (size_t)(bm + row) * K + skb);
    vb[c] = *(const half8*)(BT + (size_t)(bn + row) * K + skb);
  }
  for (int k0 = 0; k0 < K; k0 += 32) {
    __syncthreads();
    #pragma unroll
    for (int c = 0; c < 2; ++c) {
      int row = c * 64 + srow;
      *(half8*)(As + row * 32 + skb) = va[c];
      *(half8*)(Bs + row * 32 + skb) = vb[c];
    }
    __syncthreads();
    int k1 = k0 + 32;
    if (k1 < K) {
      #pragma unroll
      for (int c = 0; c < 2; ++c) {
        int row = c * 64 + srow;
        va[c] = *(const half8*)(A + (size_t)(bm + row) * K + k1 + skb);
        vb[c] = *(const half8*)(BT + (size_t)(bn + row) * K + k1 + skb);
      }
    }
    half8 af[4], bf[4];
    #pragma unroll
    for (int mt = 0; mt < 4; ++mt)
      af[mt] = *(const half8*)(As + (wm * 64 + mt * 16 + l15) * 32 + l4 * 8);
    #pragma unroll
    for (int nt = 0; nt < 4; ++nt)
      bf[nt] = *(const half8*)(Bs + (wn * 64 + nt * 16 + l15) * 32 + l4 * 8);
    #pragma unroll
    for (int mt = 0; mt < 4; ++mt)
      #pragma unroll
      for (int nt = 0; nt < 4; ++nt)
        acc[mt][nt] = __builtin_amdgcn_mfma_f32_16x16x32_f16(af[mt], bf[nt], acc[mt][nt], 0, 0, 0);
  }
  #pragma unroll
  for (int mt = 0; mt < 4; ++mt)
    #pragma unroll
    for (int nt = 0; nt < 4; ++nt) {
      int col = bn + wn * 64 + nt * 16 + l15;
      int row0 = bm + wm * 64 + mt * 16 + l4 * 4;
      #pragma unroll
      for (int r = 0; r < 4; ++r)
        C[(size_t)(row0 + r) * N + col] = acc[mt][nt][r];
    }
}

// ---------------- fused 2-layer persistent GRU recurrence --------------------
// Identical sync protocol to the round-7 PASSING kernel (flags replicated x4,
// 16B-strided; sc0/sc1 write-through publish + vmcnt(0) drain + flag store;
// forced-miss consumer loads). Changes vs round 7: (1) E16 inputs for epoch
// e+1 are prefetched during epoch e (removes one RTT from the serial ring);
// (2) s_setprio(1) around MFMA clusters.
#define MF(af, bf, a) a = __builtin_amdgcn_mfma_f32_16x16x32_f16(af, bf, a, 0, 0, 0)
#define BC8(x) __builtin_bit_cast(half8, x)
#define GLD4(dst, base, OFS) asm volatile("global_load_dwordx4 %0, %1, off offset:" OFS " sc0 sc1" : "=v"(dst) : "v"(base))
#define GLD4P(dst, base, OFS) asm volatile("global_load_dwordx4 %0, %1, off offset:" OFS : "=v"(dst) : "v"(base))
#define HL8(t, B) GLD4(hrA[t][0],B,"0");GLD4(hrA[t][1],B,"64");GLD4(hrA[t][2],B,"128");GLD4(hrA[t][3],B,"192");GLD4(hrA[t][4],B,"256");GLD4(hrA[t][5],B,"320");GLD4(hrA[t][6],B,"384");GLD4(hrA[t][7],B,"448")
#define HL16(t, B) HL8(t,B);GLD4(hrA[t][8],B,"512");GLD4(hrA[t][9],B,"576");GLD4(hrA[t][10],B,"640");GLD4(hrA[t][11],B,"704");GLD4(hrA[t][12],B,"768");GLD4(hrA[t][13],B,"832");GLD4(hrA[t][14],B,"896");GLD4(hrA[t][15],B,"960")
#define LDH0(u, kt) (*(const half8*)(smem + ((((u) * 2048) + wv * 512 + (kt) * 64 + l4x16) ^ (((u) & 7) << 4))))
#define LDE0(u, kt) (*(const half8*)(smem + 65536 + ((((u) * 512) + wv * 128 + (kt) * 64 + l4x16) ^ (((u) & 7) << 4))))
#define LDH1(kt) (*(const half8*)(smem + ((l15 * 4096 + wv * 1024 + (kt) * 64 + l4x16) ^ ((l15 & 7) << 4))))
#define POLL(fp, tgt) { int f_; while (true) { \
    asm volatile("global_load_dword %0, %1, off sc0 sc1\n\ts_waitcnt vmcnt(0)" \
                 : "=v"(f_) : "v"(fp) : "memory"); \
    if (__all(f_ >= (tgt))) break; \
    __builtin_amdgcn_s_sleep(2); } }

__global__ __launch_bounds__(256, 1)
void recur_fused(const half_t* __restrict__ E16,  // [32768][256]
                 const half_t* __restrict__ T0,   // [3072][1280] = [U0;W0]^T
                 const half_t* __restrict__ T1,   // [3072][2048] = [W1;U1]^T
                 const float* __restrict__ bias0, // [2][3072]
                 const float* __restrict__ bias1, // [2][3072]
                 half_t* __restrict__ ys1,        // [32768][1024]
                 half_t* __restrict__ h0f,        // [6][64][1024] half
                 half_t* __restrict__ h1f,        // [4][64][1024] half
                 int* __restrict__ flags0,        // [4 rep][64 WG][4] (16B stride)
                 int* __restrict__ flags1) {      // [4 rep][128 WG][4]
  extern __shared__ unsigned char smem[];
  const int tid = threadIdx.x;
  const int lane = tid & 63, wv = tid >> 6;
  const int l15 = lane & 15, l4 = lane >> 4;
  const int l4x16 = l4 * 16;
  const int ug = tid >> 5;          // 0..7
  const int bl = lane & 31;         // batch within group

  if (blockIdx.x < 64) {
    // =================== LAYER 0 ===================
    const int w = blockIdx.x;
    const int g = w >> 5, uslot = w & 31, j0 = uslot * 32;
    float* hgp = (float*)(smem + 81920);   // [4][32][129]

    // stage h-part hh rows (32 units x 1024), XOR-swizzled
    for (int it = 0; it < 16; ++it) {
      int idx = it * 256 + tid;
      int u = idx >> 7, kc = idx & 127;
      int byteoff = (u * 2048 + kc * 16) ^ ((u & 7) << 4);
      *(half8*)(smem + byteoff) =
          *(const half8*)(T0 + (size_t)(2048 + j0 + u) * 1280 + kc * 8);
    }
    // stage e-part hh rows (32 units x 256)
    for (int it = 0; it < 4; ++it) {
      int idx = it * 256 + tid;
      int u = idx >> 5, kc = idx & 31;
      int byteoff = 65536 + ((u * 512 + kc * 16) ^ ((u & 7) << 4));
      *(half8*)(smem + byteoff) =
          *(const half8*)(T0 + (size_t)(2048 + j0 + u) * 1280 + 1024 + kc * 8);
    }
    // pin z,r B-frags: h-part and e-part
    half8 zr[2][2][8], ezr[2][2][2];
    #pragma unroll
    for (int gate = 0; gate < 2; ++gate)
      #pragma unroll
      for (int uh = 0; uh < 2; ++uh) {
        const half_t* row = T0 + (size_t)(gate * 1024 + j0 + uh * 16 + l15) * 1280;
        #pragma unroll
        for (int kt = 0; kt < 8; ++kt)
          zr[gate][uh][kt] = *(const half8*)(row + wv * 256 + kt * 32 + l4 * 8);
        #pragma unroll
        for (int kt = 0; kt < 2; ++kt)
          ezr[gate][uh][kt] = *(const half8*)(row + 1024 + wv * 64 + kt * 32 + l4 * 8);
      }
    // gate constants + master h in regs
    float bz[4], br[4], bhr[4], bxh[4], hM[4];
    #pragma unroll
    for (int q = 0; q < 4; ++q) {
      int j = j0 + ug * 4 + q;
      bz[q]  = bias0[j]        + bias0[3072 + j];
      br[q]  = bias0[1024 + j] + bias0[4096 + j];
      bxh[q] = bias0[2048 + j];
      bhr[q] = bias0[5120 + j];
      hM[q] = 0.f;
    }
    // poll addresses: lanes<32 -> own-group flags0 replica wv (data dep);
    // lanes>=32 -> flags1 quarter (WAR slack-5)
    const int* fp = (lane < 32)
        ? flags0 + (wv * 64 + g * 32 + bl) * 4
        : flags1 + (wv * 128 + g * 64 + wv * 16 + (lane & 15)) * 4;
    // E16 prefetch for epoch 0 (plain loads; double-buffered across epochs)
    f32x4 erC[2][2], erN[2][2];
    {
      const char* eb0 = (const char*)E16 + (size_t)(g * 32 + l15) * 512 + wv * 128 + l4x16;
      const char* eb1 = eb0 + 8192;
      GLD4P(erC[0][0], eb0, "0"); GLD4P(erC[0][1], eb0, "64");
      GLD4P(erC[1][0], eb1, "0"); GLD4P(erC[1][1], eb1, "64");
    }
    __syncthreads();

    for (int e = 0; e < 512; ++e) {
      int tgt = (lane < 32) ? e : (e - 5);
      POLL(fp, tgt);
      // A loads: h0[e-1] (buf (e+5)%6, sc forced-miss); E16[e] already in erC.
      // Also issue E16[e+1] prefetch so it overlaps this epoch's drain+compute.
      f32x4 hrA[2][8];
      {
        const char* hbb = (const char*)h0f + (size_t)((e + 5) % 6) * 131072;
        const char* hb0 = hbb + (g * 32 + l15) * 2048 + wv * 512 + l4x16;
        const char* hb1 = hb0 + 32768;
        HL8(0, hb0); HL8(1, hb1);
        int en = (e < 511) ? e + 1 : e;
        const char* eb0 = (const char*)E16 +
            (size_t)(en * 64 + g * 32 + l15) * 512 + wv * 128 + l4x16;
        const char* eb1 = eb0 + 8192;
        GLD4P(erN[0][0], eb0, "0"); GLD4P(erN[0][1], eb0, "64");
        GLD4P(erN[1][0], eb1, "0"); GLD4P(erN[1][1], eb1, "64");
      }
      asm volatile("s_waitcnt vmcnt(0)" ::: "memory");
      __builtin_amdgcn_sched_barrier(0);

      // MFMA: h-part 8 kt x 12 + e-part 2 kt x 12 = 120
      __builtin_amdgcn_s_setprio(1);
      f32x4 acc[2][8] = {};
      #pragma unroll
      for (int kt = 0; kt < 8; ++kt) {
        half8 af0 = BC8(hrA[0][kt]), af1 = BC8(hrA[1][kt]);
        MF(af0, zr[0][0][kt], acc[0][0]); MF(af1, zr[0][0][kt], acc[1][0]);
        MF(af0, zr[0][1][kt], acc[0][1]); MF(af1, zr[0][1][kt], acc[1][1]);
        MF(af0, zr[1][0][kt], acc[0][2]); MF(af1, zr[1][0][kt], acc[1][2]);
        MF(af0, zr[1][1][kt], acc[0][3]); MF(af1, zr[1][1][kt], acc[1][3]);
        half8 bh0 = LDH0(l15, kt), bh1 = LDH0(16 + l15, kt);
        MF(af0, bh0, acc[0][4]); MF(af1, bh0, acc[1][4]);
        MF(af0, bh1, acc[0][5]); MF(af1, bh1, acc[1][5]);
      }
      #pragma unroll
      for (int kt = 0; kt < 2; ++kt) {
        half8 af0 = BC8(erC[0][kt]), af1 = BC8(erC[1][kt]);
        MF(af0, ezr[0][0][kt], acc[0][0]); MF(af1, ezr[0][0][kt], acc[1][0]);
        MF(af0, ezr[0][1][kt], acc[0][1]); MF(af1, ezr[0][1][kt], acc[1][1]);
        MF(af0, ezr[1][0][kt], acc[0][2]); MF(af1, ezr[1][0][kt], acc[1][2]);
        MF(af0, ezr[1][1][kt], acc[0][3]); MF(af1, ezr[1][1][kt], acc[1][3]);
        half8 be0 = LDE0(l15, kt), be1 = LDE0(16 + l15, kt);
        MF(af0, be0, acc[0][6]); MF(af1, be0, acc[1][6]);
        MF(af0, be1, acc[0][7]); MF(af1, be1, acc[1][7]);
      }
      __builtin_amdgcn_s_setprio(0);
      // scatter partials: rows = kv*32 + batch, cols: z0..31|r|hh_h|hh_e
      #pragma unroll
      for (int m = 0; m < 2; ++m)
        #pragma unroll
        for (int n = 0; n < 8; ++n) {
          int colb = (n < 6) ? ((n >> 1) * 32 + (n & 1) * 16) : (96 + (n & 1) * 16);
          #pragma unroll
          for (int r = 0; r < 4; ++r)
            hgp[(wv * 32 + m * 16 + l4 * 4 + r) * 129 + colb + l15] = acc[m][n][r];
        }
      __syncthreads();
      // combine (thread = batch bl x 4 units)
      half4 hv;
      #pragma unroll
      for (int q = 0; q < 4; ++q) {
        int c = ug * 4 + q;
        float hz = 0.f, hr = 0.f, hhh = 0.f, xh = 0.f;
        #pragma unroll
        for (int kv = 0; kv < 4; ++kv) {
          const float* rowp = hgp + (kv * 32 + bl) * 129 + c;
          hz += rowp[0]; hr += rowp[32]; hhh += rowp[64]; xh += rowp[96];
        }
        float z = 1.f / (1.f + __expf(-(hz + bz[q])));
        float r = 1.f / (1.f + __expf(-(hr + br[q])));
        float targ = xh + bxh[q] + r * (hhh + bhr[q]);
        float hh = 1.f - 2.f / (1.f + __expf(2.f * targ));
        float hnew = z * hM[q] + (1.f - z) * hh;
        hM[q] = hnew;
        hv[q] = (half_t)hnew;
      }
      // rotate E16 buffers
      #pragma unroll
      for (int a = 0; a < 2; ++a)
        #pragma unroll
        for (int b2 = 0; b2 < 2; ++b2) erC[a][b2] = erN[a][b2];
      // publish h0[e] -> buf e%6
      {
        const char* dst = (const char*)h0f + (size_t)(e % 6) * 131072
                        + (g * 32 + bl) * 2048 + (j0 + ug * 4) * 2;
        f32x2 pv = __builtin_bit_cast(f32x2, hv);
        asm volatile("global_store_dwordx2 %0, %1, off sc0 sc1"
                     :: "v"(dst), "v"(pv) : "memory");
      }
      asm volatile("s_waitcnt vmcnt(0)" ::: "memory");
      __syncthreads();
      if (tid < 4) {
        int tv = e + 1;
        const int* dst = flags0 + (tid * 64 + w) * 4;
        asm volatile("global_store_dword %0, %1, off sc0 sc1"
                     :: "v"(dst), "v"(tv) : "memory");
      }
    }
  } else {
    // =================== LAYER 1 ===================
    const int wp = blockIdx.x - 64;
    const int g = wp >> 6, uslot = wp & 63, j0 = uslot * 16;
    float* hgp = (float*)(smem + 65536);   // [4][32][65]

    // stage hh rows (16 units x 2048), XOR-swizzled
    for (int it = 0; it < 16; ++it) {
      int idx = it * 256 + tid;
      int u = idx >> 8, kc = idx & 255;
      int byteoff = (u * 4096 + kc * 16) ^ ((u & 7) << 4);
      *(half8*)(smem + byteoff) =
          *(const half8*)(T1 + (size_t)(2048 + j0 + u) * 2048 + kc * 8);
    }
    // pin z,r B-frags over this wave's 512-k slice
    half8 zr1[2][16];
    #pragma unroll
    for (int gate = 0; gate < 2; ++gate) {
      const half_t* row = T1 + (size_t)(gate * 1024 + j0 + l15) * 2048 + wv * 512;
      #pragma unroll
      for (int kt = 0; kt < 16; ++kt)
        zr1[gate][kt] = *(const half8*)(row + kt * 32 + l4 * 8);
    }
    float bz[2], br[2], bhr[2], bxh[2], hM[2];
    #pragma unroll
    for (int q = 0; q < 2; ++q) {
      int j = j0 + ug * 2 + q;
      bz[q]  = bias1[j]        + bias1[3072 + j];
      br[q]  = bias1[1024 + j] + bias1[4096 + j];
      bxh[q] = bias1[2048 + j];
      bhr[q] = bias1[5120 + j];
      hM[q] = 0.f;
    }
    // poll addresses: waves 0,1 -> flags0 (replicas 0,1); waves 2,3 -> flags1
    const int* fp = (wv < 2)
        ? flags0 + (wv * 64 + g * 32 + bl) * 4
        : flags1 + (wv * 128 + g * 64 + lane) * 4;
    __syncthreads();

    for (int e = 1; e <= 512; ++e) {
      int tgt = (wv < 2) ? e : (e - 1);
      POLL(fp, tgt);
      // A loads: waves 0,1 from h0[e-1] (buf (e+5)%6); waves 2,3 from h1[e-2]
      f32x4 hrA[2][16];
      {
        const char* fb = (wv < 2)
            ? (const char*)h0f + (size_t)((e + 5) % 6) * 131072
            : (const char*)h1f + (size_t)((e + 2) & 3) * 131072;
        const char* b0 = fb + (g * 32 + l15) * 2048 + (wv & 1) * 1024 + l4x16;
        const char* b1 = b0 + 32768;
        HL16(0, b0); HL16(1, b1);
      }
      asm volatile("s_waitcnt vmcnt(0)" ::: "memory");
      __builtin_amdgcn_sched_barrier(0);

      // MFMA: 16 kt x 6 = 96
      __builtin_amdgcn_s_setprio(1);
      f32x4 acc[2][3] = {};
      #pragma unroll
      for (int kt = 0; kt < 16; ++kt) {
        half8 af0 = BC8(hrA[0][kt]), af1 = BC8(hrA[1][kt]);
        MF(af0, zr1[0][kt], acc[0][0]); MF(af1, zr1[0][kt], acc[1][0]);
        MF(af0, zr1[1][kt], acc[0][1]); MF(af1, zr1[1][kt], acc[1][1]);
        half8 bh = LDH1(kt);
        MF(af0, bh, acc[0][2]); MF(af1, bh, acc[1][2]);
      }
      __builtin_amdgcn_s_setprio(0);
      // scatter: cols z:0..15, r:16..31, hh_h:32..47 (wv>=2), hh_x:48..63 (wv<2)
      {
        int hhcol = (wv < 2) ? 48 : 32;
        #pragma unroll
        for (int m = 0; m < 2; ++m)
          #pragma unroll
          for (int r = 0; r < 4; ++r) {
            int row = (wv * 32 + m * 16 + l4 * 4 + r) * 65;
            hgp[row + l15]        = acc[m][0][r];
            hgp[row + 16 + l15]   = acc[m][1][r];
            hgp[row + hhcol + l15] = acc[m][2][r];
          }
      }
      __syncthreads();
      // combine (thread = batch bl x 2 units)
      half2 hv;
      #pragma unroll
      for (int q = 0; q < 2; ++q) {
        int c = ug * 2 + q;
        float hz = 0.f, hr = 0.f;
        #pragma unroll
        for (int kv = 0; kv < 4; ++kv) {
          const float* rowp = hgp + (kv * 32 + bl) * 65 + c;
          hz += rowp[0]; hr += rowp[16];
        }
        float hhh = hgp[(2 * 32 + bl) * 65 + 32 + c] + hgp[(3 * 32 + bl) * 65 + 32 + c];
        float xh  = hgp[(0 * 32 + bl) * 65 + 48 + c] + hgp[(1 * 32 + bl) * 65 + 48 + c];
        float z = 1.f / (1.f + __expf(-(hz + bz[q])));
        float r = 1.f / (1.f + __expf(-(hr + br[q])));
        float targ = xh + bxh[q] + r * (hhh + bhr[q]);
        float hh = 1.f - 2.f / (1.f + __expf(2.f * targ));
        float hnew = z * hM[q] + (1.f - z) * hh;
        hM[q] = hnew;
        hv[q] = (half_t)hnew;
      }
      // output + publish h1[e-1] -> buf (e-1)&3
      *(half2*)(ys1 + ((size_t)(e - 1) * 64 + g * 32 + bl) * 1024 + j0 + ug * 2) = hv;
      {
        const char* dst = (const char*)h1f + (size_t)((e + 3) & 3) * 131072
                        + (g * 32 + bl) * 2048 + (j0 + ug * 2) * 2;
        float pv = __builtin_bit_cast(float, hv);
        asm volatile("global_store_dword %0, %1, off sc0 sc1"
                     :: "v"(dst), "v"(pv) : "memory");
      }
      asm volatile("s_waitcnt vmcnt(0)" ::: "memory");
      __syncthreads();
      if (tid < 4) {
        int tv = e;
        const int* dst = flags1 + (tid * 128 + wp) * 4;
        asm volatile("global_store_dword %0, %1, off sc0 sc1"
                     :: "v"(dst), "v"(tv) : "memory");
      }
    }
  }
}

// ---------------- softmax over 256 vocab (one wave per row) -------------------
__global__ __launch_bounds__(256)
void softmax_kernel(const float* __restrict__ logits, const float* __restrict__ bd,
                    float* __restrict__ out) {
  int w = threadIdx.x >> 6, lane = threadIdx.x & 63;
  int m = blockIdx.x * 4 + w;          // m = s*64 + b
  const float* lrow = logits + (size_t)m * 256;
  float v[4];
  #pragma unroll
  for (int i = 0; i < 4; ++i) v[i] = lrow[lane + i * 64] + bd[lane + i * 64];
  float mx = fmaxf(fmaxf(v[0], v[1]), fmaxf(v[2], v[3]));
  #pragma unroll
  for (int off = 32; off; off >>= 1) mx = fmaxf(mx, __shfl_xor(mx, off));
  float s = 0.f;
  #pragma unroll
  for (int i = 0; i < 4; ++i) { v[i] = __expf(v[i] - mx); s += v[i]; }
  #pragma unroll
  for (int off = 32; off; off >>= 1) s += __shfl_xor(s, off);
  float inv = 1.f / s;
  int b = m & 63, sq = m >> 6;
  float* orow = out + ((size_t)b * 512 + sq) * 256;
  #pragma unroll
  for (int i = 0; i < 4; ++i) orow[lane + i * 64] = v[i] * inv;
}

// ---------------- launch ------------------------------------------------------
extern "C" void kernel_launch(void* const* d_in, const int* in_sizes, int n_in,
                              void* d_out, int out_size, void* d_ws, size_t ws_size,
                              hipStream_t stream) {
  const int*   x   = (const int*)d_in[0];
  const float* emb = (const float*)d_in[1];
  const float* W0  = (const float*)d_in[2];
  const float* U0  = (const float*)d_in[3];
  const float* b0  = (const float*)d_in[4];
  const float* W1  = (const float*)d_in[5];
  const float* U1  = (const float*)d_in[6];
  const float* b1  = (const float*)d_in[7];
  const float* Wd  = (const float*)d_in[8];
  const float* bd  = (const float*)d_in[9];
  float* out = (float*)d_out;
  (void)in_sizes; (void)n_in; (void)out_size; (void)ws_size;

  char* p = (char*)d_ws;
  size_t off = 0;
  auto take = [&](size_t bytes) {
    char* r = p + off;
    off = (off + bytes + 255) & ~(size_t)255;
    return r;
  };
  half_t* T0  = (half_t*)take(3072ull * 1280 * 2);   // [U0;W0]^T
  half_t* T1  = (half_t*)take(3072ull * 2048 * 2);   // [W1;U1]^T
  half_t* WdT = (half_t*)take(256ull * 1024 * 2);
  const size_t H0B = 6ull * 131072, H1B = 4ull * 131072;
  const size_t F0B = 4096, F1B = 8192;
  char* stateblk = take(H0B + H1B + F0B + F1B);
  half_t* h0f   = (half_t*)stateblk;
  half_t* h1f   = (half_t*)(stateblk + H0B);
  int*    flags0 = (int*)(stateblk + H0B + H1B);
  int*    flags1 = (int*)(stateblk + H0B + H1B + F0B);
  half_t* E16 = (half_t*)take(32768ull * 256 * 2);
  half_t* ys1 = (half_t*)take(32768ull * 1024 * 2);
  float* logits = (float*)take(32768ull * 256 * 4);

  // weight transposes fp32->fp16 into concat layouts
  wt_transpose<<<dim3(96, 32), dim3(32, 8), 0, stream>>>(U0, T0, 1024, 3072, 1280, 0);
  wt_transpose<<<dim3(96, 8),  dim3(32, 8), 0, stream>>>(W0, T0, 256,  3072, 1280, 1024);
  wt_transpose<<<dim3(96, 32), dim3(32, 8), 0, stream>>>(W1, T1, 1024, 3072, 2048, 0);
  wt_transpose<<<dim3(96, 32), dim3(32, 8), 0, stream>>>(U1, T1, 1024, 3072, 2048, 1024);
  wt_transpose<<<dim3(8, 32),  dim3(32, 8), 0, stream>>>(Wd, WdT, 1024, 256, 1024, 0);
  embed_kernel<<<4096, 256, 0, stream>>>(x, emb, E16);

  hipFuncSetAttribute((const void*)recur_fused,
                      hipFuncAttributeMaxDynamicSharedMemorySize, 147968);
  hipMemsetAsync(stateblk, 0, H0B + H1B + F0B + F1B, stream);

  recur_fused<<<192, 256, 147968, stream>>>(E16, T0, T1, b0, b1, ys1,
                                            h0f, h1f, flags0, flags1);

  gemm128<<<dim3(2, 256), 256, 0, stream>>>(ys1, WdT, logits, 256, 1024);
  softmax_kernel<<<8192, 256, 0, stream>>>(logits, bd, out);
}

// Round 12
// 3567.852 us; speedup vs baseline: 4.2717x; 1.0581x over previous
//
#include <hip/hip_runtime.h>

typedef _Float16 half_t;
typedef _Float16 half8 __attribute__((ext_vector_type(8)));
typedef _Float16 half4 __attribute__((ext_vector_type(4)));
typedef _Float16 half2 __attribute__((ext_vector_type(2)));
typedef float f32x4 __attribute__((ext_vector_type(4)));
typedef float f32x2 __attribute__((ext_vector_type(2)));

// ---------------- fp32 [K][N] -> fp16 [N rows][ldo] transpose (col offset) ---
__global__ void wt_transpose(const float* __restrict__ in, half_t* __restrict__ outp,
                             int K, int N, int ldo, int co) {
  __shared__ float tile[32][33];
  int nb = blockIdx.x * 32, kb = blockIdx.y * 32;
  int tx = threadIdx.x, ty = threadIdx.y;  // 32 x 8
  for (int i = ty; i < 32; i += 8)
    tile[i][tx] = in[(size_t)(kb + i) * N + nb + tx];
  __syncthreads();
  for (int i = ty; i < 32; i += 8)
    outp[(size_t)(nb + i) * ldo + co + kb + tx] = (half_t)tile[tx][i];
}

// ---------------- embedding gather -> fp16 row-major [m=s*64+b][256] ---------
__global__ __launch_bounds__(256) void embed_kernel(const int* __restrict__ x,
    const float* __restrict__ emb, half_t* __restrict__ E) {
  int g = blockIdx.x * 256 + threadIdx.x;  // 0 .. 32768*32-1
  int m = g >> 5, dp = g & 31;
  int b = m & 63, s = m >> 6;
  int tok = x[b * 512 + s];
  const float* src = emb + (size_t)tok * 256 + dp * 8;
  half8 v;
  #pragma unroll
  for (int i = 0; i < 8; ++i) v[i] = (half_t)src[i];
  *(half8*)(E + (size_t)m * 256 + dp * 8) = v;
}

// ---------------- 128x128 fp16 MFMA GEMM, fp32 C row-major -------------------
__global__ __launch_bounds__(256)
void gemm128(const half_t* __restrict__ A, const half_t* __restrict__ BT,
             float* __restrict__ C, int N, int K) {
  __shared__ __align__(16) half_t As[128 * 32];
  __shared__ __align__(16) half_t Bs[128 * 32];
  const int tid = threadIdx.x;
  const int lane = tid & 63, wid = tid >> 6;
  const int wm = wid >> 1, wn = wid & 1;
  const int l15 = lane & 15, l4 = lane >> 4;
  const int bm = blockIdx.y * 128, bn = blockIdx.x * 128;
  const int srow = tid >> 2;
  const int skb = (tid & 3) * 8;
  f32x4 acc[4][4] = {};

  half8 va[2], vb[2];
  #pragma unroll
  for (int c = 0; c < 2; ++c) {
    int row = c * 64 + srow;
    va[c] = *(const half8*)(A + (size_t)(bm + row) * K + skb);
    vb[c] = *(const half8*)(BT + (size_t)(bn + row) * K + skb);
  }
  for (int k0 = 0; k0 < K; k0 += 32) {
    __syncthreads();
    #pragma unroll
    for (int c = 0; c < 2; ++c) {
      int row = c * 64 + srow;
      *(half8*)(As + row * 32 + skb) = va[c];
      *(half8*)(Bs + row * 32 + skb) = vb[c];
    }
    __syncthreads();
    int k1 = k0 + 32;
    if (k1 < K) {
      #pragma unroll
      for (int c = 0; c < 2; ++c) {
        int row = c * 64 + srow;
        va[c] = *(const half8*)(A + (size_t)(bm + row) * K + k1 + skb);
        vb[c] = *(const half8*)(BT + (size_t)(bn + row) * K + k1 + skb);
      }
    }
    half8 af[4], bf[4];
    #pragma unroll
    for (int mt = 0; mt < 4; ++mt)
      af[mt] = *(const half8*)(As + (wm * 64 + mt * 16 + l15) * 32 + l4 * 8);
    #pragma unroll
    for (int nt = 0; nt < 4; ++nt)
      bf[nt] = *(const half8*)(Bs + (wn * 64 + nt * 16 + l15) * 32 + l4 * 8);
    #pragma unroll
    for (int mt = 0; mt < 4; ++mt)
      #pragma unroll
      for (int nt = 0; nt < 4; ++nt)
        acc[mt][nt] = __builtin_amdgcn_mfma_f32_16x16x32_f16(af[mt], bf[nt], acc[mt][nt], 0, 0, 0);
  }
  #pragma unroll
  for (int mt = 0; mt < 4; ++mt)
    #pragma unroll
    for (int nt = 0; nt < 4; ++nt) {
      int col = bn + wn * 64 + nt * 16 + l15;
      int row0 = bm + wm * 64 + mt * 16 + l4 * 4;
      #pragma unroll
      for (int r = 0; r < 4; ++r)
        C[(size_t)(row0 + r) * N + col] = acc[mt][nt][r];
    }
}

// ---------------- fused 2-layer persistent GRU recurrence --------------------
// Sync protocol identical to the round-7/round-10 PASSING kernels (flags
// replicated x4, 16B-strided; sc0/sc1 write-through publish + vmcnt(0) drain +
// barrier + flag store; forced-miss consumer loads). This round's changes:
// (1) cached-flag poll: each lane caches the last (monotone) flag value it
//     read; only laggard lanes reload -> most poll traffic vanishes. Deadman
//     2^14 iters (bug -> fast absmax fail, not a hang).
// (2) counted-vmcnt load/MFMA overlap: MFMA phase split per A-tile so the
//     second half of the h-loads completes under the first MFMA block.
#define MF(af, bf, a) a = __builtin_amdgcn_mfma_f32_16x16x32_f16(af, bf, a, 0, 0, 0)
#define BC8(x) __builtin_bit_cast(half8, x)
#define GLD4(dst, base, OFS) asm volatile("global_load_dwordx4 %0, %1, off offset:" OFS " sc0 sc1" : "=v"(dst) : "v"(base))
#define GLD4P(dst, base, OFS) asm volatile("global_load_dwordx4 %0, %1, off offset:" OFS : "=v"(dst) : "v"(base))
#define HL8(t, B) GLD4(hrA[t][0],B,"0");GLD4(hrA[t][1],B,"64");GLD4(hrA[t][2],B,"128");GLD4(hrA[t][3],B,"192");GLD4(hrA[t][4],B,"256");GLD4(hrA[t][5],B,"320");GLD4(hrA[t][6],B,"384");GLD4(hrA[t][7],B,"448")
#define HL16(t, B) HL8(t,B);GLD4(hrA[t][8],B,"512");GLD4(hrA[t][9],B,"576");GLD4(hrA[t][10],B,"640");GLD4(hrA[t][11],B,"704");GLD4(hrA[t][12],B,"768");GLD4(hrA[t][13],B,"832");GLD4(hrA[t][14],B,"896");GLD4(hrA[t][15],B,"960")
#define LDH0(u, kt) (*(const half8*)(smem + ((((u) * 2048) + wv * 512 + (kt) * 64 + l4x16) ^ (((u) & 7) << 4))))
#define LDE0(u, kt) (*(const half8*)(smem + 65536 + ((((u) * 512) + wv * 128 + (kt) * 64 + l4x16) ^ (((u) & 7) << 4))))
#define LDH1(kt) (*(const half8*)(smem + ((l15 * 4096 + wv * 1024 + (kt) * 64 + l4x16) ^ ((l15 & 7) << 4))))
#define SB __builtin_amdgcn_sched_barrier(0)

// cached-flag poll: fsav is a persistent per-lane cache of the monotone flag.
// Zero memory ops when already satisfied; divergent reload otherwise.
#define POLLC(fp, tgt, fsav) { int dm_ = 0; \
    while (!__all((fsav) >= (tgt))) { \
      if ((fsav) < (tgt)) \
        asm volatile("global_load_dword %0, %1, off sc0 sc1\n\ts_waitcnt vmcnt(0)" \
                     : "=v"(fsav) : "v"(fp) : "memory"); \
      if (++dm_ > (1 << 14)) break; \
    } }

__global__ __launch_bounds__(256, 1)
void recur_fused(const half_t* __restrict__ E16,  // [32768][256]
                 const half_t* __restrict__ T0,   // [3072][1280] = [U0;W0]^T
                 const half_t* __restrict__ T1,   // [3072][2048] = [W1;U1]^T
                 const float* __restrict__ bias0, // [2][3072]
                 const float* __restrict__ bias1, // [2][3072]
                 half_t* __restrict__ ys1,        // [32768][1024]
                 half_t* __restrict__ h0f,        // [6][64][1024] half
                 half_t* __restrict__ h1f,        // [4][64][1024] half
                 int* __restrict__ flags0,        // [4 rep][64 WG][4] (16B stride)
                 int* __restrict__ flags1) {      // [4 rep][128 WG][4]
  extern __shared__ unsigned char smem[];
  const int tid = threadIdx.x;
  const int lane = tid & 63, wv = tid >> 6;
  const int l15 = lane & 15, l4 = lane >> 4;
  const int l4x16 = l4 * 16;
  const int ug = tid >> 5;          // 0..7
  const int bl = lane & 31;         // batch within group

  if (blockIdx.x < 64) {
    // =================== LAYER 0 ===================
    const int w = blockIdx.x;
    const int g = w >> 5, uslot = w & 31, j0 = uslot * 32;
    float* hgp = (float*)(smem + 81920);   // [4][32][129]

    // stage h-part hh rows (32 units x 1024), XOR-swizzled
    for (int it = 0; it < 16; ++it) {
      int idx = it * 256 + tid;
      int u = idx >> 7, kc = idx & 127;
      int byteoff = (u * 2048 + kc * 16) ^ ((u & 7) << 4);
      *(half8*)(smem + byteoff) =
          *(const half8*)(T0 + (size_t)(2048 + j0 + u) * 1280 + kc * 8);
    }
    // stage e-part hh rows (32 units x 256)
    for (int it = 0; it < 4; ++it) {
      int idx = it * 256 + tid;
      int u = idx >> 5, kc = idx & 31;
      int byteoff = 65536 + ((u * 512 + kc * 16) ^ ((u & 7) << 4));
      *(half8*)(smem + byteoff) =
          *(const half8*)(T0 + (size_t)(2048 + j0 + u) * 1280 + 1024 + kc * 8);
    }
    // pin z,r B-frags: h-part and e-part
    half8 zr[2][2][8], ezr[2][2][2];
    #pragma unroll
    for (int gate = 0; gate < 2; ++gate)
      #pragma unroll
      for (int uh = 0; uh < 2; ++uh) {
        const half_t* row = T0 + (size_t)(gate * 1024 + j0 + uh * 16 + l15) * 1280;
        #pragma unroll
        for (int kt = 0; kt < 8; ++kt)
          zr[gate][uh][kt] = *(const half8*)(row + wv * 256 + kt * 32 + l4 * 8);
        #pragma unroll
        for (int kt = 0; kt < 2; ++kt)
          ezr[gate][uh][kt] = *(const half8*)(row + 1024 + wv * 64 + kt * 32 + l4 * 8);
      }
    // gate constants + master h in regs
    float bz[4], br[4], bhr[4], bxh[4], hM[4];
    #pragma unroll
    for (int q = 0; q < 4; ++q) {
      int j = j0 + ug * 4 + q;
      bz[q]  = bias0[j]        + bias0[3072 + j];
      br[q]  = bias0[1024 + j] + bias0[4096 + j];
      bxh[q] = bias0[2048 + j];
      bhr[q] = bias0[5120 + j];
      hM[q] = 0.f;
    }
    // poll addresses: lanes<32 -> own-group flags0 replica wv (data dep);
    // lanes>=32 -> flags1 quarter (WAR slack-5)
    const int* fp = (lane < 32)
        ? flags0 + (wv * 64 + g * 32 + bl) * 4
        : flags1 + (wv * 128 + g * 64 + wv * 16 + (lane & 15)) * 4;
    int fsav0 = 0;   // cached flag value (monotone)
    // E16 prefetch for epoch 0 (plain loads; double-buffered across epochs)
    f32x4 erC[2][2], erN[2][2];
    {
      const char* eb0 = (const char*)E16 + (size_t)(g * 32 + l15) * 512 + wv * 128 + l4x16;
      const char* eb1 = eb0 + 8192;
      GLD4P(erC[0][0], eb0, "0"); GLD4P(erC[0][1], eb0, "64");
      GLD4P(erC[1][0], eb1, "0"); GLD4P(erC[1][1], eb1, "64");
    }
    asm volatile("s_waitcnt vmcnt(0)" ::: "memory");
    __syncthreads();

    for (int e = 0; e < 512; ++e) {
      POLLC(fp, ((lane < 32) ? e : (e - 5)), fsav0);
      // A loads: h0[e-1] (buf (e+5)%6, sc forced-miss); E16[e] already in erC.
      // E16[e+1] prefetch issued after the h loads (newest in vmcnt order).
      f32x4 hrA[2][8];
      {
        const char* hbb = (const char*)h0f + (size_t)((e + 5) % 6) * 131072;
        const char* hb0 = hbb + (g * 32 + l15) * 2048 + wv * 512 + l4x16;
        const char* hb1 = hb0 + 32768;
        HL8(0, hb0); HL8(1, hb1);
        int en = (e < 511) ? e + 1 : e;
        const char* eb0 = (const char*)E16 +
            (size_t)(en * 64 + g * 32 + l15) * 512 + wv * 128 + l4x16;
        const char* eb1 = eb0 + 8192;
        GLD4P(erN[0][0], eb0, "0"); GLD4P(erN[0][1], eb0, "64");
        GLD4P(erN[1][0], eb1, "0"); GLD4P(erN[1][1], eb1, "64");
      }
      // ---- MFMA phase 1: A-tile 0 (oldest 8 loads; 12 in flight allowed) ----
      asm volatile("s_waitcnt vmcnt(12)" ::: "memory"); SB;
      __builtin_amdgcn_s_setprio(1);
      f32x4 acc[2][8] = {};
      #pragma unroll
      for (int kt = 0; kt < 8; ++kt) {
        half8 af0 = BC8(hrA[0][kt]);
        MF(af0, zr[0][0][kt], acc[0][0]);
        MF(af0, zr[0][1][kt], acc[0][1]);
        MF(af0, zr[1][0][kt], acc[0][2]);
        MF(af0, zr[1][1][kt], acc[0][3]);
        half8 bh0 = LDH0(l15, kt), bh1 = LDH0(16 + l15, kt);
        MF(af0, bh0, acc[0][4]);
        MF(af0, bh1, acc[0][5]);
      }
      // ---- MFMA phase 2: A-tile 1 (all h loads done; erN may be in flight) --
      asm volatile("s_waitcnt vmcnt(4)" ::: "memory"); SB;
      #pragma unroll
      for (int kt = 0; kt < 8; ++kt) {
        half8 af1 = BC8(hrA[1][kt]);
        MF(af1, zr[0][0][kt], acc[1][0]);
        MF(af1, zr[0][1][kt], acc[1][1]);
        MF(af1, zr[1][0][kt], acc[1][2]);
        MF(af1, zr[1][1][kt], acc[1][3]);
        half8 bh0 = LDH0(l15, kt), bh1 = LDH0(16 + l15, kt);
        MF(af1, bh0, acc[1][4]);
        MF(af1, bh1, acc[1][5]);
      }
      // ---- MFMA phase 3: e-part (erC from regs; drain erN for rotation) ----
      asm volatile("s_waitcnt vmcnt(0)" ::: "memory"); SB;
      #pragma unroll
      for (int kt = 0; kt < 2; ++kt) {
        half8 af0 = BC8(erC[0][kt]), af1 = BC8(erC[1][kt]);
        MF(af0, ezr[0][0][kt], acc[0][0]); MF(af1, ezr[0][0][kt], acc[1][0]);
        MF(af0, ezr[0][1][kt], acc[0][1]); MF(af1, ezr[0][1][kt], acc[1][1]);
        MF(af0, ezr[1][0][kt], acc[0][2]); MF(af1, ezr[1][0][kt], acc[1][2]);
        MF(af0, ezr[1][1][kt], acc[0][3]); MF(af1, ezr[1][1][kt], acc[1][3]);
        half8 be0 = LDE0(l15, kt), be1 = LDE0(16 + l15, kt);
        MF(af0, be0, acc[0][6]); MF(af1, be0, acc[1][6]);
        MF(af0, be1, acc[0][7]); MF(af1, be1, acc[1][7]);
      }
      __builtin_amdgcn_s_setprio(0);
      // scatter partials: rows = kv*32 + batch, cols: z0..31|r|hh_h|hh_e
      #pragma unroll
      for (int m = 0; m < 2; ++m)
        #pragma unroll
        for (int n = 0; n < 8; ++n) {
          int colb = (n < 6) ? ((n >> 1) * 32 + (n & 1) * 16) : (96 + (n & 1) * 16);
          #pragma unroll
          for (int r = 0; r < 4; ++r)
            hgp[(wv * 32 + m * 16 + l4 * 4 + r) * 129 + colb + l15] = acc[m][n][r];
        }
      __syncthreads();
      // combine (thread = batch bl x 4 units)
      half4 hv;
      #pragma unroll
      for (int q = 0; q < 4; ++q) {
        int c = ug * 4 + q;
        float hz = 0.f, hr = 0.f, hhh = 0.f, xh = 0.f;
        #pragma unroll
        for (int kv = 0; kv < 4; ++kv) {
          const float* rowp = hgp + (kv * 32 + bl) * 129 + c;
          hz += rowp[0]; hr += rowp[32]; hhh += rowp[64]; xh += rowp[96];
        }
        float z = 1.f / (1.f + __expf(-(hz + bz[q])));
        float r = 1.f / (1.f + __expf(-(hr + br[q])));
        float targ = xh + bxh[q] + r * (hhh + bhr[q]);
        float hh = 1.f - 2.f / (1.f + __expf(2.f * targ));
        float hnew = z * hM[q] + (1.f - z) * hh;
        hM[q] = hnew;
        hv[q] = (half_t)hnew;
      }
      // rotate E16 buffers (erN drained at phase-3 vmcnt(0))
      #pragma unroll
      for (int a = 0; a < 2; ++a)
        #pragma unroll
        for (int b2 = 0; b2 < 2; ++b2) erC[a][b2] = erN[a][b2];
      // publish h0[e] -> buf e%6
      {
        const char* dst = (const char*)h0f + (size_t)(e % 6) * 131072
                        + (g * 32 + bl) * 2048 + (j0 + ug * 4) * 2;
        f32x2 pv = __builtin_bit_cast(f32x2, hv);
        asm volatile("global_store_dwordx2 %0, %1, off sc0 sc1"
                     :: "v"(dst), "v"(pv) : "memory");
      }
      asm volatile("s_waitcnt vmcnt(0)" ::: "memory");
      __syncthreads();
      if (tid < 4) {
        int tv = e + 1;
        const int* dst = flags0 + (tid * 64 + w) * 4;
        asm volatile("global_store_dword %0, %1, off sc0 sc1"
                     :: "v"(dst), "v"(tv) : "memory");
      }
    }
  } else {
    // =================== LAYER 1 ===================
    const int wp = blockIdx.x - 64;
    const int g = wp >> 6, uslot = wp & 63, j0 = uslot * 16;
    float* hgp = (float*)(smem + 65536);   // [4][32][65]

    // stage hh rows (16 units x 2048), XOR-swizzled
    for (int it = 0; it < 16; ++it) {
      int idx = it * 256 + tid;
      int u = idx >> 8, kc = idx & 255;
      int byteoff = (u * 4096 + kc * 16) ^ ((u & 7) << 4);
      *(half8*)(smem + byteoff) =
          *(const half8*)(T1 + (size_t)(2048 + j0 + u) * 2048 + kc * 8);
    }
    // pin z,r B-frags over this wave's 512-k slice
    half8 zr1[2][16];
    #pragma unroll
    for (int gate = 0; gate < 2; ++gate) {
      const half_t* row = T1 + (size_t)(gate * 1024 + j0 + l15) * 2048 + wv * 512;
      #pragma unroll
      for (int kt = 0; kt < 16; ++kt)
        zr1[gate][kt] = *(const half8*)(row + kt * 32 + l4 * 8);
    }
    float bz[2], br[2], bhr[2], bxh[2], hM[2];
    #pragma unroll
    for (int q = 0; q < 2; ++q) {
      int j = j0 + ug * 2 + q;
      bz[q]  = bias1[j]        + bias1[3072 + j];
      br[q]  = bias1[1024 + j] + bias1[4096 + j];
      bxh[q] = bias1[2048 + j];
      bhr[q] = bias1[5120 + j];
      hM[q] = 0.f;
    }
    // poll addresses: waves 0,1 -> flags0 (replicas 0,1); waves 2,3 -> flags1
    const int* fp = (wv < 2)
        ? flags0 + (wv * 64 + g * 32 + bl) * 4
        : flags1 + (wv * 128 + g * 64 + lane) * 4;
    int fsav1 = 0;
    __syncthreads();

    for (int e = 1; e <= 512; ++e) {
      POLLC(fp, ((wv < 2) ? e : (e - 1)), fsav1);
      // A loads: waves 0,1 from h0[e-1] (buf (e+5)%6); waves 2,3 from h1[e-2]
      f32x4 hrA[2][16];
      {
        const char* fb = (wv < 2)
            ? (const char*)h0f + (size_t)((e + 5) % 6) * 131072
            : (const char*)h1f + (size_t)((e + 2) & 3) * 131072;
        const char* b0 = fb + (g * 32 + l15) * 2048 + (wv & 1) * 1024 + l4x16;
        const char* b1 = b0 + 32768;
        HL16(0, b0); HL16(1, b1);
      }
      // ---- MFMA phase 1: A-tile 0 (oldest 16 loads) ----
      asm volatile("s_waitcnt vmcnt(16)" ::: "memory"); SB;
      __builtin_amdgcn_s_setprio(1);
      f32x4 acc[2][3] = {};
      #pragma unroll
      for (int kt = 0; kt < 16; ++kt) {
        half8 af0 = BC8(hrA[0][kt]);
        MF(af0, zr1[0][kt], acc[0][0]);
        MF(af0, zr1[1][kt], acc[0][1]);
        half8 bh = LDH1(kt);
        MF(af0, bh, acc[0][2]);
      }
      // ---- MFMA phase 2: A-tile 1 ----
      asm volatile("s_waitcnt vmcnt(0)" ::: "memory"); SB;
      #pragma unroll
      for (int kt = 0; kt < 16; ++kt) {
        half8 af1 = BC8(hrA[1][kt]);
        MF(af1, zr1[0][kt], acc[1][0]);
        MF(af1, zr1[1][kt], acc[1][1]);
        half8 bh = LDH1(kt);
        MF(af1, bh, acc[1][2]);
      }
      __builtin_amdgcn_s_setprio(0);
      // scatter: cols z:0..15, r:16..31, hh_h:32..47 (wv>=2), hh_x:48..63 (wv<2)
      {
        int hhcol = (wv < 2) ? 48 : 32;
        #pragma unroll
        for (int m = 0; m < 2; ++m)
          #pragma unroll
          for (int r = 0; r < 4; ++r) {
            int row = (wv * 32 + m * 16 + l4 * 4 + r) * 65;
            hgp[row + l15]        = acc[m][0][r];
            hgp[row + 16 + l15]   = acc[m][1][r];
            hgp[row + hhcol + l15] = acc[m][2][r];
          }
      }
      __syncthreads();
      // combine (thread = batch bl x 2 units)
      half2 hv;
      #pragma unroll
      for (int q = 0; q < 2; ++q) {
        int c = ug * 2 + q;
        float hz = 0.f, hr = 0.f;
        #pragma unroll
        for (int kv = 0; kv < 4; ++kv) {
          const float* rowp = hgp + (kv * 32 + bl) * 65 + c;
          hz += rowp[0]; hr += rowp[16];
        }
        float hhh = hgp[(2 * 32 + bl) * 65 + 32 + c] + hgp[(3 * 32 + bl) * 65 + 32 + c];
        float xh  = hgp[(0 * 32 + bl) * 65 + 48 + c] + hgp[(1 * 32 + bl) * 65 + 48 + c];
        float z = 1.f / (1.f + __expf(-(hz + bz[q])));
        float r = 1.f / (1.f + __expf(-(hr + br[q])));
        float targ = xh + bxh[q] + r * (hhh + bhr[q]);
        float hh = 1.f - 2.f / (1.f + __expf(2.f * targ));
        float hnew = z * hM[q] + (1.f - z) * hh;
        hM[q] = hnew;
        hv[q] = (half_t)hnew;
      }
      // output + publish h1[e-1] -> buf (e-1)&3
      *(half2*)(ys1 + ((size_t)(e - 1) * 64 + g * 32 + bl) * 1024 + j0 + ug * 2) = hv;
      {
        const char* dst = (const char*)h1f + (size_t)((e + 3) & 3) * 131072
                        + (g * 32 + bl) * 2048 + (j0 + ug * 2) * 2;
        float pv = __builtin_bit_cast(float, hv);
        asm volatile("global_store_dword %0, %1, off sc0 sc1"
                     :: "v"(dst), "v"(pv) : "memory");
      }
      asm volatile("s_waitcnt vmcnt(0)" ::: "memory");
      __syncthreads();
      if (tid < 4) {
        int tv = e;
        const int* dst = flags1 + (tid * 128 + wp) * 4;
        asm volatile("global_store_dword %0, %1, off sc0 sc1"
                     :: "v"(dst), "v"(tv) : "memory");
      }
    }
  }
}

// ---------------- softmax over 256 vocab (one wave per row) -------------------
__global__ __launch_bounds__(256)
void softmax_kernel(const float* __restrict__ logits, const float* __restrict__ bd,
                    float* __restrict__ out) {
  int w = threadIdx.x >> 6, lane = threadIdx.x & 63;
  int m = blockIdx.x * 4 + w;          // m = s*64 + b
  const float* lrow = logits + (size_t)m * 256;
  float v[4];
  #pragma unroll
  for (int i = 0; i < 4; ++i) v[i] = lrow[lane + i * 64] + bd[lane + i * 64];
  float mx = fmaxf(fmaxf(v[0], v[1]), fmaxf(v[2], v[3]));
  #pragma unroll
  for (int off = 32; off; off >>= 1) mx = fmaxf(mx, __shfl_xor(mx, off));
  float s = 0.f;
  #pragma unroll
  for (int i = 0; i < 4; ++i) { v[i] = __expf(v[i] - mx); s += v[i]; }
  #pragma unroll
  for (int off = 32; off; off >>= 1) s += __shfl_xor(s, off);
  float inv = 1.f / s;
  int b = m & 63, sq = m >> 6;
  float* orow = out + ((size_t)b * 512 + sq) * 256;
  #pragma unroll
  for (int i = 0; i < 4; ++i) orow[lane + i * 64] = v[i] * inv;
}

// ---------------- launch ------------------------------------------------------
extern "C" void kernel_launch(void* const* d_in, const int* in_sizes, int n_in,
                              void* d_out, int out_size, void* d_ws, size_t ws_size,
                              hipStream_t stream) {
  const int*   x   = (const int*)d_in[0];
  const float* emb = (const float*)d_in[1];
  const float* W0  = (const float*)d_in[2];
  const float* U0  = (const float*)d_in[3];
  const float* b0  = (const float*)d_in[4];
  const float* W1  = (const float*)d_in[5];
  const float* U1  = (const float*)d_in[6];
  const float* b1  = (const float*)d_in[7];
  const float* Wd  = (const float*)d_in[8];
  const float* bd  = (const float*)d_in[9];
  float* out = (float*)d_out;
  (void)in_sizes; (void)n_in; (void)out_size; (void)ws_size;

  char* p = (char*)d_ws;
  size_t off = 0;
  auto take = [&](size_t bytes) {
    char* r = p + off;
    off = (off + bytes + 255) & ~(size_t)255;
    return r;
  };
  half_t* T0  = (half_t*)take(3072ull * 1280 * 2);   // [U0;W0]^T
  half_t* T1  = (half_t*)take(3072ull * 2048 * 2);   // [W1;U1]^T
  half_t* WdT = (half_t*)take(256ull * 1024 * 2);
  const size_t H0B = 6ull * 131072, H1B = 4ull * 131072;
  const size_t F0B = 4096, F1B = 8192;
  char* stateblk = take(H0B + H1B + F0B + F1B);
  half_t* h0f   = (half_t*)stateblk;
  half_t* h1f   = (half_t*)(stateblk + H0B);
  int*    flags0 = (int*)(stateblk + H0B + H1B);
  int*    flags1 = (int*)(stateblk + H0B + H1B + F0B);
  half_t* E16 = (half_t*)take(32768ull * 256 * 2);
  half_t* ys1 = (half_t*)take(32768ull * 1024 * 2);
  float* logits = (float*)take(32768ull * 256 * 4);

  // weight transposes fp32->fp16 into concat layouts
  wt_transpose<<<dim3(96, 32), dim3(32, 8), 0, stream>>>(U0, T0, 1024, 3072, 1280, 0);
  wt_transpose<<<dim3(96, 8),  dim3(32, 8), 0, stream>>>(W0, T0, 256,  3072, 1280, 1024);
  wt_transpose<<<dim3(96, 32), dim3(32, 8), 0, stream>>>(W1, T1, 1024, 3072, 2048, 0);
  wt_transpose<<<dim3(96, 32), dim3(32, 8), 0, stream>>>(U1, T1, 1024, 3072, 2048, 1024);
  wt_transpose<<<dim3(8, 32),  dim3(32, 8), 0, stream>>>(Wd, WdT, 1024, 256, 1024, 0);
  embed_kernel<<<4096, 256, 0, stream>>>(x, emb, E16);

  hipFuncSetAttribute((const void*)recur_fused,
                      hipFuncAttributeMaxDynamicSharedMemorySize, 147968);
  hipMemsetAsync(stateblk, 0, H0B + H1B + F0B + F1B, stream);

  recur_fused<<<192, 256, 147968, stream>>>(E16, T0, T1, b0, b1, ys1,
                                            h0f, h1f, flags0, flags1);

  gemm128<<<dim3(2, 256), 256, 0, stream>>>(ys1, WdT, logits, 256, 1024);
  softmax_kernel<<<8192, 256, 0, stream>>>(logits, bd, out);
}